// Round 1
// baseline (702.895 us; speedup 1.0000x reference)
//
#include <hip/hip_runtime.h>

#define DEVINL __device__ __forceinline__

constexpr int Bc = 32, Cc = 64, Tc = 1024, DIM2c = 128;
constexpr int Nn = Bc * Tc;            // 32768 nodes
constexpr int Ec = 524288;             // edges
constexpr int ENc = Ec + Nn;           // 557056 edges incl self-loops

// workspace offsets (in floats)
constexpr long O_XBN  = 0;               // 2097152
constexpr long O_RES  = 2097152;         // 4194304
constexpr long O_XLXR = 6291456;         // 8388608 ([n][0..127]=xl, [128..255]=xr); z aliases this
constexpr long O_P    = 14680064;        // 1114112 (logits then p, [e][h])
constexpr long O_GOUT = 15794176;        // 4194304
constexpr long O_H2   = 19988480;        // 4194304
constexpr long O_LMAX = 24182784;        // 65536 (uint encoded)
constexpr long O_DEN  = 24248320;        // 65536
constexpr long O_STAT = 24313856;        // 2048

// monotonic float<->uint encoding for atomicMax on floats
DEVINL unsigned encf(float f) {
    unsigned ub = (unsigned)__float_as_int(f);
    unsigned mask = (ub >> 31) ? 0xFFFFFFFFu : 0x80000000u;
    return ub ^ mask;
}
DEVINL float decf(unsigned u) {
    unsigned mask = (u >> 31) ? 0x80000000u : 0xFFFFFFFFu;
    return __uint_as_float(u ^ mask);
}

// ---------------- bn0: per-channel stats over [B,C,T] (axis 0,2) ----------------
__global__ __launch_bounds__(256) void bn0_stats(const float* __restrict__ x,
        const float* __restrict__ g, const float* __restrict__ bta,
        float* __restrict__ scale0, float* __restrict__ shift0) {
    int c = blockIdx.x;
    const float* base = x + c * Tc;
    float s = 0.f, q = 0.f;
    for (int i = threadIdx.x; i < Bc * Tc; i += 256) {
        int b = i >> 10, t = i & 1023;
        float v = base[b * (Cc * Tc) + t];
        s += v; q = fmaf(v, v, q);
    }
    for (int off = 32; off; off >>= 1) { s += __shfl_down(s, off); q += __shfl_down(q, off); }
    __shared__ float ls[4], lq[4];
    int w = threadIdx.x >> 6, lane = threadIdx.x & 63;
    if (lane == 0) { ls[w] = s; lq[w] = q; }
    __syncthreads();
    if (threadIdx.x == 0) {
        s = ls[0] + ls[1] + ls[2] + ls[3];
        q = lq[0] + lq[1] + lq[2] + lq[3];
        float mu = s * (1.f / 32768.f);
        float var = q * (1.f / 32768.f) - mu * mu;
        float rs = rsqrtf(var + 1e-5f);
        float sc = rs * g[c];
        scale0[c] = sc;
        shift0[c] = bta[c] - mu * sc;
    }
}

__global__ __launch_bounds__(256) void bn0_apply(const float* __restrict__ x,
        const float* __restrict__ scale0, const float* __restrict__ shift0,
        float* __restrict__ y) {
    int idx = blockIdx.x * 256 + threadIdx.x;   // float4 index, 524288 total
    int i = idx << 2;
    int c = (i >> 10) & 63;
    float4 v = ((const float4*)x)[idx];
    float sc = scale0[c], sh = shift0[c];
    float4 o;
    o.x = fmaf(v.x, sc, sh); o.y = fmaf(v.y, sc, sh);
    o.z = fmaf(v.z, sc, sh); o.w = fmaf(v.w, sc, sh);
    ((float4*)y)[idx] = o;
}

// ---------------- conv1d K=9 SAME + bias + relu -> residual [B,128,T] ----------------
__global__ __launch_bounds__(256) void conv_relu(const float* __restrict__ xbn,
        const float* __restrict__ w, const float* __restrict__ bias,
        float* __restrict__ res) {
    __shared__ float xs[64][136];               // [ci][t0-4 .. t0+131]
    int t0  = blockIdx.x * 128;
    int co0 = blockIdx.y * 32;
    int b   = blockIdx.z;
    const float* xb = xbn + (long)b * (Cc * Tc);
    for (int i = threadIdx.x; i < 64 * 136; i += 256) {
        int ci = i / 136, tl = i - ci * 136;
        int t = t0 + tl - 4;
        xs[ci][tl] = ((unsigned)t < 1024u) ? xb[ci * Tc + t] : 0.f;
    }
    __syncthreads();
    int tg = threadIdx.x & 15;                  // t-group: 8 outputs
    int cp = threadIdx.x >> 4;                  // 0..15 -> pair of co
    int coA = co0 + cp * 2;
    float accA[8], accB[8];
    float bA = bias[coA], bB = bias[coA + 1];
    #pragma unroll
    for (int j = 0; j < 8; j++) { accA[j] = bA; accB[j] = bB; }
    const float* wA = w + coA * 576;
    const float* wB = wA + 576;
    for (int ci = 0; ci < 64; ci++) {
        float xw[16];
        const float4* xp = (const float4*)&xs[ci][tg * 8];
        float4 x0 = xp[0], x1 = xp[1], x2 = xp[2], x3 = xp[3];
        xw[0]=x0.x; xw[1]=x0.y; xw[2]=x0.z; xw[3]=x0.w;
        xw[4]=x1.x; xw[5]=x1.y; xw[6]=x1.z; xw[7]=x1.w;
        xw[8]=x2.x; xw[9]=x2.y; xw[10]=x2.z; xw[11]=x2.w;
        xw[12]=x3.x; xw[13]=x3.y; xw[14]=x3.z; xw[15]=x3.w;
        #pragma unroll
        for (int k = 0; k < 9; k++) {
            float wa = wA[ci * 9 + k], wb = wB[ci * 9 + k];
            #pragma unroll
            for (int j = 0; j < 8; j++) {
                accA[j] = fmaf(xw[j + k], wa, accA[j]);
                accB[j] = fmaf(xw[j + k], wb, accB[j]);
            }
        }
    }
    int tbase = t0 + tg * 8;
    float* oA = res + (long)b * (DIM2c * Tc) + coA * Tc + tbase;
    float* oB = oA + Tc;
    float4 sa0, sa1, sb0, sb1;
    sa0.x=fmaxf(accA[0],0.f); sa0.y=fmaxf(accA[1],0.f); sa0.z=fmaxf(accA[2],0.f); sa0.w=fmaxf(accA[3],0.f);
    sa1.x=fmaxf(accA[4],0.f); sa1.y=fmaxf(accA[5],0.f); sa1.z=fmaxf(accA[6],0.f); sa1.w=fmaxf(accA[7],0.f);
    sb0.x=fmaxf(accB[0],0.f); sb0.y=fmaxf(accB[1],0.f); sb0.z=fmaxf(accB[2],0.f); sb0.w=fmaxf(accB[3],0.f);
    sb1.x=fmaxf(accB[4],0.f); sb1.y=fmaxf(accB[5],0.f); sb1.z=fmaxf(accB[6],0.f); sb1.w=fmaxf(accB[7],0.f);
    ((float4*)oA)[0] = sa0; ((float4*)oA)[1] = sa1;
    ((float4*)oB)[0] = sb0; ((float4*)oB)[1] = sb1;
}

// ---------------- generic small GEMM: Y[m][j] = sum_c A[m][c] * Wrow(j)[c] ----------------
// W0 covers cols [0,128), W1 cols [128,256). 64x64 output tile / block, 256 thr.
__global__ __launch_bounds__(256) void gemm_nt(const float* __restrict__ A,
        const float* __restrict__ W0, const float* __restrict__ W1,
        float* __restrict__ Y, int K, int ldY) {
    __shared__ float As[64][68];
    __shared__ float Bs[64][68];
    int row0 = blockIdx.x * 64, j0 = blockIdx.y * 64;
    int tid = threadIdx.x;
    int tx = tid & 15, ty = tid >> 4;
    float acc[4][4] = {};
    for (int kt = 0; kt < K; kt += 64) {
        for (int i = tid; i < 4096; i += 256) {
            int c = i & 63, r = i >> 6;
            As[c][r] = A[(long)(row0 + r) * K + kt + c];
        }
        for (int i = tid; i < 4096; i += 256) {
            int c = i & 63, jl = i >> 6;
            int jg = j0 + jl;
            const float* Wr = (jg < 128) ? (W0 + (long)jg * K) : (W1 + (long)(jg - 128) * K);
            Bs[c][jl] = Wr[kt + c];
        }
        __syncthreads();
        #pragma unroll 4
        for (int c = 0; c < 64; c++) {
            float4 a = *(const float4*)&As[c][ty * 4];
            float4 b = *(const float4*)&Bs[c][tx * 4];
            float av[4] = {a.x, a.y, a.z, a.w};
            float bv[4] = {b.x, b.y, b.z, b.w};
            #pragma unroll
            for (int i = 0; i < 4; i++)
                #pragma unroll
                for (int j = 0; j < 4; j++)
                    acc[i][j] = fmaf(av[i], bv[j], acc[i][j]);
        }
        __syncthreads();
    }
    #pragma unroll
    for (int i = 0; i < 4; i++) {
        long r = row0 + ty * 4 + i;
        float4 v; v.x = acc[i][0]; v.y = acc[i][1]; v.z = acc[i][2]; v.w = acc[i][3];
        *(float4*)&Y[r * ldY + j0 + tx * 4] = v;
    }
}

// ---------------- GATv2 edge logits + segment max ----------------
__global__ __launch_bounds__(256) void edge_logits(const float* __restrict__ xlxr,
        const int* __restrict__ ei, const float* __restrict__ att,
        float* __restrict__ p, unsigned* __restrict__ lmaxU) {
    int gid = blockIdx.x * 256 + threadIdx.x;
    int e = gid >> 6, lane = gid & 63;
    if (e >= ENc) return;
    int s, t;
    if (e < Ec) { s = ei[e]; t = ei[Ec + e]; } else { s = e - Ec; t = s; }
    float l0 = xlxr[(long)s * 256 + lane]      + xlxr[(long)t * 256 + 128 + lane];
    float l1 = xlxr[(long)s * 256 + 64 + lane] + xlxr[(long)t * 256 + 192 + lane];
    l0 = (l0 >= 0.f) ? l0 : 0.2f * l0;
    l1 = (l1 >= 0.f) ? l1 : 0.2f * l1;
    l0 *= att[lane];
    l1 *= att[64 + lane];
    for (int off = 32; off; off >>= 1) { l0 += __shfl_down(l0, off); l1 += __shfl_down(l1, off); }
    if (lane == 0) {
        p[(long)e * 2]     = l0;
        p[(long)e * 2 + 1] = l1;
        atomicMax(lmaxU + t * 2,     encf(l0));
        atomicMax(lmaxU + t * 2 + 1, encf(l1));
    }
}

__global__ __launch_bounds__(256) void p_den(const int* __restrict__ ei,
        float* __restrict__ p, const unsigned* __restrict__ lmaxU,
        float* __restrict__ den) {
    int idx = blockIdx.x * 256 + threadIdx.x;   // < EN*2
    int e = idx >> 1, h = idx & 1;
    int t = (e < Ec) ? ei[Ec + e] : e - Ec;
    float lm = decf(lmaxU[t * 2 + h]);
    float pv = __expf(p[idx] - lm);
    p[idx] = pv;
    unsafeAtomicAdd(den + t * 2 + h, pv);
}

__global__ __launch_bounds__(256) void scatter(const float* __restrict__ xlxr,
        const int* __restrict__ ei, const float* __restrict__ p,
        const float* __restrict__ den, float* __restrict__ gout) {
    int gid = blockIdx.x * 256 + threadIdx.x;
    int e = gid >> 6, lane = gid & 63;
    if (e >= ENc) return;
    int s, t;
    if (e < Ec) { s = ei[e]; t = ei[Ec + e]; } else { s = e - Ec; t = s; }
    float a0 = p[(long)e * 2]     / den[t * 2];
    float a1 = p[(long)e * 2 + 1] / den[t * 2 + 1];
    float v0 = xlxr[(long)s * 256 + lane];
    float v1 = xlxr[(long)s * 256 + 64 + lane];
    unsafeAtomicAdd(gout + (long)t * 128 + lane,      v0 * a0);
    unsafeAtomicAdd(gout + (long)t * 128 + 64 + lane, v1 * a1);
}

// ---------------- bn over [N,128] (axis 0) ----------------
__global__ __launch_bounds__(256) void bn_stats(const float* __restrict__ X,
        float* __restrict__ sum, float* __restrict__ sq) {
    int f = threadIdx.x & 127, sub = threadIdx.x >> 7;
    int r0 = blockIdx.x * 256;
    float s = 0.f, q = 0.f;
    for (int r = r0 + sub; r < r0 + 256; r += 2) {
        float v = X[(long)r * 128 + f];
        s += v; q = fmaf(v, v, q);
    }
    __shared__ float ls[256], lq[256];
    ls[threadIdx.x] = s; lq[threadIdx.x] = q;
    __syncthreads();
    if (threadIdx.x < 128) {
        s = ls[threadIdx.x] + ls[threadIdx.x + 128];
        q = lq[threadIdx.x] + lq[threadIdx.x + 128];
        unsafeAtomicAdd(sum + f, s);
        unsafeAtomicAdd(sq + f, q);
    }
}

__global__ void stats_final(const float* __restrict__ sum, const float* __restrict__ sq,
        const float* __restrict__ g, const float* __restrict__ bta,
        float* __restrict__ scale, float* __restrict__ shift) {
    int f = threadIdx.x;
    float mu = sum[f] * (1.f / 32768.f);
    float var = sq[f] * (1.f / 32768.f) - mu * mu;
    float rs = rsqrtf(var + 1e-5f);
    float sc = rs * g[f];
    scale[f] = sc;
    shift[f] = bta[f] - mu * sc;
}

// out[i] = res[i] + relu(X[i]*scale[f] + shift[f]),  f = i % 128
__global__ __launch_bounds__(256) void bn_res(const float* __restrict__ X,
        const float* __restrict__ res, const float* __restrict__ scale,
        const float* __restrict__ shift, float* __restrict__ out) {
    int idx = blockIdx.x * 256 + threadIdx.x;   // float4 index, 1048576 total
    int f4 = idx & 31;
    float4 v = ((const float4*)X)[idx];
    float4 sc = ((const float4*)scale)[f4];
    float4 sh = ((const float4*)shift)[f4];
    float4 r = ((const float4*)res)[idx];
    float4 o;
    o.x = r.x + fmaxf(fmaf(v.x, sc.x, sh.x), 0.f);
    o.y = r.y + fmaxf(fmaf(v.y, sc.y, sh.y), 0.f);
    o.z = r.z + fmaxf(fmaf(v.z, sc.z, sh.z), 0.f);
    o.w = r.w + fmaxf(fmaf(v.w, sc.w, sh.w), 0.f);
    ((float4*)out)[idx] = o;
}

extern "C" void kernel_launch(void* const* d_in, const int* in_sizes, int n_in,
                              void* d_out, int out_size, void* d_ws, size_t ws_size,
                              hipStream_t stream) {
    const float* x   = (const float*)d_in[0];
    const int*   ei  = (const int*)d_in[1];
    const float* g0  = (const float*)d_in[2];
    const float* b0  = (const float*)d_in[3];
    const float* cw  = (const float*)d_in[4];
    const float* cb  = (const float*)d_in[5];
    const float* wl  = (const float*)d_in[6];
    const float* wr  = (const float*)d_in[7];
    const float* att = (const float*)d_in[8];
    // d_in[9] = gat_bias: cancels exactly inside the following bn2d -> unused
    const float* g1  = (const float*)d_in[10];
    const float* b1  = (const float*)d_in[11];
    const float* chw = (const float*)d_in[12];
    // d_in[13] = cheb_b: cancels inside the following bn2d -> unused
    float* out = (float*)d_out;

    float* ws   = (float*)d_ws;
    float*    xbn  = ws + O_XBN;
    float*    res  = ws + O_RES;
    float*    xlxr = ws + O_XLXR;
    float*    z    = ws + O_XLXR;     // alias: xl/xr dead before cheb gemm
    float*    p    = ws + O_P;
    float*    gout = ws + O_GOUT;
    float*    h2   = ws + O_H2;
    unsigned* lmax = (unsigned*)(ws + O_LMAX);
    float*    den  = ws + O_DEN;
    float*    st   = ws + O_STAT;
    float *scale0 = st, *shift0 = st + 64;
    float *sum1 = st + 128, *sq1 = st + 256, *scale1 = st + 384, *shift1 = st + 512;
    float *sum2 = st + 640, *sq2 = st + 768, *scale2 = st + 896, *shift2 = st + 1024;

    // zero accumulators (ws is poisoned 0xAA before every call)
    hipMemsetAsync(gout, 0, (size_t)4194304 * 4, stream);
    hipMemsetAsync(lmax, 0, (size_t)65536 * 4, stream);
    hipMemsetAsync(den,  0, (size_t)65536 * 4, stream);
    hipMemsetAsync(st,   0, (size_t)2048 * 4, stream);

    // 1. bn0
    bn0_stats<<<64, 256, 0, stream>>>(x, g0, b0, scale0, shift0);
    bn0_apply<<<2048, 256, 0, stream>>>(x, scale0, shift0, xbn);
    // 2. conv1d + relu -> residual
    conv_relu<<<dim3(8, 4, 32), 256, 0, stream>>>(xbn, cw, cb, res);
    // 3. xl | xr = h @ [wl|wr]^T   (h = xbn viewed [32768,64])
    gemm_nt<<<dim3(512, 4), 256, 0, stream>>>(xbn, wl, wr, xlxr, 64, 256);
    // 4. GATv2 softmax-attention aggregation
    edge_logits<<<ENc / 4, 256, 0, stream>>>(xlxr, ei, att, p, lmax);
    p_den<<<(ENc * 2) / 256, 256, 0, stream>>>(ei, p, lmax, den);
    scatter<<<ENc / 4, 256, 0, stream>>>(xlxr, ei, p, den, gout);
    // 5. bn1 + relu + residual -> h2
    bn_stats<<<128, 256, 0, stream>>>(gout, sum1, sq1);
    stats_final<<<1, 128, 0, stream>>>(sum1, sq1, g1, b1, scale1, shift1);
    bn_res<<<4096, 256, 0, stream>>>(gout, res, scale1, shift1, h2);
    // 6. cheb linear
    gemm_nt<<<dim3(512, 2), 256, 0, stream>>>(h2, chw, chw, z, 128, 128);
    // 7. bn1 again + relu + residual -> out
    bn_stats<<<128, 256, 0, stream>>>(z, sum2, sq2);
    stats_final<<<1, 128, 0, stream>>>(sum2, sq2, g1, b1, scale2, shift2);
    bn_res<<<4096, 256, 0, stream>>>(z, res, scale2, shift2, out);
}

// Round 2
// 497.365 us; speedup vs baseline: 1.4132x; 1.4132x over previous
//
#include <hip/hip_runtime.h>

#define DEVINL __device__ __forceinline__

constexpr int Bc = 32, Cc = 64, Tc = 1024, DIM2c = 128;
constexpr int Nn = Bc * Tc;            // 32768 nodes
constexpr int Ec = 524288;             // edges (self-loops handled implicitly)

// workspace offsets (in floats)
constexpr long O_XBN  = 0;               // 2097152
constexpr long O_RES  = 2097152;         // 4194304
constexpr long O_XLXR = 6291456;         // 8388608 ([n][0..127]=xl, [128..255]=xr); z aliases
constexpr long O_GOUT = 14680064;        // 4194304
constexpr long O_H2   = 18874368;        // 4194304
constexpr long O_STAT = 23068672;        // 2048
constexpr long O_INT  = 23070720;        // int arrays start here (as float offset)

// int-array offsets relative to O_INT (in ints)
constexpr long I_DEG  = 0;               // 32768
constexpr long I_RP   = 32768;           // 32769 rowptr
constexpr long I_CUR  = 65540;           // 32768 cursor (aligned)
constexpr long I_SRC  = 98308;           // 524288 csr src-node ids

// ---------------- bn0: per-channel stats over [B,C,T] (axis 0,2) ----------------
__global__ __launch_bounds__(256) void bn0_stats(const float* __restrict__ x,
        const float* __restrict__ g, const float* __restrict__ bta,
        float* __restrict__ scale0, float* __restrict__ shift0) {
    int c = blockIdx.x;
    const float* base = x + c * Tc;
    float s = 0.f, q = 0.f;
    for (int i = threadIdx.x; i < Bc * Tc; i += 256) {
        int b = i >> 10, t = i & 1023;
        float v = base[b * (Cc * Tc) + t];
        s += v; q = fmaf(v, v, q);
    }
    for (int off = 32; off; off >>= 1) { s += __shfl_down(s, off); q += __shfl_down(q, off); }
    __shared__ float ls[4], lq[4];
    int w = threadIdx.x >> 6, lane = threadIdx.x & 63;
    if (lane == 0) { ls[w] = s; lq[w] = q; }
    __syncthreads();
    if (threadIdx.x == 0) {
        s = ls[0] + ls[1] + ls[2] + ls[3];
        q = lq[0] + lq[1] + lq[2] + lq[3];
        float mu = s * (1.f / 32768.f);
        float var = q * (1.f / 32768.f) - mu * mu;
        float rs = rsqrtf(var + 1e-5f);
        float sc = rs * g[c];
        scale0[c] = sc;
        shift0[c] = bta[c] - mu * sc;
    }
}

__global__ __launch_bounds__(256) void bn0_apply(const float* __restrict__ x,
        const float* __restrict__ scale0, const float* __restrict__ shift0,
        float* __restrict__ y) {
    int idx = blockIdx.x * 256 + threadIdx.x;   // float4 index, 524288 total
    int i = idx << 2;
    int c = (i >> 10) & 63;
    float4 v = ((const float4*)x)[idx];
    float sc = scale0[c], sh = shift0[c];
    float4 o;
    o.x = fmaf(v.x, sc, sh); o.y = fmaf(v.y, sc, sh);
    o.z = fmaf(v.z, sc, sh); o.w = fmaf(v.w, sc, sh);
    ((float4*)y)[idx] = o;
}

// ---------------- conv1d K=9 SAME + bias + relu -> residual [B,128,T] ----------------
__global__ __launch_bounds__(256) void conv_relu(const float* __restrict__ xbn,
        const float* __restrict__ w, const float* __restrict__ bias,
        float* __restrict__ res) {
    __shared__ float xs[64][136];               // [ci][t0-4 .. t0+131]
    int t0  = blockIdx.x * 128;
    int co0 = blockIdx.y * 32;
    int b   = blockIdx.z;
    const float* xb = xbn + (long)b * (Cc * Tc);
    for (int i = threadIdx.x; i < 64 * 136; i += 256) {
        int ci = i / 136, tl = i - ci * 136;
        int t = t0 + tl - 4;
        xs[ci][tl] = ((unsigned)t < 1024u) ? xb[ci * Tc + t] : 0.f;
    }
    __syncthreads();
    int tg = threadIdx.x & 15;                  // t-group: 8 outputs
    int cp = threadIdx.x >> 4;                  // 0..15 -> pair of co
    int coA = co0 + cp * 2;
    float accA[8], accB[8];
    float bA = bias[coA], bB = bias[coA + 1];
    #pragma unroll
    for (int j = 0; j < 8; j++) { accA[j] = bA; accB[j] = bB; }
    const float* wA = w + coA * 576;
    const float* wB = wA + 576;
    for (int ci = 0; ci < 64; ci++) {
        float xw[16];
        const float4* xp = (const float4*)&xs[ci][tg * 8];
        float4 x0 = xp[0], x1 = xp[1], x2 = xp[2], x3 = xp[3];
        xw[0]=x0.x; xw[1]=x0.y; xw[2]=x0.z; xw[3]=x0.w;
        xw[4]=x1.x; xw[5]=x1.y; xw[6]=x1.z; xw[7]=x1.w;
        xw[8]=x2.x; xw[9]=x2.y; xw[10]=x2.z; xw[11]=x2.w;
        xw[12]=x3.x; xw[13]=x3.y; xw[14]=x3.z; xw[15]=x3.w;
        #pragma unroll
        for (int k = 0; k < 9; k++) {
            float wa = wA[ci * 9 + k], wb = wB[ci * 9 + k];
            #pragma unroll
            for (int j = 0; j < 8; j++) {
                accA[j] = fmaf(xw[j + k], wa, accA[j]);
                accB[j] = fmaf(xw[j + k], wb, accB[j]);
            }
        }
    }
    int tbase = t0 + tg * 8;
    float* oA = res + (long)b * (DIM2c * Tc) + coA * Tc + tbase;
    float* oB = oA + Tc;
    float4 sa0, sa1, sb0, sb1;
    sa0.x=fmaxf(accA[0],0.f); sa0.y=fmaxf(accA[1],0.f); sa0.z=fmaxf(accA[2],0.f); sa0.w=fmaxf(accA[3],0.f);
    sa1.x=fmaxf(accA[4],0.f); sa1.y=fmaxf(accA[5],0.f); sa1.z=fmaxf(accA[6],0.f); sa1.w=fmaxf(accA[7],0.f);
    sb0.x=fmaxf(accB[0],0.f); sb0.y=fmaxf(accB[1],0.f); sb0.z=fmaxf(accB[2],0.f); sb0.w=fmaxf(accB[3],0.f);
    sb1.x=fmaxf(accB[4],0.f); sb1.y=fmaxf(accB[5],0.f); sb1.z=fmaxf(accB[6],0.f); sb1.w=fmaxf(accB[7],0.f);
    ((float4*)oA)[0] = sa0; ((float4*)oA)[1] = sa1;
    ((float4*)oB)[0] = sb0; ((float4*)oB)[1] = sb1;
}

// ---------------- generic small GEMM: Y[m][j] = sum_c A[m][c] * Wrow(j)[c] ----------------
__global__ __launch_bounds__(256) void gemm_nt(const float* __restrict__ A,
        const float* __restrict__ W0, const float* __restrict__ W1,
        float* __restrict__ Y, int K, int ldY) {
    __shared__ float As[64][68];
    __shared__ float Bs[64][68];
    int row0 = blockIdx.x * 64, j0 = blockIdx.y * 64;
    int tid = threadIdx.x;
    int tx = tid & 15, ty = tid >> 4;
    float acc[4][4] = {};
    for (int kt = 0; kt < K; kt += 64) {
        for (int i = tid; i < 4096; i += 256) {
            int c = i & 63, r = i >> 6;
            As[c][r] = A[(long)(row0 + r) * K + kt + c];
        }
        for (int i = tid; i < 4096; i += 256) {
            int c = i & 63, jl = i >> 6;
            int jg = j0 + jl;
            const float* Wr = (jg < 128) ? (W0 + (long)jg * K) : (W1 + (long)(jg - 128) * K);
            Bs[c][jl] = Wr[kt + c];
        }
        __syncthreads();
        #pragma unroll 4
        for (int c = 0; c < 64; c++) {
            float4 a = *(const float4*)&As[c][ty * 4];
            float4 b = *(const float4*)&Bs[c][tx * 4];
            float av[4] = {a.x, a.y, a.z, a.w};
            float bv[4] = {b.x, b.y, b.z, b.w};
            #pragma unroll
            for (int i = 0; i < 4; i++)
                #pragma unroll
                for (int j = 0; j < 4; j++)
                    acc[i][j] = fmaf(av[i], bv[j], acc[i][j]);
        }
        __syncthreads();
    }
    #pragma unroll
    for (int i = 0; i < 4; i++) {
        long r = row0 + ty * 4 + i;
        float4 v; v.x = acc[i][0]; v.y = acc[i][1]; v.z = acc[i][2]; v.w = acc[i][3];
        *(float4*)&Y[r * ldY + j0 + tx * 4] = v;
    }
}

// ---------------- CSR build (by destination) ----------------
__global__ __launch_bounds__(256) void deg_count(const int* __restrict__ ei,
        int* __restrict__ deg) {
    int e = blockIdx.x * 256 + threadIdx.x;     // Ec = 2048*256 exact
    atomicAdd(deg + ei[Ec + e], 1);
}

// one block, 256 threads: exclusive scan of deg[32768] -> rowptr, copy to cursor
__global__ __launch_bounds__(256) void scan_deg(const int* __restrict__ deg,
        int* __restrict__ rowptr, int* __restrict__ cursor) {
    __shared__ int part[256];
    int tid = threadIdx.x;
    int base = tid * 128;
    int s = 0;
    int local[128];
    #pragma unroll 4
    for (int k = 0; k < 128; k++) { local[k] = deg[base + k]; s += local[k]; }
    part[tid] = s;
    __syncthreads();
    // Hillis-Steele inclusive scan over 256 partials
    for (int off = 1; off < 256; off <<= 1) {
        int v = (tid >= off) ? part[tid - off] : 0;
        __syncthreads();
        part[tid] += v;
        __syncthreads();
    }
    int run = (tid == 0) ? 0 : part[tid - 1];
    #pragma unroll 4
    for (int k = 0; k < 128; k++) {
        rowptr[base + k] = run;
        cursor[base + k] = run;
        run += local[k];
    }
    if (tid == 255) rowptr[32768] = run;
}

__global__ __launch_bounds__(256) void csr_fill(const int* __restrict__ ei,
        int* __restrict__ cursor, int* __restrict__ csr_src) {
    int e = blockIdx.x * 256 + threadIdx.x;
    int t = ei[Ec + e];
    int slot = atomicAdd(cursor + t, 1);
    csr_src[slot] = ei[e];
}

// ---------------- fused GATv2: wave-per-node, online softmax, no atomics ----------------
__global__ __launch_bounds__(256) void gat_agg(const float* __restrict__ xlxr,
        const int* __restrict__ rowptr, const int* __restrict__ csr_src,
        const float* __restrict__ att, float* __restrict__ gout) {
    int wid = (blockIdx.x * 256 + threadIdx.x) >> 6;   // node id
    int lane = threadIdx.x & 63;
    long nb = (long)wid * 256;
    float a0 = att[lane], a1 = att[64 + lane];
    float xr0 = xlxr[nb + 128 + lane], xr1 = xlxr[nb + 192 + lane];
    // self-loop initializes the online softmax
    float xs0 = xlxr[nb + lane], xs1 = xlxr[nb + 64 + lane];
    float m0 = xs0 + xr0; m0 = (m0 >= 0.f) ? m0 : 0.2f * m0; m0 *= a0;
    float m1 = xs1 + xr1; m1 = (m1 >= 0.f) ? m1 : 0.2f * m1; m1 *= a1;
    #pragma unroll
    for (int off = 32; off; off >>= 1) { m0 += __shfl_xor(m0, off); m1 += __shfl_xor(m1, off); }
    float M0 = m0, M1 = m1;
    float den0 = 1.f, den1 = 1.f;
    float acc0 = xs0, acc1 = xs1;
    int beg = rowptr[wid], end = rowptr[wid + 1];
    for (int i = beg; i < end; i++) {
        int s = csr_src[i];
        long sb = (long)s * 256;
        float xl0 = xlxr[sb + lane], xl1 = xlxr[sb + 64 + lane];
        float t0 = xl0 + xr0; t0 = (t0 >= 0.f) ? t0 : 0.2f * t0; t0 *= a0;
        float t1 = xl1 + xr1; t1 = (t1 >= 0.f) ? t1 : 0.2f * t1; t1 *= a1;
        #pragma unroll
        for (int off = 32; off; off >>= 1) { t0 += __shfl_xor(t0, off); t1 += __shfl_xor(t1, off); }
        float nm0 = fmaxf(M0, t0);
        float sc0 = __expf(M0 - nm0), p0 = __expf(t0 - nm0);
        den0 = fmaf(den0, sc0, p0);
        acc0 = fmaf(acc0, sc0, p0 * xl0);
        M0 = nm0;
        float nm1 = fmaxf(M1, t1);
        float sc1 = __expf(M1 - nm1), p1 = __expf(t1 - nm1);
        den1 = fmaf(den1, sc1, p1);
        acc1 = fmaf(acc1, sc1, p1 * xl1);
        M1 = nm1;
    }
    gout[(long)wid * 128 + lane]      = acc0 / den0;
    gout[(long)wid * 128 + 64 + lane] = acc1 / den1;
}

// ---------------- bn over [N,128] (axis 0) ----------------
__global__ __launch_bounds__(256) void bn_stats(const float* __restrict__ X,
        float* __restrict__ sum, float* __restrict__ sq) {
    int f = threadIdx.x & 127, sub = threadIdx.x >> 7;
    int r0 = blockIdx.x * 256;
    float s = 0.f, q = 0.f;
    for (int r = r0 + sub; r < r0 + 256; r += 2) {
        float v = X[(long)r * 128 + f];
        s += v; q = fmaf(v, v, q);
    }
    __shared__ float ls[256], lq[256];
    ls[threadIdx.x] = s; lq[threadIdx.x] = q;
    __syncthreads();
    if (threadIdx.x < 128) {
        s = ls[threadIdx.x] + ls[threadIdx.x + 128];
        q = lq[threadIdx.x] + lq[threadIdx.x + 128];
        unsafeAtomicAdd(sum + f, s);
        unsafeAtomicAdd(sq + f, q);
    }
}

__global__ void stats_final(const float* __restrict__ sum, const float* __restrict__ sq,
        const float* __restrict__ g, const float* __restrict__ bta,
        float* __restrict__ scale, float* __restrict__ shift) {
    int f = threadIdx.x;
    float mu = sum[f] * (1.f / 32768.f);
    float var = sq[f] * (1.f / 32768.f) - mu * mu;
    float rs = rsqrtf(var + 1e-5f);
    float sc = rs * g[f];
    scale[f] = sc;
    shift[f] = bta[f] - mu * sc;
}

// out[i] = res[i] + relu(X[i]*scale[f] + shift[f]),  f = i % 128
__global__ __launch_bounds__(256) void bn_res(const float* __restrict__ X,
        const float* __restrict__ res, const float* __restrict__ scale,
        const float* __restrict__ shift, float* __restrict__ out) {
    int idx = blockIdx.x * 256 + threadIdx.x;   // float4 index, 1048576 total
    int f4 = idx & 31;
    float4 v = ((const float4*)X)[idx];
    float4 sc = ((const float4*)scale)[f4];
    float4 sh = ((const float4*)shift)[f4];
    float4 r = ((const float4*)res)[idx];
    float4 o;
    o.x = r.x + fmaxf(fmaf(v.x, sc.x, sh.x), 0.f);
    o.y = r.y + fmaxf(fmaf(v.y, sc.y, sh.y), 0.f);
    o.z = r.z + fmaxf(fmaf(v.z, sc.z, sh.z), 0.f);
    o.w = r.w + fmaxf(fmaf(v.w, sc.w, sh.w), 0.f);
    ((float4*)out)[idx] = o;
}

extern "C" void kernel_launch(void* const* d_in, const int* in_sizes, int n_in,
                              void* d_out, int out_size, void* d_ws, size_t ws_size,
                              hipStream_t stream) {
    const float* x   = (const float*)d_in[0];
    const int*   ei  = (const int*)d_in[1];
    const float* g0  = (const float*)d_in[2];
    const float* b0  = (const float*)d_in[3];
    const float* cw  = (const float*)d_in[4];
    const float* cb  = (const float*)d_in[5];
    const float* wl  = (const float*)d_in[6];
    const float* wr  = (const float*)d_in[7];
    const float* att = (const float*)d_in[8];
    // d_in[9] = gat_bias: cancels exactly inside the following bn2d -> unused
    const float* g1  = (const float*)d_in[10];
    const float* b1  = (const float*)d_in[11];
    const float* chw = (const float*)d_in[12];
    // d_in[13] = cheb_b: cancels inside the following bn2d -> unused
    float* out = (float*)d_out;

    float* ws   = (float*)d_ws;
    float* xbn  = ws + O_XBN;
    float* res  = ws + O_RES;
    float* xlxr = ws + O_XLXR;
    float* z    = ws + O_XLXR;     // alias: xl/xr dead before cheb gemm
    float* gout = ws + O_GOUT;
    float* h2   = ws + O_H2;
    float* st   = ws + O_STAT;
    int*   ip   = (int*)(ws + O_INT);
    int* deg = ip + I_DEG, *rowptr = ip + I_RP, *cursor = ip + I_CUR, *csr_src = ip + I_SRC;
    float *scale0 = st, *shift0 = st + 64;
    float *sum1 = st + 128, *sq1 = st + 256, *scale1 = st + 384, *shift1 = st + 512;
    float *sum2 = st + 640, *sq2 = st + 768, *scale2 = st + 896, *shift2 = st + 1024;

    hipMemsetAsync(deg, 0, (size_t)32768 * 4, stream);
    hipMemsetAsync(st,  0, (size_t)2048 * 4, stream);

    // CSR build (independent of feature pipeline)
    deg_count<<<2048, 256, 0, stream>>>(ei, deg);
    scan_deg<<<1, 256, 0, stream>>>(deg, rowptr, cursor);
    csr_fill<<<2048, 256, 0, stream>>>(ei, cursor, csr_src);

    // 1. bn0
    bn0_stats<<<64, 256, 0, stream>>>(x, g0, b0, scale0, shift0);
    bn0_apply<<<2048, 256, 0, stream>>>(x, scale0, shift0, xbn);
    // 2. conv1d + relu -> residual
    conv_relu<<<dim3(8, 4, 32), 256, 0, stream>>>(xbn, cw, cb, res);
    // 3. xl | xr = h @ [wl|wr]^T   (h = xbn viewed [32768,64])
    gemm_nt<<<dim3(512, 4), 256, 0, stream>>>(xbn, wl, wr, xlxr, 64, 256);
    // 4. fused GATv2 (wave-per-node online softmax)
    gat_agg<<<8192, 256, 0, stream>>>(xlxr, rowptr, csr_src, att, gout);
    // 5. bn1 + relu + residual -> h2
    bn_stats<<<128, 256, 0, stream>>>(gout, sum1, sq1);
    stats_final<<<1, 128, 0, stream>>>(sum1, sq1, g1, b1, scale1, shift1);
    bn_res<<<4096, 256, 0, stream>>>(gout, res, scale1, shift1, h2);
    // 6. cheb linear
    gemm_nt<<<dim3(512, 2), 256, 0, stream>>>(h2, chw, chw, z, 128, 128);
    // 7. bn1 again + relu + residual -> out
    bn_stats<<<128, 256, 0, stream>>>(z, sum2, sq2);
    stats_final<<<1, 128, 0, stream>>>(sum2, sq2, g1, b1, scale2, shift2);
    bn_res<<<4096, 256, 0, stream>>>(z, res, scale2, shift2, out);
}

// Round 3
// 460.971 us; speedup vs baseline: 1.5248x; 1.0790x over previous
//
#include <hip/hip_runtime.h>

#define DEVINL __device__ __forceinline__

constexpr int Bc = 32, Cc = 64, Tc = 1024, DIM2c = 128;
constexpr int Nn = Bc * Tc;            // 32768 nodes
constexpr int Ec = 524288;             // edges (self-loops handled in-kernel)

// workspace layout (float offsets)
constexpr long O_RES  = 0;             // 4194304
constexpr long O_XLXR = 4194304;       // 8388608 ([n][0..127]=xl, [128..255]=xr); z aliases
constexpr long O_GOUT = 12582912;      // 4194304
constexpr long O_H2   = 16777216;      // 4194304
constexpr long O_XLP  = 20971520;      // 2097152 (uint bf16-pairs [N][64])
constexpr long O_STAT = 23068672;      // 1024 (zeroed)
// ints directly after STAT (so one memset covers STAT+deg)
constexpr long I_DEG  = 0;             // 32768 (zeroed)
constexpr long I_RP   = 32768;         // 32769
constexpr long I_CUR  = 65540;         // 32768
constexpr long I_SRC  = 98308;         // 524288

DEVINL float unpack_lo(unsigned v) { return __uint_as_float(v << 16); }
DEVINL float unpack_hi(unsigned v) { return __uint_as_float(v & 0xffff0000u); }

// ---------------- bn0 sums: per-channel over [B,C,T] axis (0,2) ----------------
__global__ __launch_bounds__(256) void bn0_sums(const float* __restrict__ x,
        float* __restrict__ sum0, float* __restrict__ sq0) {
    int c = blockIdx.x & 63, q = blockIdx.x >> 6;      // q: 8 batches each
    const float4* base = (const float4*)(x + (long)q * 8 * 65536 + (long)c * 1024);
    float s = 0.f, qq = 0.f;
    for (int i = threadIdx.x; i < 2048; i += 256) {
        int b = i >> 8, t4 = i & 255;
        float4 v = base[b * 16384 + t4];
        s += v.x + v.y + v.z + v.w;
        qq = fmaf(v.x, v.x, qq); qq = fmaf(v.y, v.y, qq);
        qq = fmaf(v.z, v.z, qq); qq = fmaf(v.w, v.w, qq);
    }
    for (int off = 32; off; off >>= 1) { s += __shfl_down(s, off); qq += __shfl_down(qq, off); }
    __shared__ float ls[4], lq[4];
    int w = threadIdx.x >> 6, lane = threadIdx.x & 63;
    if (lane == 0) { ls[w] = s; lq[w] = qq; }
    __syncthreads();
    if (threadIdx.x == 0) {
        unsafeAtomicAdd(sum0 + c, ls[0] + ls[1] + ls[2] + ls[3]);
        unsafeAtomicAdd(sq0 + c, lq[0] + lq[1] + lq[2] + lq[3]);
    }
}

// ---------------- conv1d K=9 SAME + bias + relu (bn0 fused on load) ----------------
__global__ __launch_bounds__(256) void conv_relu(const float* __restrict__ x,
        const float* __restrict__ sum0, const float* __restrict__ sq0,
        const float* __restrict__ g0, const float* __restrict__ b0,
        const float* __restrict__ w, const float* __restrict__ bias,
        float* __restrict__ res) {
    __shared__ float xs[64][136];
    __shared__ float scs[64], shs[64];
    if (threadIdx.x < 64) {
        int c = threadIdx.x;
        float mu = sum0[c] * (1.f / 32768.f);
        float var = sq0[c] * (1.f / 32768.f) - mu * mu;
        float rs = rsqrtf(var + 1e-5f);
        float sc = rs * g0[c];
        scs[c] = sc; shs[c] = b0[c] - mu * sc;
    }
    __syncthreads();
    int t0  = blockIdx.x * 128;
    int co0 = blockIdx.y * 32;
    int b   = blockIdx.z;
    const float* xb = x + (long)b * (Cc * Tc);
    for (int i = threadIdx.x; i < 64 * 136; i += 256) {
        int ci = i / 136, tl = i - ci * 136;
        int t = t0 + tl - 4;
        xs[ci][tl] = ((unsigned)t < 1024u) ? fmaf(xb[ci * Tc + t], scs[ci], shs[ci]) : 0.f;
    }
    __syncthreads();
    int tg = threadIdx.x & 15;
    int cp = threadIdx.x >> 4;
    int coA = co0 + cp * 2;
    float accA[8], accB[8];
    float bA = bias[coA], bB = bias[coA + 1];
    #pragma unroll
    for (int j = 0; j < 8; j++) { accA[j] = bA; accB[j] = bB; }
    const float* wA = w + coA * 576;
    const float* wB = wA + 576;
    for (int ci = 0; ci < 64; ci++) {
        float xw[16];
        const float4* xp = (const float4*)&xs[ci][tg * 8];
        float4 x0 = xp[0], x1 = xp[1], x2 = xp[2], x3 = xp[3];
        xw[0]=x0.x; xw[1]=x0.y; xw[2]=x0.z; xw[3]=x0.w;
        xw[4]=x1.x; xw[5]=x1.y; xw[6]=x1.z; xw[7]=x1.w;
        xw[8]=x2.x; xw[9]=x2.y; xw[10]=x2.z; xw[11]=x2.w;
        xw[12]=x3.x; xw[13]=x3.y; xw[14]=x3.z; xw[15]=x3.w;
        #pragma unroll
        for (int k = 0; k < 9; k++) {
            float wa = wA[ci * 9 + k], wb = wB[ci * 9 + k];
            #pragma unroll
            for (int j = 0; j < 8; j++) {
                accA[j] = fmaf(xw[j + k], wa, accA[j]);
                accB[j] = fmaf(xw[j + k], wb, accB[j]);
            }
        }
    }
    int tbase = t0 + tg * 8;
    float* oA = res + (long)b * (DIM2c * Tc) + coA * Tc + tbase;
    float* oB = oA + Tc;
    float4 sa0, sa1, sb0, sb1;
    sa0.x=fmaxf(accA[0],0.f); sa0.y=fmaxf(accA[1],0.f); sa0.z=fmaxf(accA[2],0.f); sa0.w=fmaxf(accA[3],0.f);
    sa1.x=fmaxf(accA[4],0.f); sa1.y=fmaxf(accA[5],0.f); sa1.z=fmaxf(accA[6],0.f); sa1.w=fmaxf(accA[7],0.f);
    sb0.x=fmaxf(accB[0],0.f); sb0.y=fmaxf(accB[1],0.f); sb0.z=fmaxf(accB[2],0.f); sb0.w=fmaxf(accB[3],0.f);
    sb1.x=fmaxf(accB[4],0.f); sb1.y=fmaxf(accB[5],0.f); sb1.z=fmaxf(accB[6],0.f); sb1.w=fmaxf(accB[7],0.f);
    ((float4*)oA)[0] = sa0; ((float4*)oA)[1] = sa1;
    ((float4*)oB)[0] = sb0; ((float4*)oB)[1] = sb1;
}

// ---------------- GEMM: Y[m][j] = sum_c A'[m][c] * Wrow(j)[c]; optional bn0 on A ----------------
__global__ __launch_bounds__(256) void gemm_nt(const float* __restrict__ A,
        const float* __restrict__ W0, const float* __restrict__ W1,
        float* __restrict__ Y, int K, int ldY,
        const float* __restrict__ sum0, const float* __restrict__ sq0,
        const float* __restrict__ g0, const float* __restrict__ b0) {
    __shared__ float As[64][68];
    __shared__ float Bs[64][68];
    __shared__ float scs[64], shs[64];
    int tid = threadIdx.x;
    bool bn = (sum0 != nullptr);
    if (bn) {
        if (tid < 64) {
            float mu = sum0[tid] * (1.f / 32768.f);
            float var = sq0[tid] * (1.f / 32768.f) - mu * mu;
            float rs = rsqrtf(var + 1e-5f);
            float sc = rs * g0[tid];
            scs[tid] = sc; shs[tid] = b0[tid] - mu * sc;
        }
        __syncthreads();
    }
    int row0 = blockIdx.x * 64, j0 = blockIdx.y * 64;
    int tx = tid & 15, ty = tid >> 4;
    float acc[4][4] = {};
    for (int kt = 0; kt < K; kt += 64) {
        for (int i = tid; i < 4096; i += 256) {
            int c = i & 63, r = i >> 6;
            long idxf = (long)(row0 + r) * K + kt + c;
            float v = A[idxf];
            if (bn) {
                int ch = (int)((idxf >> 10) & 63);
                v = fmaf(v, scs[ch], shs[ch]);
            }
            As[c][r] = v;
        }
        for (int i = tid; i < 4096; i += 256) {
            int c = i & 63, jl = i >> 6;
            int jg = j0 + jl;
            const float* Wr = (jg < 128) ? (W0 + (long)jg * K) : (W1 + (long)(jg - 128) * K);
            Bs[c][jl] = Wr[kt + c];
        }
        __syncthreads();
        #pragma unroll 4
        for (int c = 0; c < 64; c++) {
            float4 a = *(const float4*)&As[c][ty * 4];
            float4 b = *(const float4*)&Bs[c][tx * 4];
            float av[4] = {a.x, a.y, a.z, a.w};
            float bv[4] = {b.x, b.y, b.z, b.w};
            #pragma unroll
            for (int i = 0; i < 4; i++)
                #pragma unroll
                for (int j = 0; j < 4; j++)
                    acc[i][j] = fmaf(av[i], bv[j], acc[i][j]);
        }
        __syncthreads();
    }
    #pragma unroll
    for (int i = 0; i < 4; i++) {
        long r = row0 + ty * 4 + i;
        float4 v; v.x = acc[i][0]; v.y = acc[i][1]; v.z = acc[i][2]; v.w = acc[i][3];
        *(float4*)&Y[r * ldY + j0 + tx * 4] = v;
    }
}

// ---------------- pack xl to bf16 head-pairs: xlp[n*64+d] = (bf16(xl1),bf16(xl0)) ----------------
__global__ __launch_bounds__(256) void pack_xl(const float* __restrict__ xlxr,
        unsigned* __restrict__ xlp) {
    int i = blockIdx.x * 256 + threadIdx.x;   // 2097152 total
    int n = i >> 6, d = i & 63;
    unsigned h0 = __float_as_uint(xlxr[(long)n * 256 + d]);
    unsigned h1 = __float_as_uint(xlxr[(long)n * 256 + 64 + d]);
    xlp[i] = ((h1 + 0x8000u) & 0xffff0000u) | ((h0 + 0x8000u) >> 16);
}

// ---------------- CSR build (by destination) ----------------
__global__ __launch_bounds__(256) void deg_count(const int* __restrict__ ei,
        int* __restrict__ deg) {
    int e = blockIdx.x * 256 + threadIdx.x;
    atomicAdd(deg + ei[Ec + e], 1);
}

__global__ __launch_bounds__(256) void scan_deg(const int* __restrict__ deg,
        int* __restrict__ rowptr, int* __restrict__ cursor) {
    __shared__ int part[256];
    int tid = threadIdx.x;
    int base = tid * 128;
    int s = 0;
    int local[128];
    #pragma unroll 4
    for (int k = 0; k < 128; k++) { local[k] = deg[base + k]; s += local[k]; }
    part[tid] = s;
    __syncthreads();
    for (int off = 1; off < 256; off <<= 1) {
        int v = (tid >= off) ? part[tid - off] : 0;
        __syncthreads();
        part[tid] += v;
        __syncthreads();
    }
    int run = (tid == 0) ? 0 : part[tid - 1];
    #pragma unroll 4
    for (int k = 0; k < 128; k++) {
        rowptr[base + k] = run;
        cursor[base + k] = run;
        run += local[k];
    }
    if (tid == 255) rowptr[32768] = run;
}

__global__ __launch_bounds__(256) void csr_fill(const int* __restrict__ ei,
        int* __restrict__ cursor, int* __restrict__ csr_src) {
    int e = blockIdx.x * 256 + threadIdx.x;
    int t = ei[Ec + e];
    int slot = atomicAdd(cursor + t, 1);
    csr_src[slot] = ei[e];
}

// ---------------- fused GATv2: wave-per-node, no max (logits bounded), bf16 gathers ----------------
__global__ __launch_bounds__(256) void gat_agg(const float* __restrict__ xlxr,
        const unsigned* __restrict__ xlp,
        const int* __restrict__ rowptr, const int* __restrict__ csr_src,
        const float* __restrict__ att, float* __restrict__ gout) {
    int wid = (blockIdx.x * 256 + threadIdx.x) >> 6;   // node id
    int lane = threadIdx.x & 63;
    long nb = (long)wid * 256;
    float a0 = att[lane], a1 = att[64 + lane];
    float xr0 = xlxr[nb + 128 + lane], xr1 = xlxr[nb + 192 + lane];
    // self-loop term
    unsigned vs = xlp[(long)wid * 64 + lane];
    float xs0 = unpack_lo(vs), xs1 = unpack_hi(vs);
    float t0 = xs0 + xr0; t0 = fmaxf(t0, 0.2f * t0) * a0;
    float t1 = xs1 + xr1; t1 = fmaxf(t1, 0.2f * t1) * a1;
    t0 += __shfl_xor(t0, 32); t1 += __shfl_xor(t1, 32);
    float wv = (lane < 32) ? t0 : t1;
    #pragma unroll
    for (int off = 16; off; off >>= 1) wv += __shfl_xor(wv, off);
    float p0 = __expf(__shfl(wv, 0)), p1 = __expf(__shfl(wv, 32));
    float den0 = p0, den1 = p1;
    float acc0 = p0 * xs0, acc1 = p1 * xs1;
    int beg = rowptr[wid], end = rowptr[wid + 1];
    #pragma unroll 2
    for (int i = beg; i < end; i++) {
        int s = csr_src[i];
        unsigned v = xlp[(long)s * 64 + lane];
        float xl0 = unpack_lo(v), xl1 = unpack_hi(v);
        float u0 = xl0 + xr0; u0 = fmaxf(u0, 0.2f * u0) * a0;
        float u1 = xl1 + xr1; u1 = fmaxf(u1, 0.2f * u1) * a1;
        u0 += __shfl_xor(u0, 32); u1 += __shfl_xor(u1, 32);
        float w2 = (lane < 32) ? u0 : u1;
        #pragma unroll
        for (int off = 16; off; off >>= 1) w2 += __shfl_xor(w2, off);
        float e0 = __expf(__shfl(w2, 0)), e1 = __expf(__shfl(w2, 32));
        den0 += e0; den1 += e1;
        acc0 = fmaf(e0, xl0, acc0);
        acc1 = fmaf(e1, xl1, acc1);
    }
    float i0 = __builtin_amdgcn_rcpf(den0), i1 = __builtin_amdgcn_rcpf(den1);
    gout[(long)wid * 128 + lane]      = acc0 * i0;
    gout[(long)wid * 128 + 64 + lane] = acc1 * i1;
}

// ---------------- bn over [N,128] (axis 0) ----------------
__global__ __launch_bounds__(256) void bn_stats(const float* __restrict__ X,
        float* __restrict__ sum, float* __restrict__ sq) {
    int f = threadIdx.x & 127, sub = threadIdx.x >> 7;
    int r0 = blockIdx.x * 256;
    float s = 0.f, q = 0.f;
    for (int r = r0 + sub; r < r0 + 256; r += 2) {
        float v = X[(long)r * 128 + f];
        s += v; q = fmaf(v, v, q);
    }
    __shared__ float ls[256], lq[256];
    ls[threadIdx.x] = s; lq[threadIdx.x] = q;
    __syncthreads();
    if (threadIdx.x < 128) {
        s = ls[threadIdx.x] + ls[threadIdx.x + 128];
        q = lq[threadIdx.x] + lq[threadIdx.x + 128];
        unsafeAtomicAdd(sum + f, s);
        unsafeAtomicAdd(sq + f, q);
    }
}

// out[i] = res[i] + relu(X[i]*scale[f] + shift[f]); scale/shift computed from sums in-block
__global__ __launch_bounds__(256) void bn_res(const float* __restrict__ X,
        const float* __restrict__ res, const float* __restrict__ sum,
        const float* __restrict__ sq, const float* __restrict__ g,
        const float* __restrict__ bta, float* __restrict__ out) {
    __shared__ float scs[128], shs[128];
    int tid = threadIdx.x;
    if (tid < 128) {
        float mu = sum[tid] * (1.f / 32768.f);
        float var = sq[tid] * (1.f / 32768.f) - mu * mu;
        float rs = rsqrtf(var + 1e-5f);
        float sc = rs * g[tid];
        scs[tid] = sc; shs[tid] = bta[tid] - mu * sc;
    }
    __syncthreads();
    int idx = blockIdx.x * 256 + tid;
    int f0 = (idx & 31) * 4;
    float4 v = ((const float4*)X)[idx];
    float4 r = ((const float4*)res)[idx];
    float4 o;
    o.x = r.x + fmaxf(fmaf(v.x, scs[f0],     shs[f0]),     0.f);
    o.y = r.y + fmaxf(fmaf(v.y, scs[f0 + 1], shs[f0 + 1]), 0.f);
    o.z = r.z + fmaxf(fmaf(v.z, scs[f0 + 2], shs[f0 + 2]), 0.f);
    o.w = r.w + fmaxf(fmaf(v.w, scs[f0 + 3], shs[f0 + 3]), 0.f);
    ((float4*)out)[idx] = o;
}

extern "C" void kernel_launch(void* const* d_in, const int* in_sizes, int n_in,
                              void* d_out, int out_size, void* d_ws, size_t ws_size,
                              hipStream_t stream) {
    const float* x   = (const float*)d_in[0];
    const int*   ei  = (const int*)d_in[1];
    const float* g0  = (const float*)d_in[2];
    const float* b0  = (const float*)d_in[3];
    const float* cw  = (const float*)d_in[4];
    const float* cb  = (const float*)d_in[5];
    const float* wl  = (const float*)d_in[6];
    const float* wr  = (const float*)d_in[7];
    const float* att = (const float*)d_in[8];
    // d_in[9] = gat_bias: cancels exactly inside the following bn2d -> unused
    const float* g1  = (const float*)d_in[10];
    const float* b1  = (const float*)d_in[11];
    const float* chw = (const float*)d_in[12];
    // d_in[13] = cheb_b: cancels inside the following bn2d -> unused
    float* out = (float*)d_out;

    float* ws = (float*)d_ws;
    float*    res  = ws + O_RES;
    float*    xlxr = ws + O_XLXR;
    float*    z    = ws + O_XLXR;     // alias: xlxr dead before cheb gemm
    float*    gout = ws + O_GOUT;
    float*    h2   = ws + O_H2;
    unsigned* xlp  = (unsigned*)(ws + O_XLP);
    float*    st   = ws + O_STAT;
    int*      ip   = (int*)(ws + O_STAT + 1024);
    int *deg = ip + I_DEG, *rowptr = ip + I_RP, *cursor = ip + I_CUR, *csr_src = ip + I_SRC;
    float *sum0 = st,       *sq0 = st + 64;
    float *sum1 = st + 128, *sq1 = st + 256;
    float *sum2 = st + 384, *sq2 = st + 512;

    // one memset covers stat block (4KB) + deg (128KB), contiguous
    hipMemsetAsync(st, 0, (size_t)(1024 + 32768) * 4, stream);

    // CSR build
    deg_count<<<2048, 256, 0, stream>>>(ei, deg);
    scan_deg<<<1, 256, 0, stream>>>(deg, rowptr, cursor);
    csr_fill<<<2048, 256, 0, stream>>>(ei, cursor, csr_src);

    // bn0 (stats only; apply fused into consumers)
    bn0_sums<<<256, 256, 0, stream>>>(x, sum0, sq0);
    // conv1d + relu -> residual (bn0 fused)
    conv_relu<<<dim3(8, 4, 32), 256, 0, stream>>>(x, sum0, sq0, g0, b0, cw, cb, res);
    // xl|xr = bn0(h) @ [wl|wr]^T
    gemm_nt<<<dim3(512, 4), 256, 0, stream>>>(x, wl, wr, xlxr, 64, 256, sum0, sq0, g0, b0);
    // bf16 pack of xl
    pack_xl<<<8192, 256, 0, stream>>>(xlxr, xlp);
    // fused GATv2
    gat_agg<<<8192, 256, 0, stream>>>(xlxr, xlp, rowptr, csr_src, att, gout);
    // bn1 + relu + residual -> h2
    bn_stats<<<128, 256, 0, stream>>>(gout, sum1, sq1);
    bn_res<<<4096, 256, 0, stream>>>(gout, res, sum1, sq1, g1, b1, h2);
    // cheb linear
    gemm_nt<<<dim3(512, 2), 256, 0, stream>>>(h2, chw, chw, z, 128, 128,
                                              nullptr, nullptr, nullptr, nullptr);
    // bn1 again + relu + residual -> out
    bn_stats<<<128, 256, 0, stream>>>(z, sum2, sq2);
    bn_res<<<4096, 256, 0, stream>>>(z, res, sum2, sq2, g1, b1, out);
}

// Round 4
// 423.699 us; speedup vs baseline: 1.6589x; 1.0880x over previous
//
#include <hip/hip_runtime.h>

#define DEVINL __device__ __forceinline__

constexpr int Bc = 32, Cc = 64, Tc = 1024, DIM2c = 128;
constexpr int Nn = Bc * Tc;            // 32768 nodes
constexpr int Ec = 524288;             // edges (self-loops handled in-kernel)

// workspace layout (float offsets)
constexpr long O_RES  = 0;             // 4194304
constexpr long O_XLXR = 4194304;       // 8388608 ([n][0..127]=xl, [128..255]=xr); z aliases
constexpr long O_GOUT = 12582912;      // 4194304
constexpr long O_H2   = 16777216;      // 4194304 ; bucket (2097152 ints) aliases front half
constexpr long O_XLP  = 20971520;      // 2097152 (uint bf16-pairs [N][64])
constexpr long O_STAT = 23068672;      // 1024 (zeroed)
constexpr long O_CUR  = 23069696;      // 32768 ints (zeroed, contiguous with STAT)
constexpr long O_WPAD = 23102464;      // 98304 (conv weights padded [co][ci][12])

DEVINL float unpack_lo(unsigned v) { return __uint_as_float(v << 16); }
DEVINL float unpack_hi(unsigned v) { return __uint_as_float(v & 0xffff0000u); }

// ---------------- bn0 sums: per-channel over [B,C,T] axis (0,2) ----------------
__global__ __launch_bounds__(256) void bn0_sums(const float* __restrict__ x,
        float* __restrict__ sum0, float* __restrict__ sq0) {
    int c = blockIdx.x & 63, q = blockIdx.x >> 6;      // q: 8 batches each
    const float4* base = (const float4*)(x + (long)q * 8 * 65536 + (long)c * 1024);
    float s = 0.f, qq = 0.f;
    for (int i = threadIdx.x; i < 2048; i += 256) {
        int b = i >> 8, t4 = i & 255;
        float4 v = base[b * 16384 + t4];
        s += v.x + v.y + v.z + v.w;
        qq = fmaf(v.x, v.x, qq); qq = fmaf(v.y, v.y, qq);
        qq = fmaf(v.z, v.z, qq); qq = fmaf(v.w, v.w, qq);
    }
    for (int off = 32; off; off >>= 1) { s += __shfl_down(s, off); qq += __shfl_down(qq, off); }
    __shared__ float ls[4], lq[4];
    int w = threadIdx.x >> 6, lane = threadIdx.x & 63;
    if (lane == 0) { ls[w] = s; lq[w] = qq; }
    __syncthreads();
    if (threadIdx.x == 0) {
        unsafeAtomicAdd(sum0 + c, ls[0] + ls[1] + ls[2] + ls[3]);
        unsafeAtomicAdd(sq0 + c, lq[0] + lq[1] + lq[2] + lq[3]);
    }
}

// ---------------- pad conv weights to [co][ci][12] for aligned float4 taps ----------------
__global__ __launch_bounds__(256) void wpad_prep(const float* __restrict__ w,
        float* __restrict__ wpad) {
    int i = blockIdx.x * 256 + threadIdx.x;    // 8192 = co*64+ci
    const float* src = w + (long)i * 9;
    float* dst = wpad + (long)i * 12;
    #pragma unroll
    for (int k = 0; k < 9; k++) dst[k] = src[k];
    dst[9] = 0.f; dst[10] = 0.f; dst[11] = 0.f;
}

// ---------------- conv1d K=9 SAME + bias + relu (bn0 fused on load) ----------------
// grid (16 t-tiles of 64, 2 co-tiles of 64, 32 b); lane: 4 t x 4 co
__global__ __launch_bounds__(256) void conv_relu(const float* __restrict__ x,
        const float* __restrict__ sum0, const float* __restrict__ sq0,
        const float* __restrict__ g0, const float* __restrict__ b0,
        const float* __restrict__ wpad, const float* __restrict__ bias,
        float* __restrict__ res) {
    __shared__ float xs[64][72];               // [ci][t0-4 .. t0+67]
    __shared__ float scs[64], shs[64];
    int tid = threadIdx.x;
    if (tid < 64) {
        float mu = sum0[tid] * (1.f / 32768.f);
        float var = sq0[tid] * (1.f / 32768.f) - mu * mu;
        float rs = rsqrtf(var + 1e-5f);
        float sc = rs * g0[tid];
        scs[tid] = sc; shs[tid] = b0[tid] - mu * sc;
    }
    __syncthreads();
    int t0  = blockIdx.x * 64;
    int co0 = blockIdx.y * 64;
    int b   = blockIdx.z;
    const float* xb = x + (long)b * (Cc * Tc);
    for (int i = tid; i < 64 * 72; i += 256) {
        int ci = (int)(((unsigned)i * 7282u) >> 19);   // i/72 exact for i<4608
        int tl = i - ci * 72;
        int t = t0 + tl - 4;
        xs[ci][tl] = ((unsigned)t < 1024u) ? fmaf(xb[ci * Tc + t], scs[ci], shs[ci]) : 0.f;
    }
    __syncthreads();
    int tg = tid & 15;                  // 4 t-outputs at t0 + tg*4
    int cp = tid >> 4;                  // 16 groups x 4 co
    int co = co0 + cp * 4;
    float acc[4][4];
    #pragma unroll
    for (int c4 = 0; c4 < 4; c4++) {
        float bb = bias[co + c4];
        #pragma unroll
        for (int j = 0; j < 4; j++) acc[c4][j] = bb;
    }
    for (int ci = 0; ci < 64; ci++) {
        float xw[12];
        const float4* xp = (const float4*)&xs[ci][tg * 4];
        float4 x0 = xp[0], x1 = xp[1], x2 = xp[2];
        xw[0]=x0.x; xw[1]=x0.y; xw[2]=x0.z; xw[3]=x0.w;
        xw[4]=x1.x; xw[5]=x1.y; xw[6]=x1.z; xw[7]=x1.w;
        xw[8]=x2.x; xw[9]=x2.y; xw[10]=x2.z; xw[11]=x2.w;
        #pragma unroll
        for (int c4 = 0; c4 < 4; c4++) {
            const float4* wp = (const float4*)(wpad + ((long)(co + c4) * 64 + ci) * 12);
            float4 w0 = wp[0], w1 = wp[1], w2 = wp[2];
            float wt[9] = {w0.x, w0.y, w0.z, w0.w, w1.x, w1.y, w1.z, w1.w, w2.x};
            #pragma unroll
            for (int k = 0; k < 9; k++) {
                #pragma unroll
                for (int j = 0; j < 4; j++)
                    acc[c4][j] = fmaf(xw[j + k], wt[k], acc[c4][j]);
            }
        }
    }
    int tbase = t0 + tg * 4;
    #pragma unroll
    for (int c4 = 0; c4 < 4; c4++) {
        float4 o;
        o.x = fmaxf(acc[c4][0], 0.f); o.y = fmaxf(acc[c4][1], 0.f);
        o.z = fmaxf(acc[c4][2], 0.f); o.w = fmaxf(acc[c4][3], 0.f);
        *(float4*)&res[(long)b * (DIM2c * Tc) + (long)(co + c4) * Tc + tbase] = o;
    }
}

// ---------------- GEMM: Y[m][j] = sum_c A'[m][c] * Wrow(j)[c]; optional bn0 on A ----------------
// optional epilogue: bf16-pack cols [0,128) into xlp pairs
__global__ __launch_bounds__(256) void gemm_nt(const float* __restrict__ A,
        const float* __restrict__ W0, const float* __restrict__ W1,
        float* __restrict__ Y, int K, int ldY,
        const float* __restrict__ sum0, const float* __restrict__ sq0,
        const float* __restrict__ g0, const float* __restrict__ b0,
        unsigned* __restrict__ xlp) {
    __shared__ float As[64][68];
    __shared__ float Bs[64][68];
    __shared__ float scs[64], shs[64];
    int tid = threadIdx.x;
    bool bn = (sum0 != nullptr);
    if (bn) {
        if (tid < 64) {
            float mu = sum0[tid] * (1.f / 32768.f);
            float var = sq0[tid] * (1.f / 32768.f) - mu * mu;
            float rs = rsqrtf(var + 1e-5f);
            float sc = rs * g0[tid];
            scs[tid] = sc; shs[tid] = b0[tid] - mu * sc;
        }
        __syncthreads();
    }
    int row0 = blockIdx.x * 64, j0 = blockIdx.y * 64;
    int tx = tid & 15, ty = tid >> 4;
    float acc[4][4] = {};
    for (int kt = 0; kt < K; kt += 64) {
        for (int i = tid; i < 4096; i += 256) {
            int c = i & 63, r = i >> 6;
            long idxf = (long)(row0 + r) * K + kt + c;
            float v = A[idxf];
            if (bn) {
                int ch = (int)((idxf >> 10) & 63);
                v = fmaf(v, scs[ch], shs[ch]);
            }
            As[c][r] = v;
        }
        for (int i = tid; i < 4096; i += 256) {
            int c = i & 63, jl = i >> 6;
            int jg = j0 + jl;
            const float* Wr = (jg < 128) ? (W0 + (long)jg * K) : (W1 + (long)(jg - 128) * K);
            Bs[c][jl] = Wr[kt + c];
        }
        __syncthreads();
        #pragma unroll 4
        for (int c = 0; c < 64; c++) {
            float4 a = *(const float4*)&As[c][ty * 4];
            float4 b = *(const float4*)&Bs[c][tx * 4];
            float av[4] = {a.x, a.y, a.z, a.w};
            float bv[4] = {b.x, b.y, b.z, b.w};
            #pragma unroll
            for (int i = 0; i < 4; i++)
                #pragma unroll
                for (int j = 0; j < 4; j++)
                    acc[i][j] = fmaf(av[i], bv[j], acc[i][j]);
        }
        __syncthreads();
    }
    bool pack = (xlp != nullptr) && (j0 < 128);    // uniform per block
    int hi = j0 >> 6;                              // 0: xl0 half, 1: xl1 half
    #pragma unroll
    for (int i = 0; i < 4; i++) {
        long r = row0 + ty * 4 + i;
        float4 v; v.x = acc[i][0]; v.y = acc[i][1]; v.z = acc[i][2]; v.w = acc[i][3];
        *(float4*)&Y[r * ldY + j0 + tx * 4] = v;
        if (pack) {
            unsigned short* xp = (unsigned short*)xlp;
            #pragma unroll
            for (int j = 0; j < 4; j++) {
                int d = (j0 + tx * 4 + j) & 63;
                unsigned u = __float_as_uint(acc[i][j]) + 0x8000u;
                xp[(r * 64 + d) * 2 + hi] = (unsigned short)(u >> 16);
            }
        }
    }
}

// ---------------- bucket CSR build (capacity 64; deg ~ Binom(E, 1/N), max << 64) ----------------
__global__ __launch_bounds__(256) void bucket_fill(const int* __restrict__ ei,
        int* __restrict__ cursor, int* __restrict__ bucket) {
    int e = blockIdx.x * 256 + threadIdx.x;
    int t = ei[Ec + e];
    int slot = atomicAdd(cursor + t, 1);
    bucket[t * 64 + slot] = ei[e];
}

// ---------------- fused GATv2: wave-per-node, no max (logits bounded), bf16 gathers ----------------
__global__ __launch_bounds__(256) void gat_agg(const float* __restrict__ xlxr,
        const unsigned* __restrict__ xlp,
        const int* __restrict__ cursor, const int* __restrict__ bucket,
        const float* __restrict__ att, float* __restrict__ gout) {
    int wid = (blockIdx.x * 256 + threadIdx.x) >> 6;   // node id
    int lane = threadIdx.x & 63;
    long nb = (long)wid * 256;
    float a0 = att[lane], a1 = att[64 + lane];
    float xr0 = xlxr[nb + 128 + lane], xr1 = xlxr[nb + 192 + lane];
    // self-loop term
    unsigned vs = xlp[(long)wid * 64 + lane];
    float xs0 = unpack_lo(vs), xs1 = unpack_hi(vs);
    float t0 = xs0 + xr0; t0 = fmaxf(t0, 0.2f * t0) * a0;
    float t1 = xs1 + xr1; t1 = fmaxf(t1, 0.2f * t1) * a1;
    t0 += __shfl_xor(t0, 32); t1 += __shfl_xor(t1, 32);
    float wv = (lane < 32) ? t0 : t1;
    #pragma unroll
    for (int off = 16; off; off >>= 1) wv += __shfl_xor(wv, off);
    float p0 = __expf(__shfl(wv, 0)), p1 = __expf(__shfl(wv, 32));
    float den0 = p0, den1 = p1;
    float acc0 = p0 * xs0, acc1 = p1 * xs1;
    int cnt = cursor[wid];
    const int* bk = bucket + wid * 64;
    #pragma unroll 2
    for (int i = 0; i < cnt; i++) {
        int s = bk[i];
        unsigned v = xlp[(long)s * 64 + lane];
        float xl0 = unpack_lo(v), xl1 = unpack_hi(v);
        float u0 = xl0 + xr0; u0 = fmaxf(u0, 0.2f * u0) * a0;
        float u1 = xl1 + xr1; u1 = fmaxf(u1, 0.2f * u1) * a1;
        u0 += __shfl_xor(u0, 32); u1 += __shfl_xor(u1, 32);
        float w2 = (lane < 32) ? u0 : u1;
        #pragma unroll
        for (int off = 16; off; off >>= 1) w2 += __shfl_xor(w2, off);
        float e0 = __expf(__shfl(w2, 0)), e1 = __expf(__shfl(w2, 32));
        den0 += e0; den1 += e1;
        acc0 = fmaf(e0, xl0, acc0);
        acc1 = fmaf(e1, xl1, acc1);
    }
    float i0 = __builtin_amdgcn_rcpf(den0), i1 = __builtin_amdgcn_rcpf(den1);
    gout[(long)wid * 128 + lane]      = acc0 * i0;
    gout[(long)wid * 128 + 64 + lane] = acc1 * i1;
}

// ---------------- bn over [N,128] (axis 0) ----------------
__global__ __launch_bounds__(256) void bn_stats(const float* __restrict__ X,
        float* __restrict__ sum, float* __restrict__ sq) {
    int f = threadIdx.x & 127, sub = threadIdx.x >> 7;
    int r0 = blockIdx.x * 256;
    float s = 0.f, q = 0.f;
    for (int r = r0 + sub; r < r0 + 256; r += 2) {
        float v = X[(long)r * 128 + f];
        s += v; q = fmaf(v, v, q);
    }
    __shared__ float ls[256], lq[256];
    ls[threadIdx.x] = s; lq[threadIdx.x] = q;
    __syncthreads();
    if (threadIdx.x < 128) {
        s = ls[threadIdx.x] + ls[threadIdx.x + 128];
        q = lq[threadIdx.x] + lq[threadIdx.x + 128];
        unsafeAtomicAdd(sum + f, s);
        unsafeAtomicAdd(sq + f, q);
    }
}

// out[i] = res[i] + relu(X[i]*scale[f] + shift[f]); scale/shift computed from sums in-block
__global__ __launch_bounds__(256) void bn_res(const float* __restrict__ X,
        const float* __restrict__ res, const float* __restrict__ sum,
        const float* __restrict__ sq, const float* __restrict__ g,
        const float* __restrict__ bta, float* __restrict__ out) {
    __shared__ float scs[128], shs[128];
    int tid = threadIdx.x;
    if (tid < 128) {
        float mu = sum[tid] * (1.f / 32768.f);
        float var = sq[tid] * (1.f / 32768.f) - mu * mu;
        float rs = rsqrtf(var + 1e-5f);
        float sc = rs * g[tid];
        scs[tid] = sc; shs[tid] = bta[tid] - mu * sc;
    }
    __syncthreads();
    int idx = blockIdx.x * 256 + tid;
    int f0 = (idx & 31) * 4;
    float4 v = ((const float4*)X)[idx];
    float4 r = ((const float4*)res)[idx];
    float4 o;
    o.x = r.x + fmaxf(fmaf(v.x, scs[f0],     shs[f0]),     0.f);
    o.y = r.y + fmaxf(fmaf(v.y, scs[f0 + 1], shs[f0 + 1]), 0.f);
    o.z = r.z + fmaxf(fmaf(v.z, scs[f0 + 2], shs[f0 + 2]), 0.f);
    o.w = r.w + fmaxf(fmaf(v.w, scs[f0 + 3], shs[f0 + 3]), 0.f);
    ((float4*)out)[idx] = o;
}

extern "C" void kernel_launch(void* const* d_in, const int* in_sizes, int n_in,
                              void* d_out, int out_size, void* d_ws, size_t ws_size,
                              hipStream_t stream) {
    const float* x   = (const float*)d_in[0];
    const int*   ei  = (const int*)d_in[1];
    const float* g0  = (const float*)d_in[2];
    const float* b0  = (const float*)d_in[3];
    const float* cw  = (const float*)d_in[4];
    const float* cb  = (const float*)d_in[5];
    const float* wl  = (const float*)d_in[6];
    const float* wr  = (const float*)d_in[7];
    const float* att = (const float*)d_in[8];
    // d_in[9] = gat_bias: cancels exactly inside the following bn2d -> unused
    const float* g1  = (const float*)d_in[10];
    const float* b1  = (const float*)d_in[11];
    const float* chw = (const float*)d_in[12];
    // d_in[13] = cheb_b: cancels inside the following bn2d -> unused
    float* out = (float*)d_out;

    float* ws = (float*)d_ws;
    float*    res  = ws + O_RES;
    float*    xlxr = ws + O_XLXR;
    float*    z    = ws + O_XLXR;     // alias: xlxr dead before cheb gemm
    float*    gout = ws + O_GOUT;
    float*    h2   = ws + O_H2;
    int*      bucket = (int*)(ws + O_H2);  // alias: dead before h2 written
    unsigned* xlp  = (unsigned*)(ws + O_XLP);
    float*    st   = ws + O_STAT;
    int*      cursor = (int*)(ws + O_CUR);
    float*    wpad = ws + O_WPAD;
    float *sum0 = st,       *sq0 = st + 64;
    float *sum1 = st + 128, *sq1 = st + 256;
    float *sum2 = st + 384, *sq2 = st + 512;

    // one memset covers stat block (4KB) + cursor (128KB), contiguous
    hipMemsetAsync(st, 0, (size_t)(1024 + 32768) * 4, stream);

    // conv weight padding + bucket CSR (independent of feature pipeline)
    wpad_prep<<<32, 256, 0, stream>>>(cw, wpad);
    bucket_fill<<<2048, 256, 0, stream>>>(ei, cursor, bucket);

    // bn0 (stats only; apply fused into consumers)
    bn0_sums<<<256, 256, 0, stream>>>(x, sum0, sq0);
    // conv1d + relu -> residual (bn0 fused)
    conv_relu<<<dim3(16, 2, 32), 256, 0, stream>>>(x, sum0, sq0, g0, b0, wpad, cb, res);
    // xl|xr = bn0(h) @ [wl|wr]^T, with fused bf16 pack of xl
    gemm_nt<<<dim3(512, 4), 256, 0, stream>>>(x, wl, wr, xlxr, 64, 256, sum0, sq0, g0, b0, xlp);
    // fused GATv2
    gat_agg<<<8192, 256, 0, stream>>>(xlxr, xlp, cursor, bucket, att, gout);
    // bn1 + relu + residual -> h2
    bn_stats<<<128, 256, 0, stream>>>(gout, sum1, sq1);
    bn_res<<<4096, 256, 0, stream>>>(gout, res, sum1, sq1, g1, b1, h2);
    // cheb linear
    gemm_nt<<<dim3(512, 2), 256, 0, stream>>>(h2, chw, chw, z, 128, 128,
                                              nullptr, nullptr, nullptr, nullptr, nullptr);
    // bn1 again + relu + residual -> out
    bn_stats<<<128, 256, 0, stream>>>(z, sum2, sq2);
    bn_res<<<4096, 256, 0, stream>>>(z, res, sum2, sq2, g1, b1, out);
}

// Round 5
// 342.552 us; speedup vs baseline: 2.0519x; 1.2369x over previous
//
#include <hip/hip_runtime.h>

#define DEVINL __device__ __forceinline__

constexpr int Bc = 32, Cc = 64, Tc = 1024, DIM2c = 128;
constexpr int Nn = Bc * Tc;            // 32768 nodes
constexpr int Ec = 524288;             // edges (self-loops handled in-kernel)

typedef __bf16 bf16x8 __attribute__((ext_vector_type(8)));
typedef float  f32x4  __attribute__((ext_vector_type(4)));

// workspace layout (float offsets)
constexpr long O_RES   = 0;            // 4194304 fp32
constexpr long O_GOUT  = 4194304;      // 4194304 fp32
constexpr long O_XT    = 8388608;      // 1048576 (bf16 x 2097152: [b*1024+t][ci])
constexpr long O_HBF   = 9437184;      // 1048576 (bf16 x 2097152: flat bn0(x))
constexpr long O_XLP   = 10485760;     // 2097152 uint (bf16 pairs [n][64])
constexpr long O_XRP   = 12582912;     // 2097152 uint
constexpr long O_H2BF  = 14680064;     // 2097152 (bf16 x 4194304: [n][128])
constexpr long O_Z     = 16777216;     // 4194304 fp32
constexpr long O_WCBF  = 20971520;     // 36864 (bf16 x 73728: [kk][co][ci])
constexpr long O_WLR   = 21008384;     // 8192  (bf16 x 16384: [j 256][c 64])
constexpr long O_CHB   = 21016576;     // 8192  (bf16 x 16384: [j 128][c 128])
constexpr long O_STAT  = 21024768;     // 1024 (zeroed)
constexpr long O_CUR   = 21025792;     // 32768 ints (zeroed, contiguous w/ STAT)
constexpr long O_BUCK  = 21058560;     // 2097152 ints

DEVINL float unpack_lo(unsigned v) { return __uint_as_float(v << 16); }
DEVINL float unpack_hi(unsigned v) { return __uint_as_float(v & 0xffff0000u); }
DEVINL unsigned bfb(float f) { return (__float_as_uint(f) + 0x8000u) >> 16; }
DEVINL unsigned pk2(float lo, float hi) {
    return ((__float_as_uint(hi) + 0x8000u) & 0xffff0000u) | bfb(lo);
}
DEVINL bf16x8 zero8() {
    bf16x8 v;
    #pragma unroll
    for (int i = 0; i < 8; i++) v[i] = (__bf16)0.f;
    return v;
}

// ---------------- bn0 sums: per-channel over [B,C,T] axis (0,2) ----------------
__global__ __launch_bounds__(256) void bn0_sums(const float* __restrict__ x,
        float* __restrict__ sum0, float* __restrict__ sq0) {
    int c = blockIdx.x & 63, q = blockIdx.x >> 6;
    const float4* base = (const float4*)(x + (long)q * 8 * 65536 + (long)c * 1024);
    float s = 0.f, qq = 0.f;
    for (int i = threadIdx.x; i < 2048; i += 256) {
        int b = i >> 8, t4 = i & 255;
        float4 v = base[b * 16384 + t4];
        s += v.x + v.y + v.z + v.w;
        qq = fmaf(v.x, v.x, qq); qq = fmaf(v.y, v.y, qq);
        qq = fmaf(v.z, v.z, qq); qq = fmaf(v.w, v.w, qq);
    }
    for (int off = 32; off; off >>= 1) { s += __shfl_down(s, off); qq += __shfl_down(qq, off); }
    __shared__ float ls[4], lq[4];
    int w = threadIdx.x >> 6, lane = threadIdx.x & 63;
    if (lane == 0) { ls[w] = s; lq[w] = qq; }
    __syncthreads();
    if (threadIdx.x == 0) {
        unsafeAtomicAdd(sum0 + c, ls[0] + ls[1] + ls[2] + ls[3]);
        unsafeAtomicAdd(sq0 + c, lq[0] + lq[1] + lq[2] + lq[3]);
    }
}

// ---------------- weight prep: bf16 conversions / transposes ----------------
__global__ __launch_bounds__(256) void prep_w(const float* __restrict__ cw,
        const float* __restrict__ wl, const float* __restrict__ wr,
        const float* __restrict__ chw,
        __bf16* __restrict__ wcbf, __bf16* __restrict__ wlrbf,
        __bf16* __restrict__ chwbf) {
    int i = blockIdx.x * 256 + threadIdx.x;
    if (i < 73728) {                    // wcbf[kk][co][ci] = cw[co][ci*9+kk]
        int kk = i >> 13, co = (i >> 6) & 127, ci = i & 63;
        wcbf[i] = (__bf16)cw[co * 576 + ci * 9 + kk];
    } else if (i < 73728 + 16384) {     // wlrbf[j][c]
        int j = i - 73728;
        int r = j >> 6, c = j & 63;
        float v = (r < 128) ? wl[r * 64 + c] : wr[(r - 128) * 64 + c];
        wlrbf[j] = (__bf16)v;
    } else if (i < 73728 + 32768) {     // chwbf[j][c]
        int j = i - 73728 - 16384;
        chwbf[j] = (__bf16)chw[j];
    }
}

// ---------------- xprep: bn0-apply -> hbf (flat bf16) + xt (transposed bf16) ----------------
__global__ __launch_bounds__(256) void xprep(const float* __restrict__ x,
        const float* __restrict__ sum0, const float* __restrict__ sq0,
        const float* __restrict__ g0, const float* __restrict__ b0,
        __bf16* __restrict__ hbf, __bf16* __restrict__ xt) {
    __shared__ float lds[64][65];
    __shared__ float scs[64], shs[64];
    int tid = threadIdx.x;
    if (tid < 64) {
        float mu = sum0[tid] * (1.f / 32768.f);
        float var = sq0[tid] * (1.f / 32768.f) - mu * mu;
        float rs = rsqrtf(var + 1e-5f);
        float sc = rs * g0[tid];
        scs[tid] = sc; shs[tid] = b0[tid] - mu * sc;
    }
    __syncthreads();
    int t0 = blockIdx.x * 64;
    int b  = blockIdx.y;
    const float* xb = x + (long)b * 65536;
    for (int i = tid; i < 4096; i += 256) {
        int ci = i >> 6, tl = i & 63;
        float v = fmaf(xb[ci * 1024 + t0 + tl], scs[ci], shs[ci]);
        hbf[(long)b * 65536 + ci * 1024 + t0 + tl] = (__bf16)v;
        lds[ci][tl] = v;
    }
    __syncthreads();
    for (int i = tid; i < 4096; i += 256) {
        int t = i >> 6, ci = i & 63;
        xt[((long)b * 1024 + t0 + t) * 64 + ci] = (__bf16)lds[ci][t];
    }
}

// ---------------- conv1d K=9 via MFMA: C[co][t] = sum_kk W_kk[co][ci] x xt[t+kk-4][ci] ----------------
// grid (8 tsplit, 2 cohalf, 32 b), block 256 = 4 waves; wave owns 16 co
__global__ __launch_bounds__(256) void conv_mfma(const __bf16* __restrict__ xt,
        const __bf16* __restrict__ wcbf, const float* __restrict__ cb,
        float* __restrict__ res) {
    int wv = threadIdx.x >> 6, lane = threadIdx.x & 63;
    int col = lane & 15, q = lane >> 4;
    int co0 = blockIdx.y * 64 + wv * 16;
    int b = blockIdx.z;
    int tbase = blockIdx.x * 128;
    bf16x8 af[18];
    #pragma unroll
    for (int kk = 0; kk < 9; kk++)
        #pragma unroll
        for (int ks = 0; ks < 2; ks++)
            af[kk * 2 + ks] = *(const bf16x8*)(wcbf +
                ((long)kk * 8192 + (long)(co0 + col) * 64 + ks * 32 + q * 8));
    float bi0 = cb[co0 + q * 4], bi1 = cb[co0 + q * 4 + 1];
    float bi2 = cb[co0 + q * 4 + 2], bi3 = cb[co0 + q * 4 + 3];
    const __bf16* xb = xt + (long)b * 65536;
    bf16x8 z = zero8();
    for (int nt = 0; nt < 8; nt++) {
        int t0 = tbase + nt * 16;
        f32x4 acc; acc[0] = bi0; acc[1] = bi1; acc[2] = bi2; acc[3] = bi3;
        #pragma unroll
        for (int kk = 0; kk < 9; kk++) {
            int tg = t0 + col + kk - 4;
            bool ok = (unsigned)tg < 1024u;
            const bf16x8* bp = (const bf16x8*)(xb + (long)(ok ? tg : 0) * 64 + q * 8);
            bf16x8 bf0 = ok ? bp[0] : z;
            bf16x8 bf1 = ok ? bp[4] : z;   // +32 elements (ks=1)
            acc = __builtin_amdgcn_mfma_f32_16x16x32_bf16(af[kk * 2],     bf0, acc, 0, 0, 0);
            acc = __builtin_amdgcn_mfma_f32_16x16x32_bf16(af[kk * 2 + 1], bf1, acc, 0, 0, 0);
        }
        long ob = (long)b * 131072 + (long)(co0 + q * 4) * 1024 + t0 + col;
        res[ob]        = fmaxf(acc[0], 0.f);
        res[ob + 1024] = fmaxf(acc[1], 0.f);
        res[ob + 2048] = fmaxf(acc[2], 0.f);
        res[ob + 3072] = fmaxf(acc[3], 0.f);
    }
}

// ---------------- gemm1 via MFMA: [xl|xr] = hbf @ wlrbf^T, output packed bf16 pairs ----------------
// grid 512 (m-chunks of 64 rows), block 4 waves; wave w owns cols {w*16, w*16+64, +128, +192}
__global__ __launch_bounds__(256) void gemm1_mfma(const __bf16* __restrict__ hbf,
        const __bf16* __restrict__ wlrbf,
        unsigned* __restrict__ xlp, unsigned* __restrict__ xrp) {
    int wv = threadIdx.x >> 6, lane = threadIdx.x & 63;
    int col = lane & 15, q = lane >> 4;
    int d0 = wv * 16;
    long mbase = (long)blockIdx.x * 64;
    bf16x8 bfr[4][2];
    #pragma unroll
    for (int t = 0; t < 4; t++) {
        int j = d0 + t * 64 + col;
        #pragma unroll
        for (int ks = 0; ks < 2; ks++)
            bfr[t][ks] = *(const bf16x8*)(wlrbf + (long)j * 64 + ks * 32 + q * 8);
    }
    for (int mt = 0; mt < 4; mt++) {
        long r0 = mbase + mt * 16;
        bf16x8 a0 = *(const bf16x8*)(hbf + (r0 + col) * 64 + q * 8);
        bf16x8 a1 = *(const bf16x8*)(hbf + (r0 + col) * 64 + 32 + q * 8);
        f32x4 acc[4];
        #pragma unroll
        for (int t = 0; t < 4; t++) { acc[t][0] = 0.f; acc[t][1] = 0.f; acc[t][2] = 0.f; acc[t][3] = 0.f; }
        #pragma unroll
        for (int t = 0; t < 4; t++) {
            acc[t] = __builtin_amdgcn_mfma_f32_16x16x32_bf16(a0, bfr[t][0], acc[t], 0, 0, 0);
            acc[t] = __builtin_amdgcn_mfma_f32_16x16x32_bf16(a1, bfr[t][1], acc[t], 0, 0, 0);
        }
        #pragma unroll
        for (int reg = 0; reg < 4; reg++) {
            long r = r0 + q * 4 + reg;
            xlp[r * 64 + d0 + col] = pk2(acc[0][reg], acc[1][reg]);
            xrp[r * 64 + d0 + col] = pk2(acc[2][reg], acc[3][reg]);
        }
    }
}

// ---------------- bucket CSR build (capacity 64) ----------------
__global__ __launch_bounds__(256) void bucket_fill(const int* __restrict__ ei,
        int* __restrict__ cursor, int* __restrict__ bucket) {
    int e = blockIdx.x * 256 + threadIdx.x;
    int t = ei[Ec + e];
    int slot = atomicAdd(cursor + t, 1);
    bucket[t * 64 + slot] = ei[e];
}

// ---------------- fused GATv2: wave-per-node, bf16 gathers, no softmax-max ----------------
__global__ __launch_bounds__(256) void gat_agg(const unsigned* __restrict__ xlp,
        const unsigned* __restrict__ xrp,
        const int* __restrict__ cursor, const int* __restrict__ bucket,
        const float* __restrict__ att, float* __restrict__ gout) {
    int wid = (blockIdx.x * 256 + threadIdx.x) >> 6;
    int lane = threadIdx.x & 63;
    float a0 = att[lane], a1 = att[64 + lane];
    unsigned vr = xrp[(long)wid * 64 + lane];
    float xr0 = unpack_lo(vr), xr1 = unpack_hi(vr);
    unsigned vs = xlp[(long)wid * 64 + lane];
    float xs0 = unpack_lo(vs), xs1 = unpack_hi(vs);
    float t0 = xs0 + xr0; t0 = fmaxf(t0, 0.2f * t0) * a0;
    float t1 = xs1 + xr1; t1 = fmaxf(t1, 0.2f * t1) * a1;
    t0 += __shfl_xor(t0, 32); t1 += __shfl_xor(t1, 32);
    float wvr = (lane < 32) ? t0 : t1;
    #pragma unroll
    for (int off = 16; off; off >>= 1) wvr += __shfl_xor(wvr, off);
    float p0 = __expf(__shfl(wvr, 0)), p1 = __expf(__shfl(wvr, 32));
    float den0 = p0, den1 = p1;
    float acc0 = p0 * xs0, acc1 = p1 * xs1;
    int cnt = cursor[wid];
    const int* bk = bucket + wid * 64;
    #pragma unroll 2
    for (int i = 0; i < cnt; i++) {
        int s = bk[i];
        unsigned v = xlp[(long)s * 64 + lane];
        float xl0 = unpack_lo(v), xl1 = unpack_hi(v);
        float u0 = xl0 + xr0; u0 = fmaxf(u0, 0.2f * u0) * a0;
        float u1 = xl1 + xr1; u1 = fmaxf(u1, 0.2f * u1) * a1;
        u0 += __shfl_xor(u0, 32); u1 += __shfl_xor(u1, 32);
        float w2 = (lane < 32) ? u0 : u1;
        #pragma unroll
        for (int off = 16; off; off >>= 1) w2 += __shfl_xor(w2, off);
        float e0 = __expf(__shfl(w2, 0)), e1 = __expf(__shfl(w2, 32));
        den0 += e0; den1 += e1;
        acc0 = fmaf(e0, xl0, acc0);
        acc1 = fmaf(e1, xl1, acc1);
    }
    float i0 = __builtin_amdgcn_rcpf(den0), i1 = __builtin_amdgcn_rcpf(den1);
    gout[(long)wid * 128 + lane]      = acc0 * i0;
    gout[(long)wid * 128 + 64 + lane] = acc1 * i1;
}

// ---------------- bn over [N,128] (axis 0) ----------------
__global__ __launch_bounds__(256) void bn_stats(const float* __restrict__ X,
        float* __restrict__ sum, float* __restrict__ sq) {
    int f = threadIdx.x & 127, sub = threadIdx.x >> 7;
    int r0 = blockIdx.x * 256;
    float s = 0.f, q = 0.f;
    for (int r = r0 + sub; r < r0 + 256; r += 2) {
        float v = X[(long)r * 128 + f];
        s += v; q = fmaf(v, v, q);
    }
    __shared__ float ls[256], lq[256];
    ls[threadIdx.x] = s; lq[threadIdx.x] = q;
    __syncthreads();
    if (threadIdx.x < 128) {
        s = ls[threadIdx.x] + ls[threadIdx.x + 128];
        q = lq[threadIdx.x] + lq[threadIdx.x + 128];
        unsafeAtomicAdd(sum + f, s);
        unsafeAtomicAdd(sq + f, q);
    }
}

// res[i] + relu(bn(X[i])) -> bf16 out (for cheb input)
__global__ __launch_bounds__(256) void bn_res_bf(const float* __restrict__ X,
        const float* __restrict__ res, const float* __restrict__ sum,
        const float* __restrict__ sq, const float* __restrict__ g,
        const float* __restrict__ bta, unsigned* __restrict__ outb) {
    __shared__ float scs[128], shs[128];
    int tid = threadIdx.x;
    if (tid < 128) {
        float mu = sum[tid] * (1.f / 32768.f);
        float var = sq[tid] * (1.f / 32768.f) - mu * mu;
        float rs = rsqrtf(var + 1e-5f);
        float sc = rs * g[tid];
        scs[tid] = sc; shs[tid] = bta[tid] - mu * sc;
    }
    __syncthreads();
    int idx = blockIdx.x * 256 + tid;
    int f0 = (idx & 31) * 4;
    float4 v = ((const float4*)X)[idx];
    float4 r = ((const float4*)res)[idx];
    float o0 = r.x + fmaxf(fmaf(v.x, scs[f0],     shs[f0]),     0.f);
    float o1 = r.y + fmaxf(fmaf(v.y, scs[f0 + 1], shs[f0 + 1]), 0.f);
    float o2 = r.z + fmaxf(fmaf(v.z, scs[f0 + 2], shs[f0 + 2]), 0.f);
    float o3 = r.w + fmaxf(fmaf(v.w, scs[f0 + 3], shs[f0 + 3]), 0.f);
    uint2 o; o.x = (bfb(o1) << 16) | bfb(o0); o.y = (bfb(o3) << 16) | bfb(o2);
    ((uint2*)outb)[idx] = o;
}

// res[i] + relu(bn(X[i])) -> fp32 out (final output)
__global__ __launch_bounds__(256) void bn_res(const float* __restrict__ X,
        const float* __restrict__ res, const float* __restrict__ sum,
        const float* __restrict__ sq, const float* __restrict__ g,
        const float* __restrict__ bta, float* __restrict__ out) {
    __shared__ float scs[128], shs[128];
    int tid = threadIdx.x;
    if (tid < 128) {
        float mu = sum[tid] * (1.f / 32768.f);
        float var = sq[tid] * (1.f / 32768.f) - mu * mu;
        float rs = rsqrtf(var + 1e-5f);
        float sc = rs * g[tid];
        scs[tid] = sc; shs[tid] = bta[tid] - mu * sc;
    }
    __syncthreads();
    int idx = blockIdx.x * 256 + tid;
    int f0 = (idx & 31) * 4;
    float4 v = ((const float4*)X)[idx];
    float4 r = ((const float4*)res)[idx];
    float4 o;
    o.x = r.x + fmaxf(fmaf(v.x, scs[f0],     shs[f0]),     0.f);
    o.y = r.y + fmaxf(fmaf(v.y, scs[f0 + 1], shs[f0 + 1]), 0.f);
    o.z = r.z + fmaxf(fmaf(v.z, scs[f0 + 2], shs[f0 + 2]), 0.f);
    o.w = r.w + fmaxf(fmaf(v.w, scs[f0 + 3], shs[f0 + 3]), 0.f);
    ((float4*)out)[idx] = o;
}

// ---------------- cheb via MFMA: z = h2bf @ chwbf^T ----------------
// grid 512 (m-chunks of 64), block 4 waves; wave w owns cols {w*16, w*16+64}
__global__ __launch_bounds__(256) void cheb_mfma(const __bf16* __restrict__ h2bf,
        const __bf16* __restrict__ chwbf, float* __restrict__ z) {
    int wv = threadIdx.x >> 6, lane = threadIdx.x & 63;
    int col = lane & 15, q = lane >> 4;
    long mbase = (long)blockIdx.x * 64;
    bf16x8 bfr[2][4];
    #pragma unroll
    for (int t = 0; t < 2; t++) {
        int j = wv * 16 + t * 64 + col;
        #pragma unroll
        for (int ks = 0; ks < 4; ks++)
            bfr[t][ks] = *(const bf16x8*)(chwbf + (long)j * 128 + ks * 32 + q * 8);
    }
    for (int mt = 0; mt < 4; mt++) {
        long r0 = mbase + mt * 16;
        bf16x8 a[4];
        #pragma unroll
        for (int ks = 0; ks < 4; ks++)
            a[ks] = *(const bf16x8*)(h2bf + (r0 + col) * 128 + ks * 32 + q * 8);
        f32x4 acc[2];
        #pragma unroll
        for (int t = 0; t < 2; t++) { acc[t][0] = 0.f; acc[t][1] = 0.f; acc[t][2] = 0.f; acc[t][3] = 0.f; }
        #pragma unroll
        for (int t = 0; t < 2; t++)
            #pragma unroll
            for (int ks = 0; ks < 4; ks++)
                acc[t] = __builtin_amdgcn_mfma_f32_16x16x32_bf16(a[ks], bfr[t][ks], acc[t], 0, 0, 0);
        #pragma unroll
        for (int t = 0; t < 2; t++)
            #pragma unroll
            for (int reg = 0; reg < 4; reg++)
                z[(r0 + q * 4 + reg) * 128 + wv * 16 + t * 64 + col] = acc[t][reg];
    }
}

extern "C" void kernel_launch(void* const* d_in, const int* in_sizes, int n_in,
                              void* d_out, int out_size, void* d_ws, size_t ws_size,
                              hipStream_t stream) {
    const float* x   = (const float*)d_in[0];
    const int*   ei  = (const int*)d_in[1];
    const float* g0  = (const float*)d_in[2];
    const float* b0  = (const float*)d_in[3];
    const float* cw  = (const float*)d_in[4];
    const float* cb  = (const float*)d_in[5];
    const float* wl  = (const float*)d_in[6];
    const float* wr  = (const float*)d_in[7];
    const float* att = (const float*)d_in[8];
    // d_in[9] = gat_bias: cancels exactly inside the following bn2d -> unused
    const float* g1  = (const float*)d_in[10];
    const float* b1  = (const float*)d_in[11];
    const float* chw = (const float*)d_in[12];
    // d_in[13] = cheb_b: cancels inside the following bn2d -> unused
    float* out = (float*)d_out;

    float* ws = (float*)d_ws;
    float*    res   = ws + O_RES;
    float*    gout  = ws + O_GOUT;
    __bf16*   xt    = (__bf16*)(ws + O_XT);
    __bf16*   hbf   = (__bf16*)(ws + O_HBF);
    unsigned* xlp   = (unsigned*)(ws + O_XLP);
    unsigned* xrp   = (unsigned*)(ws + O_XRP);
    unsigned* h2bf  = (unsigned*)(ws + O_H2BF);
    float*    z     = ws + O_Z;
    __bf16*   wcbf  = (__bf16*)(ws + O_WCBF);
    __bf16*   wlrbf = (__bf16*)(ws + O_WLR);
    __bf16*   chwbf = (__bf16*)(ws + O_CHB);
    float*    st    = ws + O_STAT;
    int*      cursor = (int*)(ws + O_CUR);
    int*      bucket = (int*)(ws + O_BUCK);
    float *sum0 = st,       *sq0 = st + 64;
    float *sum1 = st + 128, *sq1 = st + 256;
    float *sum2 = st + 384, *sq2 = st + 512;

    // one memset covers stat block (4KB) + cursor (128KB), contiguous
    hipMemsetAsync(st, 0, (size_t)(1024 + 32768) * 4, stream);

    // independent prep
    prep_w<<<417, 256, 0, stream>>>(cw, wl, wr, chw, wcbf, wlrbf, chwbf);
    bucket_fill<<<2048, 256, 0, stream>>>(ei, cursor, bucket);

    // bn0 stats -> bf16 activations (flat + transposed)
    bn0_sums<<<256, 256, 0, stream>>>(x, sum0, sq0);
    xprep<<<dim3(16, 32), 256, 0, stream>>>(x, sum0, sq0, g0, b0, hbf, xt);
    // conv1d + relu -> residual (MFMA)
    conv_mfma<<<dim3(8, 2, 32), 256, 0, stream>>>(xt, wcbf, cb, res);
    // xl|xr (MFMA, packed bf16 pair outputs)
    gemm1_mfma<<<512, 256, 0, stream>>>(hbf, wlrbf, xlp, xrp);
    // fused GATv2
    gat_agg<<<8192, 256, 0, stream>>>(xlp, xrp, cursor, bucket, att, gout);
    // bn1 + relu + residual -> h2 (bf16)
    bn_stats<<<128, 256, 0, stream>>>(gout, sum1, sq1);
    bn_res_bf<<<4096, 256, 0, stream>>>(gout, res, sum1, sq1, g1, b1, h2bf);
    // cheb linear (MFMA)
    cheb_mfma<<<512, 256, 0, stream>>>((const __bf16*)h2bf, chwbf, z);
    // bn1 again + relu + residual -> out
    bn_stats<<<128, 256, 0, stream>>>(z, sum2, sq2);
    bn_res<<<4096, 256, 0, stream>>>(z, res, sum2, sq2, g1, b1, out);
}

// Round 7
// 335.793 us; speedup vs baseline: 2.0932x; 1.0201x over previous
//
#include <hip/hip_runtime.h>

#define DEVINL __device__ __forceinline__

constexpr int Bc = 32, Cc = 64, Tc = 1024, DIM2c = 128;
constexpr int Nn = Bc * Tc;            // 32768 nodes
constexpr int Ec = 524288;             // edges (self-loops handled in-kernel)

typedef __bf16 bf16x8 __attribute__((ext_vector_type(8)));
typedef float  f32x4  __attribute__((ext_vector_type(4)));

// workspace layout (float offsets) — identical to round 5
constexpr long O_RES   = 0;            // 4194304 fp32
constexpr long O_GOUT  = 4194304;      // 4194304 fp32
constexpr long O_XT    = 8388608;      // bf16 x 2097152: [b*1024+t][ci]
constexpr long O_HBF   = 9437184;      // bf16 x 2097152: flat bn0(x)
constexpr long O_XLQ   = 10485760;     // 2097152 uint (head-split bf16, u16[n][128])
constexpr long O_XRQ   = 12582912;     // 2097152 uint
constexpr long O_H2BF  = 14680064;     // bf16 x 4194304: [n][128]
constexpr long O_Z     = 16777216;     // 4194304 fp32
constexpr long O_WCBF  = 20971520;     // bf16 x 73728: [kk][co][ci]
constexpr long O_WLR   = 21008384;     // bf16 x 16384: [j 256][c 64]
constexpr long O_CHB   = 21016576;     // bf16 x 16384: [j 128][c 128]
constexpr long O_STAT  = 21024768;     // 1024 (zeroed by memset)
constexpr long O_CUR   = 21025792;     // 32768 ints (zeroed, contiguous w/ STAT)
constexpr long O_BUCK  = 21058560;     // 2097152 ints

DEVINL float unpack_lo(unsigned v) { return __uint_as_float(v << 16); }
DEVINL float unpack_hi(unsigned v) { return __uint_as_float(v & 0xffff0000u); }
DEVINL unsigned bfb(float f) { return (__float_as_uint(f) + 0x8000u) >> 16; }

// ---------------- bn0 sums: per-channel over [B,C,T] axis (0,2) ----------------
__global__ __launch_bounds__(256) void bn0_sums(const float* __restrict__ x,
        float* __restrict__ sum0, float* __restrict__ sq0) {
    int c = blockIdx.x & 63, q = blockIdx.x >> 6;
    const float4* base = (const float4*)(x + (long)q * 8 * 65536 + (long)c * 1024);
    float s = 0.f, qq = 0.f;
    for (int i = threadIdx.x; i < 2048; i += 256) {
        int b = i >> 8, t4 = i & 255;
        float4 v = base[b * 16384 + t4];
        s += v.x + v.y + v.z + v.w;
        qq = fmaf(v.x, v.x, qq); qq = fmaf(v.y, v.y, qq);
        qq = fmaf(v.z, v.z, qq); qq = fmaf(v.w, v.w, qq);
    }
    for (int off = 32; off; off >>= 1) { s += __shfl_down(s, off); qq += __shfl_down(qq, off); }
    __shared__ float ls[4], lq[4];
    int w = threadIdx.x >> 6, lane = threadIdx.x & 63;
    if (lane == 0) { ls[w] = s; lq[w] = qq; }
    __syncthreads();
    if (threadIdx.x == 0) {
        unsafeAtomicAdd(sum0 + c, ls[0] + ls[1] + ls[2] + ls[3]);
        unsafeAtomicAdd(sq0 + c, lq[0] + lq[1] + lq[2] + lq[3]);
    }
}

// ---------------- weight prep: bf16 conversions / transposes ----------------
__global__ __launch_bounds__(256) void prep_w(const float* __restrict__ cw,
        const float* __restrict__ wl, const float* __restrict__ wr,
        const float* __restrict__ chw,
        __bf16* __restrict__ wcbf, __bf16* __restrict__ wlrbf,
        __bf16* __restrict__ chwbf) {
    int i = blockIdx.x * 256 + threadIdx.x;
    if (i < 73728) {                    // wcbf[kk][co][ci] = cw[co][ci*9+kk]
        int kk = i >> 13, co = (i >> 6) & 127, ci = i & 63;
        wcbf[i] = (__bf16)cw[co * 576 + ci * 9 + kk];
    } else if (i < 73728 + 16384) {     // wlrbf[j][c]
        int j = i - 73728;
        int r = j >> 6, c = j & 63;
        float v = (r < 128) ? wl[r * 64 + c] : wr[(r - 128) * 64 + c];
        wlrbf[j] = (__bf16)v;
    } else if (i < 73728 + 32768) {     // chwbf[j][c]
        int j = i - 73728 - 16384;
        chwbf[j] = (__bf16)chw[j];
    }
}

// ---------------- xprep: bn0-apply -> hbf (flat bf16) + xt (transposed bf16) ----------------
__global__ __launch_bounds__(256) void xprep(const float* __restrict__ x,
        const float* __restrict__ sum0, const float* __restrict__ sq0,
        const float* __restrict__ g0, const float* __restrict__ b0,
        __bf16* __restrict__ hbf, __bf16* __restrict__ xt) {
    __shared__ float lds[64][65];
    __shared__ float scs[64], shs[64];
    int tid = threadIdx.x;
    if (tid < 64) {
        float mu = sum0[tid] * (1.f / 32768.f);
        float var = sq0[tid] * (1.f / 32768.f) - mu * mu;
        float rs = rsqrtf(var + 1e-5f);
        float sc = rs * g0[tid];
        scs[tid] = sc; shs[tid] = b0[tid] - mu * sc;
    }
    __syncthreads();
    int t0 = blockIdx.x * 64;
    int b  = blockIdx.y;
    const float* xb = x + (long)b * 65536;
    for (int i = tid; i < 4096; i += 256) {
        int ci = i >> 6, tl = i & 63;
        float v = fmaf(xb[ci * 1024 + t0 + tl], scs[ci], shs[ci]);
        hbf[(long)b * 65536 + ci * 1024 + t0 + tl] = (__bf16)v;
        lds[ci][tl] = v;
    }
    __syncthreads();
    for (int i = tid; i < 4096; i += 256) {
        int t = i >> 6, ci = i & 63;
        xt[((long)b * 1024 + t0 + t) * 64 + ci] = (__bf16)lds[ci][t];
    }
}

// ---------------- conv1d K=9 via MFMA ----------------
__global__ __launch_bounds__(256) void conv_mfma(const __bf16* __restrict__ xt,
        const __bf16* __restrict__ wcbf, const float* __restrict__ cb,
        float* __restrict__ res) {
    int wv = threadIdx.x >> 6, lane = threadIdx.x & 63;
    int col = lane & 15, q = lane >> 4;
    int co0 = blockIdx.y * 64 + wv * 16;
    int b = blockIdx.z;
    int tbase = blockIdx.x * 128;
    bf16x8 af[18];
    #pragma unroll
    for (int kk = 0; kk < 9; kk++)
        #pragma unroll
        for (int ks = 0; ks < 2; ks++)
            af[kk * 2 + ks] = *(const bf16x8*)(wcbf +
                ((long)kk * 8192 + (long)(co0 + col) * 64 + ks * 32 + q * 8));
    float bi0 = cb[co0 + q * 4], bi1 = cb[co0 + q * 4 + 1];
    float bi2 = cb[co0 + q * 4 + 2], bi3 = cb[co0 + q * 4 + 3];
    const __bf16* xb = xt + (long)b * 65536;
    bf16x8 z8;
    #pragma unroll
    for (int i = 0; i < 8; i++) z8[i] = (__bf16)0.f;
    for (int nt = 0; nt < 8; nt++) {
        int t0 = tbase + nt * 16;
        f32x4 acc; acc[0] = bi0; acc[1] = bi1; acc[2] = bi2; acc[3] = bi3;
        #pragma unroll
        for (int kk = 0; kk < 9; kk++) {
            int tg = t0 + col + kk - 4;
            bool ok = (unsigned)tg < 1024u;
            const bf16x8* bp = (const bf16x8*)(xb + (long)(ok ? tg : 0) * 64 + q * 8);
            bf16x8 bf0 = ok ? bp[0] : z8;
            bf16x8 bf1 = ok ? bp[4] : z8;
            acc = __builtin_amdgcn_mfma_f32_16x16x32_bf16(af[kk * 2],     bf0, acc, 0, 0, 0);
            acc = __builtin_amdgcn_mfma_f32_16x16x32_bf16(af[kk * 2 + 1], bf1, acc, 0, 0, 0);
        }
        long ob = (long)b * 131072 + (long)(co0 + q * 4) * 1024 + t0 + col;
        res[ob]        = fmaxf(acc[0], 0.f);
        res[ob + 1024] = fmaxf(acc[1], 0.f);
        res[ob + 2048] = fmaxf(acc[2], 0.f);
        res[ob + 3072] = fmaxf(acc[3], 0.f);
    }
}

// ---------------- gemm1 via MFMA: [xl|xr] = hbf @ wlrbf^T -> head-split u16 layout ----------------
// u16 slot d (d<64) = head0 dim d; slot 64+d = head1 dim d  (per node row of 128 u16)
__global__ __launch_bounds__(256) void gemm1_mfma(const __bf16* __restrict__ hbf,
        const __bf16* __restrict__ wlrbf,
        unsigned short* __restrict__ xl16, unsigned short* __restrict__ xr16) {
    int wv = threadIdx.x >> 6, lane = threadIdx.x & 63;
    int col = lane & 15, q = lane >> 4;
    int d0 = wv * 16;
    long mbase = (long)blockIdx.x * 64;
    bf16x8 bfr[4][2];
    #pragma unroll
    for (int t = 0; t < 4; t++) {
        int j = d0 + t * 64 + col;
        #pragma unroll
        for (int ks = 0; ks < 2; ks++)
            bfr[t][ks] = *(const bf16x8*)(wlrbf + (long)j * 64 + ks * 32 + q * 8);
    }
    int d = d0 + col;
    for (int mt = 0; mt < 4; mt++) {
        long r0 = mbase + mt * 16;
        bf16x8 a0 = *(const bf16x8*)(hbf + (r0 + col) * 64 + q * 8);
        bf16x8 a1 = *(const bf16x8*)(hbf + (r0 + col) * 64 + 32 + q * 8);
        f32x4 acc[4];
        #pragma unroll
        for (int t = 0; t < 4; t++) { acc[t][0] = 0.f; acc[t][1] = 0.f; acc[t][2] = 0.f; acc[t][3] = 0.f; }
        #pragma unroll
        for (int t = 0; t < 4; t++) {
            acc[t] = __builtin_amdgcn_mfma_f32_16x16x32_bf16(a0, bfr[t][0], acc[t], 0, 0, 0);
            acc[t] = __builtin_amdgcn_mfma_f32_16x16x32_bf16(a1, bfr[t][1], acc[t], 0, 0, 0);
        }
        #pragma unroll
        for (int reg = 0; reg < 4; reg++) {
            long rb = (r0 + q * 4 + reg) * 128;    // u16 units per node row
            xl16[rb + d]      = (unsigned short)bfb(acc[0][reg]);   // head0 dim d
            xl16[rb + 64 + d] = (unsigned short)bfb(acc[1][reg]);   // head1 dim d
            xr16[rb + d]      = (unsigned short)bfb(acc[2][reg]);
            xr16[rb + 64 + d] = (unsigned short)bfb(acc[3][reg]);
        }
    }
}

// ---------------- bucket CSR build (capacity 64) ----------------
__global__ __launch_bounds__(256) void bucket_fill(const int* __restrict__ ei,
        int* __restrict__ cursor, int* __restrict__ bucket) {
    int e = blockIdx.x * 256 + threadIdx.x;
    int t = ei[Ec + e];
    int slot = atomicAdd(cursor + t, 1);
    bucket[t * 64 + slot] = ei[e];
}

// ---------------- fused GATv2: wave-per-node, head-split 5-shuffle reduction ----------------
// lane l<32 holds head0 dims 2l,2l+1; l>=32 head1 dims 2(l-32),2(l-32)+1.
// xor-butterfly masks 16..1 stay within each 32-half -> both head logits in 5 shuffles, 1 exp.
__global__ __launch_bounds__(256) void gat_agg(const unsigned* __restrict__ xlq,
        const unsigned* __restrict__ xrq,
        const int* __restrict__ cursor, const int* __restrict__ bucket,
        const float* __restrict__ att, float* __restrict__ gout) {
    int wid = (blockIdx.x * 256 + threadIdx.x) >> 6;
    int lane = threadIdx.x & 63;
    int h = lane >> 5, dd = (lane & 31) * 2;
    float a_lo = att[h * 64 + dd], a_hi = att[h * 64 + dd + 1];
    unsigned vr = xrq[(long)wid * 64 + lane];
    float xr_lo = unpack_lo(vr), xr_hi = unpack_hi(vr);
    unsigned vs = xlq[(long)wid * 64 + lane];
    float xs_lo = unpack_lo(vs), xs_hi = unpack_hi(vs);
    float u0 = xs_lo + xr_lo; u0 = fmaxf(u0, 0.2f * u0);
    float u1 = xs_hi + xr_hi; u1 = fmaxf(u1, 0.2f * u1);
    float w = fmaf(u1, a_hi, u0 * a_lo);
    #pragma unroll
    for (int off = 16; off; off >>= 1) w += __shfl_xor(w, off);
    float e = __expf(w);
    float den = e, acc_lo = e * xs_lo, acc_hi = e * xs_hi;
    int cnt = cursor[wid];
    const int* bk = bucket + wid * 64;
    #pragma unroll 2
    for (int i = 0; i < cnt; i++) {
        int s = bk[i];
        unsigned v = xlq[(long)s * 64 + lane];
        float xl_lo = unpack_lo(v), xl_hi = unpack_hi(v);
        float v0 = xl_lo + xr_lo; v0 = fmaxf(v0, 0.2f * v0);
        float v1 = xl_hi + xr_hi; v1 = fmaxf(v1, 0.2f * v1);
        float w2 = fmaf(v1, a_hi, v0 * a_lo);
        #pragma unroll
        for (int off = 16; off; off >>= 1) w2 += __shfl_xor(w2, off);
        float e2 = __expf(w2);
        den += e2;
        acc_lo = fmaf(e2, xl_lo, acc_lo);
        acc_hi = fmaf(e2, xl_hi, acc_hi);
    }
    float rn = __builtin_amdgcn_rcpf(den);
    float2 o; o.x = acc_lo * rn; o.y = acc_hi * rn;
    *(float2*)(gout + (long)wid * 128 + h * 64 + dd) = o;
}

// ---------------- bn over [N,128] (axis 0) ----------------
__global__ __launch_bounds__(256) void bn_stats(const float* __restrict__ X,
        float* __restrict__ sum, float* __restrict__ sq) {
    int f = threadIdx.x & 127, sub = threadIdx.x >> 7;
    int r0 = blockIdx.x * 256;
    float s = 0.f, q = 0.f;
    for (int r = r0 + sub; r < r0 + 256; r += 2) {
        float v = X[(long)r * 128 + f];
        s += v; q = fmaf(v, v, q);
    }
    __shared__ float ls[256], lq[256];
    ls[threadIdx.x] = s; lq[threadIdx.x] = q;
    __syncthreads();
    if (threadIdx.x < 128) {
        s = ls[threadIdx.x] + ls[threadIdx.x + 128];
        q = lq[threadIdx.x] + lq[threadIdx.x + 128];
        unsafeAtomicAdd(sum + f, s);
        unsafeAtomicAdd(sq + f, q);
    }
}

// res + relu(bn(X)) -> bf16 (cheb input)
__global__ __launch_bounds__(256) void bn_res_bf(const float* __restrict__ X,
        const float* __restrict__ res, const float* __restrict__ sum,
        const float* __restrict__ sq, const float* __restrict__ g,
        const float* __restrict__ bta, unsigned* __restrict__ outb) {
    __shared__ float scs[128], shs[128];
    int tid = threadIdx.x;
    if (tid < 128) {
        float mu = sum[tid] * (1.f / 32768.f);
        float var = sq[tid] * (1.f / 32768.f) - mu * mu;
        float rs = rsqrtf(var + 1e-5f);
        float sc = rs * g[tid];
        scs[tid] = sc; shs[tid] = bta[tid] - mu * sc;
    }
    __syncthreads();
    int idx = blockIdx.x * 256 + tid;
    int f0 = (idx & 31) * 4;
    float4 v = ((const float4*)X)[idx];
    float4 r = ((const float4*)res)[idx];
    float o0 = r.x + fmaxf(fmaf(v.x, scs[f0],     shs[f0]),     0.f);
    float o1 = r.y + fmaxf(fmaf(v.y, scs[f0 + 1], shs[f0 + 1]), 0.f);
    float o2 = r.z + fmaxf(fmaf(v.z, scs[f0 + 2], shs[f0 + 2]), 0.f);
    float o3 = r.w + fmaxf(fmaf(v.w, scs[f0 + 3], shs[f0 + 3]), 0.f);
    uint2 o; o.x = (bfb(o1) << 16) | bfb(o0); o.y = (bfb(o3) << 16) | bfb(o2);
    ((uint2*)outb)[idx] = o;
}

// res + relu(bn(X)) -> fp32 (final output)
__global__ __launch_bounds__(256) void bn_res(const float* __restrict__ X,
        const float* __restrict__ res, const float* __restrict__ sum,
        const float* __restrict__ sq, const float* __restrict__ g,
        const float* __restrict__ bta, float* __restrict__ out) {
    __shared__ float scs[128], shs[128];
    int tid = threadIdx.x;
    if (tid < 128) {
        float mu = sum[tid] * (1.f / 32768.f);
        float var = sq[tid] * (1.f / 32768.f) - mu * mu;
        float rs = rsqrtf(var + 1e-5f);
        float sc = rs * g[tid];
        scs[tid] = sc; shs[tid] = bta[tid] - mu * sc;
    }
    __syncthreads();
    int idx = blockIdx.x * 256 + tid;
    int f0 = (idx & 31) * 4;
    float4 v = ((const float4*)X)[idx];
    float4 r = ((const float4*)res)[idx];
    float4 o;
    o.x = r.x + fmaxf(fmaf(v.x, scs[f0],     shs[f0]),     0.f);
    o.y = r.y + fmaxf(fmaf(v.y, scs[f0 + 1], shs[f0 + 1]), 0.f);
    o.z = r.z + fmaxf(fmaf(v.z, scs[f0 + 2], shs[f0 + 2]), 0.f);
    o.w = r.w + fmaxf(fmaf(v.w, scs[f0 + 3], shs[f0 + 3]), 0.f);
    ((float4*)out)[idx] = o;
}

// ---------------- cheb via MFMA: z = h2bf @ chwbf^T ----------------
__global__ __launch_bounds__(256) void cheb_mfma(const __bf16* __restrict__ h2bf,
        const __bf16* __restrict__ chwbf, float* __restrict__ z) {
    int wv = threadIdx.x >> 6, lane = threadIdx.x & 63;
    int col = lane & 15, q = lane >> 4;
    long mbase = (long)blockIdx.x * 64;
    bf16x8 bfr[2][4];
    #pragma unroll
    for (int t = 0; t < 2; t++) {
        int j = wv * 16 + t * 64 + col;
        #pragma unroll
        for (int ks = 0; ks < 4; ks++)
            bfr[t][ks] = *(const bf16x8*)(chwbf + (long)j * 128 + ks * 32 + q * 8);
    }
    for (int mt = 0; mt < 4; mt++) {
        long r0 = mbase + mt * 16;
        bf16x8 a[4];
        #pragma unroll
        for (int ks = 0; ks < 4; ks++)
            a[ks] = *(const bf16x8*)(h2bf + (r0 + col) * 128 + ks * 32 + q * 8);
        f32x4 acc[2];
        #pragma unroll
        for (int t = 0; t < 2; t++) { acc[t][0] = 0.f; acc[t][1] = 0.f; acc[t][2] = 0.f; acc[t][3] = 0.f; }
        #pragma unroll
        for (int t = 0; t < 2; t++)
            #pragma unroll
            for (int ks = 0; ks < 4; ks++)
                acc[t] = __builtin_amdgcn_mfma_f32_16x16x32_bf16(a[ks], bfr[t][ks], acc[t], 0, 0, 0);
        #pragma unroll
        for (int t = 0; t < 2; t++)
            #pragma unroll
            for (int reg = 0; reg < 4; reg++)
                z[(r0 + q * 4 + reg) * 128 + wv * 16 + t * 64 + col] = acc[t][reg];
    }
}

extern "C" void kernel_launch(void* const* d_in, const int* in_sizes, int n_in,
                              void* d_out, int out_size, void* d_ws, size_t ws_size,
                              hipStream_t stream) {
    const float* x   = (const float*)d_in[0];
    const int*   ei  = (const int*)d_in[1];
    const float* g0  = (const float*)d_in[2];
    const float* b0  = (const float*)d_in[3];
    const float* cw  = (const float*)d_in[4];
    const float* cb  = (const float*)d_in[5];
    const float* wl  = (const float*)d_in[6];
    const float* wr  = (const float*)d_in[7];
    const float* att = (const float*)d_in[8];
    // d_in[9] = gat_bias: cancels exactly inside the following bn2d -> unused
    const float* g1  = (const float*)d_in[10];
    const float* b1  = (const float*)d_in[11];
    const float* chw = (const float*)d_in[12];
    // d_in[13] = cheb_b: cancels inside the following bn2d -> unused
    float* out = (float*)d_out;

    float* ws = (float*)d_ws;
    float*    res   = ws + O_RES;
    float*    gout  = ws + O_GOUT;
    __bf16*   xt    = (__bf16*)(ws + O_XT);
    __bf16*   hbf   = (__bf16*)(ws + O_HBF);
    unsigned* xlq   = (unsigned*)(ws + O_XLQ);
    unsigned* xrq   = (unsigned*)(ws + O_XRQ);
    unsigned* h2bf  = (unsigned*)(ws + O_H2BF);
    float*    z     = ws + O_Z;
    __bf16*   wcbf  = (__bf16*)(ws + O_WCBF);
    __bf16*   wlrbf = (__bf16*)(ws + O_WLR);
    __bf16*   chwbf = (__bf16*)(ws + O_CHB);
    float*    st    = ws + O_STAT;
    int*      cursor = (int*)(ws + O_CUR);
    int*      bucket = (int*)(ws + O_BUCK);
    float *sum0 = st,       *sq0 = st + 64;
    float *sum1 = st + 128, *sq1 = st + 256;
    float *sum2 = st + 384, *sq2 = st + 512;

    // one memset covers stat block (4KB) + cursor (128KB), contiguous
    hipMemsetAsync(st, 0, (size_t)(1024 + 32768) * 4, stream);

    // independent prep
    prep_w<<<417, 256, 0, stream>>>(cw, wl, wr, chw, wcbf, wlrbf, chwbf);
    bucket_fill<<<2048, 256, 0, stream>>>(ei, cursor, bucket);

    // bn0 stats -> bf16 activations (flat + transposed)
    bn0_sums<<<256, 256, 0, stream>>>(x, sum0, sq0);
    xprep<<<dim3(16, 32), 256, 0, stream>>>(x, sum0, sq0, g0, b0, hbf, xt);
    // conv1d + relu -> residual (MFMA)
    conv_mfma<<<dim3(8, 2, 32), 256, 0, stream>>>(xt, wcbf, cb, res);
    // xl|xr (MFMA, head-split u16 outputs)
    gemm1_mfma<<<512, 256, 0, stream>>>(hbf, wlrbf,
                                        (unsigned short*)xlq, (unsigned short*)xrq);
    // fused GATv2
    gat_agg<<<8192, 256, 0, stream>>>(xlq, xrq, cursor, bucket, att, gout);
    // bn1 + relu + residual -> h2 (bf16)
    bn_stats<<<128, 256, 0, stream>>>(gout, sum1, sq1);
    bn_res_bf<<<4096, 256, 0, stream>>>(gout, res, sum1, sq1, g1, b1, h2bf);
    // cheb linear (MFMA)
    cheb_mfma<<<512, 256, 0, stream>>>((const __bf16*)h2bf, chwbf, z);
    // bn1 again + relu + residual -> out
    bn_stats<<<128, 256, 0, stream>>>(z, sum2, sq2);
    bn_res<<<4096, 256, 0, stream>>>(z, res, sum2, sq2, g1, b1, out);
}

// Round 8
// 296.336 us; speedup vs baseline: 2.3720x; 1.1332x over previous
//
#include <hip/hip_runtime.h>

#define DEVINL __device__ __forceinline__

constexpr int Bc = 32, Cc = 64, Tc = 1024, DIM2c = 128;
constexpr int Nn = Bc * Tc;            // 32768 nodes
constexpr int Ec = 524288;             // edges (self-loops handled in-kernel)

typedef __bf16 bf16x8 __attribute__((ext_vector_type(8)));
typedef float  f32x4  __attribute__((ext_vector_type(4)));

// workspace layout (float offsets)
constexpr long O_RES   = 0;            // 4194304 fp32
constexpr long O_GOUT  = 4194304;      // 4194304 fp32
constexpr long O_XT    = 8388608;      // bf16 x 2097152: [b*1024+t][ci]
constexpr long O_HBF   = 9437184;      // bf16 x 2097152: flat bn0(x)
constexpr long O_XLQ   = 10485760;     // 2097152 uint (head-split bf16, u16[n][128])
constexpr long O_XRQ   = 12582912;     // 2097152 uint
constexpr long O_H2BF  = 14680064;     // bf16 x 4194304: [n][128]
constexpr long O_Z     = 16777216;     // 4194304 fp32
constexpr long O_WCBF  = 20971520;     // bf16 x 73728: [kk][co][ci]
constexpr long O_WLR   = 21008384;     // bf16 x 16384: [j 256][c 64]
constexpr long O_CHB   = 21016576;     // bf16 x 16384: [j 128][c 128]
constexpr long O_STAT  = 21024768;     // 1024 (zeroed by memset)
constexpr long O_CUR   = 21025792;     // 32768 ints (zeroed, contiguous w/ STAT)
constexpr long O_BUCK  = 21058560;     // 2097152 ints

DEVINL float unpack_lo(unsigned v) { return __uint_as_float(v << 16); }
DEVINL float unpack_hi(unsigned v) { return __uint_as_float(v & 0xffff0000u); }
DEVINL unsigned bfb(float f) { return (__float_as_uint(f) + 0x8000u) >> 16; }

// ================= dispatch 2: setup = prep_w U bn0_sums U bucket_fill =================
__global__ __launch_bounds__(256) void setup(const float* __restrict__ x,
        const float* __restrict__ cw, const float* __restrict__ wl,
        const float* __restrict__ wr, const float* __restrict__ chw,
        const int* __restrict__ ei,
        __bf16* __restrict__ wcbf, __bf16* __restrict__ wlrbf,
        __bf16* __restrict__ chwbf,
        float* __restrict__ sum0, float* __restrict__ sq0,
        int* __restrict__ cursor, int* __restrict__ bucket) {
    int bid = blockIdx.x, tid = threadIdx.x;
    if (bid < 416) {                           // weight prep (106496 items exactly)
        int i = bid * 256 + tid;
        if (i < 73728) {                       // wcbf[kk][co][ci] = cw[co][ci*9+kk]
            int kk = i >> 13, co = (i >> 6) & 127, ci = i & 63;
            wcbf[i] = (__bf16)cw[co * 576 + ci * 9 + kk];
        } else if (i < 73728 + 16384) {        // wlrbf[j][c]
            int j = i - 73728;
            int r = j >> 6, c = j & 63;
            float v = (r < 128) ? wl[r * 64 + c] : wr[(r - 128) * 64 + c];
            wlrbf[j] = (__bf16)v;
        } else {                               // chwbf[j][c]
            int j = i - 73728 - 16384;
            chwbf[j] = (__bf16)chw[j];
        }
    } else if (bid < 672) {                    // bn0 sums (atomics into memset-zeroed stat)
        int pq = bid - 416;
        int c = pq & 63, q = pq >> 6;
        const float4* base = (const float4*)(x + (long)q * 8 * 65536 + (long)c * 1024);
        float s = 0.f, qq = 0.f;
        for (int i = tid; i < 2048; i += 256) {
            int b = i >> 8, t4 = i & 255;
            float4 v = base[b * 16384 + t4];
            s += v.x + v.y + v.z + v.w;
            qq = fmaf(v.x, v.x, qq); qq = fmaf(v.y, v.y, qq);
            qq = fmaf(v.z, v.z, qq); qq = fmaf(v.w, v.w, qq);
        }
        for (int off = 32; off; off >>= 1) { s += __shfl_down(s, off); qq += __shfl_down(qq, off); }
        __shared__ float ls[4], lq[4];
        int w = tid >> 6, lane = tid & 63;
        if (lane == 0) { ls[w] = s; lq[w] = qq; }
        __syncthreads();
        if (tid == 0) {
            unsafeAtomicAdd(sum0 + c, ls[0] + ls[1] + ls[2] + ls[3]);
            unsafeAtomicAdd(sq0 + c, lq[0] + lq[1] + lq[2] + lq[3]);
        }
    } else {                                   // bucket CSR fill (2048 blocks)
        int e = (bid - 672) * 256 + tid;
        int t = ei[Ec + e];
        int slot = atomicAdd(cursor + t, 1);
        bucket[t * 64 + slot] = ei[e];
    }
}

// ================= dispatch 3: xprep: bn0-apply -> hbf + xt =================
__global__ __launch_bounds__(256) void xprep(const float* __restrict__ x,
        const float* __restrict__ sum0, const float* __restrict__ sq0,
        const float* __restrict__ g0, const float* __restrict__ b0,
        __bf16* __restrict__ hbf, __bf16* __restrict__ xt) {
    __shared__ float lds[64][65];
    __shared__ float scs[64], shs[64];
    int tid = threadIdx.x;
    if (tid < 64) {
        float mu = sum0[tid] * (1.f / 32768.f);
        float var = sq0[tid] * (1.f / 32768.f) - mu * mu;
        float rs = rsqrtf(var + 1e-5f);
        float sc = rs * g0[tid];
        scs[tid] = sc; shs[tid] = b0[tid] - mu * sc;
    }
    __syncthreads();
    int t0 = blockIdx.x * 64;
    int b  = blockIdx.y;
    const float* xb = x + (long)b * 65536;
    for (int i = tid; i < 4096; i += 256) {
        int ci = i >> 6, tl = i & 63;
        float v = fmaf(xb[ci * 1024 + t0 + tl], scs[ci], shs[ci]);
        hbf[(long)b * 65536 + ci * 1024 + t0 + tl] = (__bf16)v;
        lds[ci][tl] = v;
    }
    __syncthreads();
    for (int i = tid; i < 4096; i += 256) {
        int t = i >> 6, ci = i & 63;
        xt[((long)b * 1024 + t0 + t) * 64 + ci] = (__bf16)lds[ci][t];
    }
}

// ================= dispatch 4: conv (bid<512) U gemm1 (MFMA) =================
DEVINL void conv_role(int bid, const __bf16* __restrict__ xt,
        const __bf16* __restrict__ wcbf, const float* __restrict__ cb,
        float* __restrict__ res) {
    int wv = threadIdx.x >> 6, lane = threadIdx.x & 63;
    int col = lane & 15, q = lane >> 4;
    int tbase = (bid & 7) * 128;
    int co0 = ((bid >> 3) & 1) * 64 + wv * 16;
    int b = bid >> 4;
    bf16x8 af[18];
    #pragma unroll
    for (int kk = 0; kk < 9; kk++)
        #pragma unroll
        for (int ks = 0; ks < 2; ks++)
            af[kk * 2 + ks] = *(const bf16x8*)(wcbf +
                ((long)kk * 8192 + (long)(co0 + col) * 64 + ks * 32 + q * 8));
    float bi0 = cb[co0 + q * 4], bi1 = cb[co0 + q * 4 + 1];
    float bi2 = cb[co0 + q * 4 + 2], bi3 = cb[co0 + q * 4 + 3];
    const __bf16* xb = xt + (long)b * 65536;
    bf16x8 z8;
    #pragma unroll
    for (int i = 0; i < 8; i++) z8[i] = (__bf16)0.f;
    for (int nt = 0; nt < 8; nt++) {
        int t0 = tbase + nt * 16;
        f32x4 acc; acc[0] = bi0; acc[1] = bi1; acc[2] = bi2; acc[3] = bi3;
        #pragma unroll
        for (int kk = 0; kk < 9; kk++) {
            int tg = t0 + col + kk - 4;
            bool ok = (unsigned)tg < 1024u;
            const bf16x8* bp = (const bf16x8*)(xb + (long)(ok ? tg : 0) * 64 + q * 8);
            bf16x8 bf0 = ok ? bp[0] : z8;
            bf16x8 bf1 = ok ? bp[4] : z8;
            acc = __builtin_amdgcn_mfma_f32_16x16x32_bf16(af[kk * 2],     bf0, acc, 0, 0, 0);
            acc = __builtin_amdgcn_mfma_f32_16x16x32_bf16(af[kk * 2 + 1], bf1, acc, 0, 0, 0);
        }
        long ob = (long)b * 131072 + (long)(co0 + q * 4) * 1024 + t0 + col;
        res[ob]        = fmaxf(acc[0], 0.f);
        res[ob + 1024] = fmaxf(acc[1], 0.f);
        res[ob + 2048] = fmaxf(acc[2], 0.f);
        res[ob + 3072] = fmaxf(acc[3], 0.f);
    }
}

// u16 slot d (d<64) = head0 dim d; slot 64+d = head1 dim d  (per node row of 128 u16)
DEVINL void gemm1_role(int mb, const __bf16* __restrict__ hbf,
        const __bf16* __restrict__ wlrbf,
        unsigned short* __restrict__ xl16, unsigned short* __restrict__ xr16) {
    int wv = threadIdx.x >> 6, lane = threadIdx.x & 63;
    int col = lane & 15, q = lane >> 4;
    int d0 = wv * 16;
    long mbase = (long)mb * 64;
    bf16x8 bfr[4][2];
    #pragma unroll
    for (int t = 0; t < 4; t++) {
        int j = d0 + t * 64 + col;
        #pragma unroll
        for (int ks = 0; ks < 2; ks++)
            bfr[t][ks] = *(const bf16x8*)(wlrbf + (long)j * 64 + ks * 32 + q * 8);
    }
    int d = d0 + col;
    for (int mt = 0; mt < 4; mt++) {
        long r0 = mbase + mt * 16;
        bf16x8 a0 = *(const bf16x8*)(hbf + (r0 + col) * 64 + q * 8);
        bf16x8 a1 = *(const bf16x8*)(hbf + (r0 + col) * 64 + 32 + q * 8);
        f32x4 acc[4];
        #pragma unroll
        for (int t = 0; t < 4; t++) { acc[t][0] = 0.f; acc[t][1] = 0.f; acc[t][2] = 0.f; acc[t][3] = 0.f; }
        #pragma unroll
        for (int t = 0; t < 4; t++) {
            acc[t] = __builtin_amdgcn_mfma_f32_16x16x32_bf16(a0, bfr[t][0], acc[t], 0, 0, 0);
            acc[t] = __builtin_amdgcn_mfma_f32_16x16x32_bf16(a1, bfr[t][1], acc[t], 0, 0, 0);
        }
        #pragma unroll
        for (int reg = 0; reg < 4; reg++) {
            long rb = (r0 + q * 4 + reg) * 128;
            xl16[rb + d]      = (unsigned short)bfb(acc[0][reg]);
            xl16[rb + 64 + d] = (unsigned short)bfb(acc[1][reg]);
            xr16[rb + d]      = (unsigned short)bfb(acc[2][reg]);
            xr16[rb + 64 + d] = (unsigned short)bfb(acc[3][reg]);
        }
    }
}

__global__ __launch_bounds__(256) void conv_gemm1(const __bf16* __restrict__ xt,
        const __bf16* __restrict__ wcbf, const float* __restrict__ cb,
        float* __restrict__ res, const __bf16* __restrict__ hbf,
        const __bf16* __restrict__ wlrbf,
        unsigned* __restrict__ xlq, unsigned* __restrict__ xrq) {
    int bid = blockIdx.x;
    if (bid < 512) conv_role(bid, xt, wcbf, cb, res);
    else gemm1_role(bid - 512, hbf, wlrbf, (unsigned short*)xlq, (unsigned short*)xrq);
}

// ================= dispatch 5: fused GATv2, pipelined =================
// head-split: lane l<32 head0 dims 2l,2l+1; l>=32 head1. 5-shuffle butterfly, 1 exp/edge.
// bucket preloaded in one coalesced load; 4-deep rotating gather prefetch, unroll-4 body.
#define GAT_EDGE(VREG) {                                              \
    float xl_lo = unpack_lo(VREG), xl_hi = unpack_hi(VREG);           \
    float v0 = xl_lo + xr_lo; v0 = fmaxf(v0, 0.2f * v0);              \
    float v1 = xl_hi + xr_hi; v1 = fmaxf(v1, 0.2f * v1);              \
    float w2 = fmaf(v1, a_hi, v0 * a_lo);                             \
    _Pragma("unroll")                                                 \
    for (int off = 16; off; off >>= 1) w2 += __shfl_xor(w2, off);     \
    float e2 = __expf(w2);                                            \
    den += e2;                                                        \
    acc_lo = fmaf(e2, xl_lo, acc_lo);                                 \
    acc_hi = fmaf(e2, xl_hi, acc_hi);                                 \
}

__global__ __launch_bounds__(256) void gat_agg(const unsigned* __restrict__ xlq,
        const unsigned* __restrict__ xrq,
        const int* __restrict__ cursor, const int* __restrict__ bucket,
        const float* __restrict__ att, float* __restrict__ gout) {
    int wid = (blockIdx.x * 256 + threadIdx.x) >> 6;
    int lane = threadIdx.x & 63;
    int h = lane >> 5, dd = (lane & 31) * 2;
    float a_lo = att[h * 64 + dd], a_hi = att[h * 64 + dd + 1];
    int cnt = cursor[wid];
    int s_all = bucket[wid * 64 + lane];       // lane i holds bucket entry i (i>=cnt: garbage, never used)
    unsigned vr = xrq[(long)wid * 64 + lane];
    float xr_lo = unpack_lo(vr), xr_hi = unpack_hi(vr);
    unsigned vs = xlq[(long)wid * 64 + lane];
    float xs_lo = unpack_lo(vs), xs_hi = unpack_hi(vs);
    // self-loop
    float u0 = xs_lo + xr_lo; u0 = fmaxf(u0, 0.2f * u0);
    float u1 = xs_hi + xr_hi; u1 = fmaxf(u1, 0.2f * u1);
    float w = fmaf(u1, a_hi, u0 * a_lo);
    #pragma unroll
    for (int off = 16; off; off >>= 1) w += __shfl_xor(w, off);
    float e = __expf(w);
    float den = e, acc_lo = e * xs_lo, acc_hi = e * xs_hi;
    // prime 4-deep prefetch
    unsigned pf0 = 0, pf1 = 0, pf2 = 0, pf3 = 0;
    {
        int s0 = __shfl(s_all, 0), s1 = __shfl(s_all, 1);
        int s2 = __shfl(s_all, 2), s3 = __shfl(s_all, 3);
        if (0 < cnt) pf0 = xlq[(long)s0 * 64 + lane];
        if (1 < cnt) pf1 = xlq[(long)s1 * 64 + lane];
        if (2 < cnt) pf2 = xlq[(long)s2 * 64 + lane];
        if (3 < cnt) pf3 = xlq[(long)s3 * 64 + lane];
    }
    int i = 0;
    for (; i + 4 <= cnt; i += 4) {
        unsigned v0 = pf0, v1 = pf1, v2 = pf2, v3 = pf3;
        int s4 = __shfl(s_all, i + 4), s5 = __shfl(s_all, i + 5);
        int s6 = __shfl(s_all, i + 6), s7 = __shfl(s_all, i + 7);
        if (i + 4 < cnt) pf0 = xlq[(long)s4 * 64 + lane];
        if (i + 5 < cnt) pf1 = xlq[(long)s5 * 64 + lane];
        if (i + 6 < cnt) pf2 = xlq[(long)s6 * 64 + lane];
        if (i + 7 < cnt) pf3 = xlq[(long)s7 * 64 + lane];
        GAT_EDGE(v0) GAT_EDGE(v1) GAT_EDGE(v2) GAT_EDGE(v3)
    }
    // tail (<4): use remaining prefetched regs in order
    if (i < cnt) { GAT_EDGE(pf0) i++;
        if (i < cnt) { GAT_EDGE(pf1) i++;
            if (i < cnt) { GAT_EDGE(pf2) } } }
    float rn = __builtin_amdgcn_rcpf(den);
    float2 o; o.x = acc_lo * rn; o.y = acc_hi * rn;
    *(float2*)(gout + (long)wid * 128 + h * 64 + dd) = o;
}

// ================= bn over [N,128] (axis 0) =================
__global__ __launch_bounds__(256) void bn_stats(const float* __restrict__ X,
        float* __restrict__ sum, float* __restrict__ sq) {
    int f = threadIdx.x & 127, sub = threadIdx.x >> 7;
    int r0 = blockIdx.x * 256;
    float s = 0.f, q = 0.f;
    for (int r = r0 + sub; r < r0 + 256; r += 2) {
        float v = X[(long)r * 128 + f];
        s += v; q = fmaf(v, v, q);
    }
    __shared__ float ls[256], lq[256];
    ls[threadIdx.x] = s; lq[threadIdx.x] = q;
    __syncthreads();
    if (threadIdx.x < 128) {
        s = ls[threadIdx.x] + ls[threadIdx.x + 128];
        q = lq[threadIdx.x] + lq[threadIdx.x + 128];
        unsafeAtomicAdd(sum + f, s);
        unsafeAtomicAdd(sq + f, q);
    }
}

// res + relu(bn(X)) -> bf16 (cheb input)
__global__ __launch_bounds__(256) void bn_res_bf(const float* __restrict__ X,
        const float* __restrict__ res, const float* __restrict__ sum,
        const float* __restrict__ sq, const float* __restrict__ g,
        const float* __restrict__ bta, unsigned* __restrict__ outb) {
    __shared__ float scs[128], shs[128];
    int tid = threadIdx.x;
    if (tid < 128) {
        float mu = sum[tid] * (1.f / 32768.f);
        float var = sq[tid] * (1.f / 32768.f) - mu * mu;
        float rs = rsqrtf(var + 1e-5f);
        float sc = rs * g[tid];
        scs[tid] = sc; shs[tid] = bta[tid] - mu * sc;
    }
    __syncthreads();
    int idx = blockIdx.x * 256 + tid;
    int f0 = (idx & 31) * 4;
    float4 v = ((const float4*)X)[idx];
    float4 r = ((const float4*)res)[idx];
    float o0 = r.x + fmaxf(fmaf(v.x, scs[f0],     shs[f0]),     0.f);
    float o1 = r.y + fmaxf(fmaf(v.y, scs[f0 + 1], shs[f0 + 1]), 0.f);
    float o2 = r.z + fmaxf(fmaf(v.z, scs[f0 + 2], shs[f0 + 2]), 0.f);
    float o3 = r.w + fmaxf(fmaf(v.w, scs[f0 + 3], shs[f0 + 3]), 0.f);
    uint2 o; o.x = (bfb(o1) << 16) | bfb(o0); o.y = (bfb(o3) << 16) | bfb(o2);
    ((uint2*)outb)[idx] = o;
}

// res + relu(bn(X)) -> fp32 (final output)
__global__ __launch_bounds__(256) void bn_res(const float* __restrict__ X,
        const float* __restrict__ res, const float* __restrict__ sum,
        const float* __restrict__ sq, const float* __restrict__ g,
        const float* __restrict__ bta, float* __restrict__ out) {
    __shared__ float scs[128], shs[128];
    int tid = threadIdx.x;
    if (tid < 128) {
        float mu = sum[tid] * (1.f / 32768.f);
        float var = sq[tid] * (1.f / 32768.f) - mu * mu;
        float rs = rsqrtf(var + 1e-5f);
        float sc = rs * g[tid];
        scs[tid] = sc; shs[tid] = bta[tid] - mu * sc;
    }
    __syncthreads();
    int idx = blockIdx.x * 256 + tid;
    int f0 = (idx & 31) * 4;
    float4 v = ((const float4*)X)[idx];
    float4 r = ((const float4*)res)[idx];
    float4 o;
    o.x = r.x + fmaxf(fmaf(v.x, scs[f0],     shs[f0]),     0.f);
    o.y = r.y + fmaxf(fmaf(v.y, scs[f0 + 1], shs[f0 + 1]), 0.f);
    o.z = r.z + fmaxf(fmaf(v.z, scs[f0 + 2], shs[f0 + 2]), 0.f);
    o.w = r.w + fmaxf(fmaf(v.w, scs[f0 + 3], shs[f0 + 3]), 0.f);
    ((float4*)out)[idx] = o;
}

// ================= cheb via MFMA: z = h2bf @ chwbf^T =================
__global__ __launch_bounds__(256) void cheb_mfma(const __bf16* __restrict__ h2bf,
        const __bf16* __restrict__ chwbf, float* __restrict__ z) {
    int wv = threadIdx.x >> 6, lane = threadIdx.x & 63;
    int col = lane & 15, q = lane >> 4;
    long mbase = (long)blockIdx.x * 64;
    bf16x8 bfr[2][4];
    #pragma unroll
    for (int t = 0; t < 2; t++) {
        int j = wv * 16 + t * 64 + col;
        #pragma unroll
        for (int ks = 0; ks < 4; ks++)
            bfr[t][ks] = *(const bf16x8*)(chwbf + (long)j * 128 + ks * 32 + q * 8);
    }
    for (int mt = 0; mt < 4; mt++) {
        long r0 = mbase + mt * 16;
        bf16x8 a[4];
        #pragma unroll
        for (int ks = 0; ks < 4; ks++)
            a[ks] = *(const bf16x8*)(h2bf + (r0 + col) * 128 + ks * 32 + q * 8);
        f32x4 acc[2];
        #pragma unroll
        for (int t = 0; t < 2; t++) { acc[t][0] = 0.f; acc[t][1] = 0.f; acc[t][2] = 0.f; acc[t][3] = 0.f; }
        #pragma unroll
        for (int t = 0; t < 2; t++)
            #pragma unroll
            for (int ks = 0; ks < 4; ks++)
                acc[t] = __builtin_amdgcn_mfma_f32_16x16x32_bf16(a[ks], bfr[t][ks], acc[t], 0, 0, 0);
        #pragma unroll
        for (int t = 0; t < 2; t++)
            #pragma unroll
            for (int reg = 0; reg < 4; reg++)
                z[(r0 + q * 4 + reg) * 128 + wv * 16 + t * 64 + col] = acc[t][reg];
    }
}

extern "C" void kernel_launch(void* const* d_in, const int* in_sizes, int n_in,
                              void* d_out, int out_size, void* d_ws, size_t ws_size,
                              hipStream_t stream) {
    const float* x   = (const float*)d_in[0];
    const int*   ei  = (const int*)d_in[1];
    const float* g0  = (const float*)d_in[2];
    const float* b0  = (const float*)d_in[3];
    const float* cw  = (const float*)d_in[4];
    const float* cb  = (const float*)d_in[5];
    const float* wl  = (const float*)d_in[6];
    const float* wr  = (const float*)d_in[7];
    const float* att = (const float*)d_in[8];
    // d_in[9] = gat_bias: cancels exactly inside the following bn2d -> unused
    const float* g1  = (const float*)d_in[10];
    const float* b1  = (const float*)d_in[11];
    const float* chw = (const float*)d_in[12];
    // d_in[13] = cheb_b: cancels inside the following bn2d -> unused
    float* out = (float*)d_out;

    float* ws = (float*)d_ws;
    float*    res   = ws + O_RES;
    float*    gout  = ws + O_GOUT;
    __bf16*   xt    = (__bf16*)(ws + O_XT);
    __bf16*   hbf   = (__bf16*)(ws + O_HBF);
    unsigned* xlq   = (unsigned*)(ws + O_XLQ);
    unsigned* xrq   = (unsigned*)(ws + O_XRQ);
    unsigned* h2bf  = (unsigned*)(ws + O_H2BF);
    float*    z     = ws + O_Z;
    __bf16*   wcbf  = (__bf16*)(ws + O_WCBF);
    __bf16*   wlrbf = (__bf16*)(ws + O_WLR);
    __bf16*   chwbf = (__bf16*)(ws + O_CHB);
    float*    st    = ws + O_STAT;
    int*      cursor = (int*)(ws + O_CUR);
    int*      bucket = (int*)(ws + O_BUCK);
    float *sum0 = st,       *sq0 = st + 64;
    float *sum1 = st + 128, *sq1 = st + 256;
    float *sum2 = st + 384, *sq2 = st + 512;

    // one memset covers stat block (4KB) + cursor (128KB), contiguous
    hipMemsetAsync(st, 0, (size_t)(1024 + 32768) * 4, stream);

    // prep_w U bn0_sums U bucket_fill
    setup<<<2720, 256, 0, stream>>>(x, cw, wl, wr, chw, ei,
                                    wcbf, wlrbf, chwbf, sum0, sq0, cursor, bucket);
    // bn0-apply -> bf16 (flat + transposed)
    xprep<<<dim3(16, 32), 256, 0, stream>>>(x, sum0, sq0, g0, b0, hbf, xt);
    // conv1d+relu->res U gemm1->xlq/xrq (MFMA)
    conv_gemm1<<<1024, 256, 0, stream>>>(xt, wcbf, cb, res, hbf, wlrbf, xlq, xrq);
    // fused GATv2 (pipelined)
    gat_agg<<<8192, 256, 0, stream>>>(xlq, xrq, cursor, bucket, att, gout);
    // bn1 + relu + residual -> h2 (bf16)
    bn_stats<<<128, 256, 0, stream>>>(gout, sum1, sq1);
    bn_res_bf<<<4096, 256, 0, stream>>>(gout, res, sum1, sq1, g1, b1, h2bf);
    // cheb linear (MFMA)
    cheb_mfma<<<512, 256, 0, stream>>>((const __bf16*)h2bf, chwbf, z);
    // bn1 again + relu + residual -> out
    bn_stats<<<128, 256, 0, stream>>>(z, sum2, sq2);
    bn_res<<<4096, 256, 0, stream>>>(z, res, sum2, sq2, g1, b1, out);
}

// Round 9
// 273.748 us; speedup vs baseline: 2.5677x; 1.0825x over previous
//
#include <hip/hip_runtime.h>

#define DEVINL __device__ __forceinline__

constexpr int Bc = 32, Cc = 64, Tc = 1024, DIM2c = 128;
constexpr int Nn = Bc * Tc;            // 32768 nodes
constexpr int Ec = 524288;             // edges (self-loops handled in-kernel)

typedef __bf16 bf16x8 __attribute__((ext_vector_type(8)));
typedef __bf16 bf16x4 __attribute__((ext_vector_type(4)));
typedef float  f32x4  __attribute__((ext_vector_type(4)));

// workspace layout (float offsets)
constexpr long O_RES   = 0;            // 4194304 fp32
constexpr long O_GOUT  = 4194304;      // 4194304 fp32
constexpr long O_XT    = 8388608;      // bf16 x 2097152: [b*1024+t][ci]
constexpr long O_HBF   = 9437184;      // bf16 x 2097152: flat bn0(x)
constexpr long O_XLQ   = 10485760;     // 2097152 uint (head-split bf16, u16[n][128])
constexpr long O_XRQ   = 12582912;     // 2097152 uint
constexpr long O_H2BF  = 14680064;     // bf16 x 4194304: [n][128]
constexpr long O_Z     = 16777216;     // 4194304 fp32
constexpr long O_WCBF  = 20971520;     // bf16 x 73728: [kk][co][ci]
constexpr long O_WLR   = 21008384;     // bf16 x 16384: [j 256][c 64]
constexpr long O_CHB   = 21016576;     // bf16 x 16384: [j 128][c 128]
constexpr long O_STAT  = 21024768;     // 1024 (zeroed by memset)
constexpr long O_CUR   = 21025792;     // 32768 ints (zeroed, contiguous w/ STAT)
constexpr long O_BUCK  = 21058560;     // 2097152 ints

DEVINL float unpack_lo(unsigned v) { return __uint_as_float(v << 16); }
DEVINL float unpack_hi(unsigned v) { return __uint_as_float(v & 0xffff0000u); }
DEVINL unsigned bfb(float f) { return (__float_as_uint(f) + 0x8000u) >> 16; }

// ================= setup = prep_w U bn0_sums U bucket_fill =================
__global__ __launch_bounds__(256) void setup(const float* __restrict__ x,
        const float* __restrict__ cw, const float* __restrict__ wl,
        const float* __restrict__ wr, const float* __restrict__ chw,
        const int* __restrict__ ei,
        __bf16* __restrict__ wcbf, __bf16* __restrict__ wlrbf,
        __bf16* __restrict__ chwbf,
        float* __restrict__ sum0, float* __restrict__ sq0,
        int* __restrict__ cursor, int* __restrict__ bucket) {
    int bid = blockIdx.x, tid = threadIdx.x;
    if (bid < 416) {                           // weight prep (106496 items exactly)
        int i = bid * 256 + tid;
        if (i < 73728) {                       // wcbf[kk][co][ci] = cw[co][ci*9+kk]
            int kk = i >> 13, co = (i >> 6) & 127, ci = i & 63;
            wcbf[i] = (__bf16)cw[co * 576 + ci * 9 + kk];
        } else if (i < 73728 + 16384) {        // wlrbf[j][c]
            int j = i - 73728;
            int r = j >> 6, c = j & 63;
            float v = (r < 128) ? wl[r * 64 + c] : wr[(r - 128) * 64 + c];
            wlrbf[j] = (__bf16)v;
        } else {                               // chwbf[j][c]
            int j = i - 73728 - 16384;
            chwbf[j] = (__bf16)chw[j];
        }
    } else if (bid < 672) {                    // bn0 sums (atomics into memset-zeroed stat)
        int pq = bid - 416;
        int c = pq & 63, q = pq >> 6;
        const float4* base = (const float4*)(x + (long)q * 8 * 65536 + (long)c * 1024);
        float s = 0.f, qq = 0.f;
        for (int i = tid; i < 2048; i += 256) {
            int b = i >> 8, t4 = i & 255;
            float4 v = base[b * 16384 + t4];
            s += v.x + v.y + v.z + v.w;
            qq = fmaf(v.x, v.x, qq); qq = fmaf(v.y, v.y, qq);
            qq = fmaf(v.z, v.z, qq); qq = fmaf(v.w, v.w, qq);
        }
        for (int off = 32; off; off >>= 1) { s += __shfl_down(s, off); qq += __shfl_down(qq, off); }
        __shared__ float ls[4], lq[4];
        int w = tid >> 6, lane = tid & 63;
        if (lane == 0) { ls[w] = s; lq[w] = qq; }
        __syncthreads();
        if (tid == 0) {
            unsafeAtomicAdd(sum0 + c, ls[0] + ls[1] + ls[2] + ls[3]);
            unsafeAtomicAdd(sq0 + c, lq[0] + lq[1] + lq[2] + lq[3]);
        }
    } else {                                   // bucket CSR fill (2048 blocks)
        int e = (bid - 672) * 256 + tid;
        int t = ei[Ec + e];
        int slot = atomicAdd(cursor + t, 1);
        bucket[t * 64 + slot] = ei[e];
    }
}

// ================= xprep: bn0-apply -> hbf + xt =================
__global__ __launch_bounds__(256) void xprep(const float* __restrict__ x,
        const float* __restrict__ sum0, const float* __restrict__ sq0,
        const float* __restrict__ g0, const float* __restrict__ b0,
        __bf16* __restrict__ hbf, __bf16* __restrict__ xt) {
    __shared__ float lds[64][65];
    __shared__ float scs[64], shs[64];
    int tid = threadIdx.x;
    if (tid < 64) {
        float mu = sum0[tid] * (1.f / 32768.f);
        float var = sq0[tid] * (1.f / 32768.f) - mu * mu;
        float rs = rsqrtf(var + 1e-5f);
        float sc = rs * g0[tid];
        scs[tid] = sc; shs[tid] = b0[tid] - mu * sc;
    }
    __syncthreads();
    int t0 = blockIdx.x * 64;
    int b  = blockIdx.y;
    const float* xb = x + (long)b * 65536;
    for (int i = tid; i < 4096; i += 256) {
        int ci = i >> 6, tl = i & 63;
        float v = fmaf(xb[ci * 1024 + t0 + tl], scs[ci], shs[ci]);
        hbf[(long)b * 65536 + ci * 1024 + t0 + tl] = (__bf16)v;
        lds[ci][tl] = v;
    }
    __syncthreads();
    for (int i = tid; i < 4096; i += 256) {
        int t = i >> 6, ci = i & 63;
        xt[((long)b * 1024 + t0 + t) * 64 + ci] = (__bf16)lds[ci][t];
    }
}

// ================= conv (LDS-staged) U gemm1 (MFMA), interleaved roles =================
constexpr int XS_STRIDE = 68;          // bf16 units; 136 B rows (8 B aligned, ~4-way worst)

DEVINL void conv_role(int cid, const __bf16* __restrict__ xt,
        const __bf16* __restrict__ wcbf, const float* __restrict__ cb,
        float* __restrict__ res, __bf16* xs) {
    int tid = threadIdx.x;
    int tbase = (cid & 7) * 128;
    int cohalf = (cid >> 3) & 1;
    int b = cid >> 4;
    // stage 136 t-rows x 64 ci into LDS (shared across the block's 4 waves)
    const uint2* xg = (const uint2*)(xt + (long)b * 65536);
    for (int i = tid; i < 136 * 16; i += 256) {
        int row = i >> 4, c4 = i & 15;        // 8 B = 4 bf16 chunks
        int t = tbase + row - 4;
        uint2 v; v.x = 0u; v.y = 0u;
        if ((unsigned)t < 1024u) v = xg[t * 16 + c4];
        *(uint2*)(xs + row * XS_STRIDE + c4 * 4) = v;
    }
    __syncthreads();
    int wv = tid >> 6, lane = tid & 63;
    int col = lane & 15, q = lane >> 4;
    int co0 = cohalf * 64 + wv * 16;
    bf16x8 af[18];
    #pragma unroll
    for (int kk = 0; kk < 9; kk++)
        #pragma unroll
        for (int ks = 0; ks < 2; ks++)
            af[kk * 2 + ks] = *(const bf16x8*)(wcbf +
                ((long)kk * 8192 + (long)(co0 + col) * 64 + ks * 32 + q * 8));
    float bi0 = cb[co0 + q * 4], bi1 = cb[co0 + q * 4 + 1];
    float bi2 = cb[co0 + q * 4 + 2], bi3 = cb[co0 + q * 4 + 3];
    for (int nt = 0; nt < 8; nt++) {
        int t0 = tbase + nt * 16;
        f32x4 acc; acc[0] = bi0; acc[1] = bi1; acc[2] = bi2; acc[3] = bi3;
        #pragma unroll
        for (int kk = 0; kk < 9; kk++) {
            const __bf16* rp = xs + (nt * 16 + col + kk) * XS_STRIDE + q * 8;
            #pragma unroll
            for (int ks = 0; ks < 2; ks++) {
                bf16x4 lo = *(const bf16x4*)(rp + ks * 32);
                bf16x4 hi = *(const bf16x4*)(rp + ks * 32 + 4);
                bf16x8 bfx;
                bfx[0]=lo[0]; bfx[1]=lo[1]; bfx[2]=lo[2]; bfx[3]=lo[3];
                bfx[4]=hi[0]; bfx[5]=hi[1]; bfx[6]=hi[2]; bfx[7]=hi[3];
                acc = __builtin_amdgcn_mfma_f32_16x16x32_bf16(af[kk * 2 + ks], bfx, acc, 0, 0, 0);
            }
        }
        long ob = (long)b * 131072 + (long)(co0 + q * 4) * 1024 + t0 + col;
        res[ob]        = fmaxf(acc[0], 0.f);
        res[ob + 1024] = fmaxf(acc[1], 0.f);
        res[ob + 2048] = fmaxf(acc[2], 0.f);
        res[ob + 3072] = fmaxf(acc[3], 0.f);
    }
}

// u16 slot d (d<64) = head0 dim d; slot 64+d = head1 dim d  (per node row of 128 u16)
DEVINL void gemm1_role(int mb, const __bf16* __restrict__ hbf,
        const __bf16* __restrict__ wlrbf,
        unsigned short* __restrict__ xl16, unsigned short* __restrict__ xr16) {
    int wv = threadIdx.x >> 6, lane = threadIdx.x & 63;
    int col = lane & 15, q = lane >> 4;
    int d0 = wv * 16;
    long mbase = (long)mb * 64;
    bf16x8 bfr[4][2];
    #pragma unroll
    for (int t = 0; t < 4; t++) {
        int j = d0 + t * 64 + col;
        #pragma unroll
        for (int ks = 0; ks < 2; ks++)
            bfr[t][ks] = *(const bf16x8*)(wlrbf + (long)j * 64 + ks * 32 + q * 8);
    }
    int d = d0 + col;
    for (int mt = 0; mt < 4; mt++) {
        long r0 = mbase + mt * 16;
        bf16x8 a0 = *(const bf16x8*)(hbf + (r0 + col) * 64 + q * 8);
        bf16x8 a1 = *(const bf16x8*)(hbf + (r0 + col) * 64 + 32 + q * 8);
        f32x4 acc[4];
        #pragma unroll
        for (int t = 0; t < 4; t++) { acc[t][0] = 0.f; acc[t][1] = 0.f; acc[t][2] = 0.f; acc[t][3] = 0.f; }
        #pragma unroll
        for (int t = 0; t < 4; t++) {
            acc[t] = __builtin_amdgcn_mfma_f32_16x16x32_bf16(a0, bfr[t][0], acc[t], 0, 0, 0);
            acc[t] = __builtin_amdgcn_mfma_f32_16x16x32_bf16(a1, bfr[t][1], acc[t], 0, 0, 0);
        }
        #pragma unroll
        for (int reg = 0; reg < 4; reg++) {
            long rb = (r0 + q * 4 + reg) * 128;
            xl16[rb + d]      = (unsigned short)bfb(acc[0][reg]);
            xl16[rb + 64 + d] = (unsigned short)bfb(acc[1][reg]);
            xr16[rb + d]      = (unsigned short)bfb(acc[2][reg]);
            xr16[rb + 64 + d] = (unsigned short)bfb(acc[3][reg]);
        }
    }
}

__global__ __launch_bounds__(256) void conv_gemm1(const __bf16* __restrict__ xt,
        const __bf16* __restrict__ wcbf, const float* __restrict__ cb,
        float* __restrict__ res, const __bf16* __restrict__ hbf,
        const __bf16* __restrict__ wlrbf,
        unsigned* __restrict__ xlq, unsigned* __restrict__ xrq) {
    __shared__ __bf16 xs[136 * XS_STRIDE];
    int bid = blockIdx.x;
    if (bid & 1) gemm1_role(bid >> 1, hbf, wlrbf, (unsigned short*)xlq, (unsigned short*)xrq);
    else conv_role(bid >> 1, xt, wcbf, cb, res, xs);
}

// ================= fused GATv2, pipelined =================
#define GAT_EDGE(VREG) {                                              \
    float xl_lo = unpack_lo(VREG), xl_hi = unpack_hi(VREG);           \
    float v0 = xl_lo + xr_lo; v0 = fmaxf(v0, 0.2f * v0);              \
    float v1 = xl_hi + xr_hi; v1 = fmaxf(v1, 0.2f * v1);              \
    float w2 = fmaf(v1, a_hi, v0 * a_lo);                             \
    _Pragma("unroll")                                                 \
    for (int off = 16; off; off >>= 1) w2 += __shfl_xor(w2, off);     \
    float e2 = __expf(w2);                                            \
    den += e2;                                                        \
    acc_lo = fmaf(e2, xl_lo, acc_lo);                                 \
    acc_hi = fmaf(e2, xl_hi, acc_hi);                                 \
}

__global__ __launch_bounds__(256) void gat_agg(const unsigned* __restrict__ xlq,
        const unsigned* __restrict__ xrq,
        const int* __restrict__ cursor, const int* __restrict__ bucket,
        const float* __restrict__ att, float* __restrict__ gout) {
    int wid = (blockIdx.x * 256 + threadIdx.x) >> 6;
    int lane = threadIdx.x & 63;
    int h = lane >> 5, dd = (lane & 31) * 2;
    float a_lo = att[h * 64 + dd], a_hi = att[h * 64 + dd + 1];
    int cnt = cursor[wid];
    int s_all = bucket[wid * 64 + lane];
    unsigned vr = xrq[(long)wid * 64 + lane];
    float xr_lo = unpack_lo(vr), xr_hi = unpack_hi(vr);
    unsigned vs = xlq[(long)wid * 64 + lane];
    float xs_lo = unpack_lo(vs), xs_hi = unpack_hi(vs);
    float u0 = xs_lo + xr_lo; u0 = fmaxf(u0, 0.2f * u0);
    float u1 = xs_hi + xr_hi; u1 = fmaxf(u1, 0.2f * u1);
    float w = fmaf(u1, a_hi, u0 * a_lo);
    #pragma unroll
    for (int off = 16; off; off >>= 1) w += __shfl_xor(w, off);
    float e = __expf(w);
    float den = e, acc_lo = e * xs_lo, acc_hi = e * xs_hi;
    unsigned pf0 = 0, pf1 = 0, pf2 = 0, pf3 = 0;
    {
        int s0 = __shfl(s_all, 0), s1 = __shfl(s_all, 1);
        int s2 = __shfl(s_all, 2), s3 = __shfl(s_all, 3);
        if (0 < cnt) pf0 = xlq[(long)s0 * 64 + lane];
        if (1 < cnt) pf1 = xlq[(long)s1 * 64 + lane];
        if (2 < cnt) pf2 = xlq[(long)s2 * 64 + lane];
        if (3 < cnt) pf3 = xlq[(long)s3 * 64 + lane];
    }
    int i = 0;
    for (; i + 4 <= cnt; i += 4) {
        unsigned v0 = pf0, v1 = pf1, v2 = pf2, v3 = pf3;
        int s4 = __shfl(s_all, i + 4), s5 = __shfl(s_all, i + 5);
        int s6 = __shfl(s_all, i + 6), s7 = __shfl(s_all, i + 7);
        if (i + 4 < cnt) pf0 = xlq[(long)s4 * 64 + lane];
        if (i + 5 < cnt) pf1 = xlq[(long)s5 * 64 + lane];
        if (i + 6 < cnt) pf2 = xlq[(long)s6 * 64 + lane];
        if (i + 7 < cnt) pf3 = xlq[(long)s7 * 64 + lane];
        GAT_EDGE(v0) GAT_EDGE(v1) GAT_EDGE(v2) GAT_EDGE(v3)
    }
    if (i < cnt) { GAT_EDGE(pf0) i++;
        if (i < cnt) { GAT_EDGE(pf1) i++;
            if (i < cnt) { GAT_EDGE(pf2) } } }
    float rn = __builtin_amdgcn_rcpf(den);
    float2 o; o.x = acc_lo * rn; o.y = acc_hi * rn;
    *(float2*)(gout + (long)wid * 128 + h * 64 + dd) = o;
}

// ================= bn over [N,128] (axis 0) =================
__global__ __launch_bounds__(256) void bn_stats(const float* __restrict__ X,
        float* __restrict__ sum, float* __restrict__ sq) {
    int f = threadIdx.x & 127, sub = threadIdx.x >> 7;
    int r0 = blockIdx.x * 256;
    float s = 0.f, q = 0.f;
    for (int r = r0 + sub; r < r0 + 256; r += 2) {
        float v = X[(long)r * 128 + f];
        s += v; q = fmaf(v, v, q);
    }
    __shared__ float ls[256], lq[256];
    ls[threadIdx.x] = s; lq[threadIdx.x] = q;
    __syncthreads();
    if (threadIdx.x < 128) {
        s = ls[threadIdx.x] + ls[threadIdx.x + 128];
        q = lq[threadIdx.x] + lq[threadIdx.x + 128];
        unsafeAtomicAdd(sum + f, s);
        unsafeAtomicAdd(sq + f, q);
    }
}

// res + relu(bn(X)) -> bf16 (cheb input)
__global__ __launch_bounds__(256) void bn_res_bf(const float* __restrict__ X,
        const float* __restrict__ res, const float* __restrict__ sum,
        const float* __restrict__ sq, const float* __restrict__ g,
        const float* __restrict__ bta, unsigned* __restrict__ outb) {
    __shared__ float scs[128], shs[128];
    int tid = threadIdx.x;
    if (tid < 128) {
        float mu = sum[tid] * (1.f / 32768.f);
        float var = sq[tid] * (1.f / 32768.f) - mu * mu;
        float rs = rsqrtf(var + 1e-5f);
        float sc = rs * g[tid];
        scs[tid] = sc; shs[tid] = bta[tid] - mu * sc;
    }
    __syncthreads();
    int idx = blockIdx.x * 256 + tid;
    int f0 = (idx & 31) * 4;
    float4 v = ((const float4*)X)[idx];
    float4 r = ((const float4*)res)[idx];
    float o0 = r.x + fmaxf(fmaf(v.x, scs[f0],     shs[f0]),     0.f);
    float o1 = r.y + fmaxf(fmaf(v.y, scs[f0 + 1], shs[f0 + 1]), 0.f);
    float o2 = r.z + fmaxf(fmaf(v.z, scs[f0 + 2], shs[f0 + 2]), 0.f);
    float o3 = r.w + fmaxf(fmaf(v.w, scs[f0 + 3], shs[f0 + 3]), 0.f);
    uint2 o; o.x = (bfb(o1) << 16) | bfb(o0); o.y = (bfb(o3) << 16) | bfb(o2);
    ((uint2*)outb)[idx] = o;
}

// res + relu(bn(X)) -> fp32 (final output)
__global__ __launch_bounds__(256) void bn_res(const float* __restrict__ X,
        const float* __restrict__ res, const float* __restrict__ sum,
        const float* __restrict__ sq, const float* __restrict__ g,
        const float* __restrict__ bta, float* __restrict__ out) {
    __shared__ float scs[128], shs[128];
    int tid = threadIdx.x;
    if (tid < 128) {
        float mu = sum[tid] * (1.f / 32768.f);
        float var = sq[tid] * (1.f / 32768.f) - mu * mu;
        float rs = rsqrtf(var + 1e-5f);
        float sc = rs * g[tid];
        scs[tid] = sc; shs[tid] = bta[tid] - mu * sc;
    }
    __syncthreads();
    int idx = blockIdx.x * 256 + tid;
    int f0 = (idx & 31) * 4;
    float4 v = ((const float4*)X)[idx];
    float4 r = ((const float4*)res)[idx];
    float4 o;
    o.x = r.x + fmaxf(fmaf(v.x, scs[f0],     shs[f0]),     0.f);
    o.y = r.y + fmaxf(fmaf(v.y, scs[f0 + 1], shs[f0 + 1]), 0.f);
    o.z = r.z + fmaxf(fmaf(v.z, scs[f0 + 2], shs[f0 + 2]), 0.f);
    o.w = r.w + fmaxf(fmaf(v.w, scs[f0 + 3], shs[f0 + 3]), 0.f);
    ((float4*)out)[idx] = o;
}

// ================= cheb via MFMA: z = h2bf @ chwbf^T =================
__global__ __launch_bounds__(256) void cheb_mfma(const __bf16* __restrict__ h2bf,
        const __bf16* __restrict__ chwbf, float* __restrict__ z) {
    int wv = threadIdx.x >> 6, lane = threadIdx.x & 63;
    int col = lane & 15, q = lane >> 4;
    long mbase = (long)blockIdx.x * 64;
    bf16x8 bfr[2][4];
    #pragma unroll
    for (int t = 0; t < 2; t++) {
        int j = wv * 16 + t * 64 + col;
        #pragma unroll
        for (int ks = 0; ks < 4; ks++)
            bfr[t][ks] = *(const bf16x8*)(chwbf + (long)j * 128 + ks * 32 + q * 8);
    }
    for (int mt = 0; mt < 4; mt++) {
        long r0 = mbase + mt * 16;
        bf16x8 a[4];
        #pragma unroll
        for (int ks = 0; ks < 4; ks++)
            a[ks] = *(const bf16x8*)(h2bf + (r0 + col) * 128 + ks * 32 + q * 8);
        f32x4 acc[2];
        #pragma unroll
        for (int t = 0; t < 2; t++) { acc[t][0] = 0.f; acc[t][1] = 0.f; acc[t][2] = 0.f; acc[t][3] = 0.f; }
        #pragma unroll
        for (int t = 0; t < 2; t++)
            #pragma unroll
            for (int ks = 0; ks < 4; ks++)
                acc[t] = __builtin_amdgcn_mfma_f32_16x16x32_bf16(a[ks], bfr[t][ks], acc[t], 0, 0, 0);
        #pragma unroll
        for (int t = 0; t < 2; t++)
            #pragma unroll
            for (int reg = 0; reg < 4; reg++)
                z[(r0 + q * 4 + reg) * 128 + wv * 16 + t * 64 + col] = acc[t][reg];
    }
}

extern "C" void kernel_launch(void* const* d_in, const int* in_sizes, int n_in,
                              void* d_out, int out_size, void* d_ws, size_t ws_size,
                              hipStream_t stream) {
    const float* x   = (const float*)d_in[0];
    const int*   ei  = (const int*)d_in[1];
    const float* g0  = (const float*)d_in[2];
    const float* b0  = (const float*)d_in[3];
    const float* cw  = (const float*)d_in[4];
    const float* cb  = (const float*)d_in[5];
    const float* wl  = (const float*)d_in[6];
    const float* wr  = (const float*)d_in[7];
    const float* att = (const float*)d_in[8];
    // d_in[9] = gat_bias: cancels exactly inside the following bn2d -> unused
    const float* g1  = (const float*)d_in[10];
    const float* b1  = (const float*)d_in[11];
    const float* chw = (const float*)d_in[12];
    // d_in[13] = cheb_b: cancels inside the following bn2d -> unused
    float* out = (float*)d_out;

    float* ws = (float*)d_ws;
    float*    res   = ws + O_RES;
    float*    gout  = ws + O_GOUT;
    __bf16*   xt    = (__bf16*)(ws + O_XT);
    __bf16*   hbf   = (__bf16*)(ws + O_HBF);
    unsigned* xlq   = (unsigned*)(ws + O_XLQ);
    unsigned* xrq   = (unsigned*)(ws + O_XRQ);
    unsigned* h2bf  = (unsigned*)(ws + O_H2BF);
    float*    z     = ws + O_Z;
    __bf16*   wcbf  = (__bf16*)(ws + O_WCBF);
    __bf16*   wlrbf = (__bf16*)(ws + O_WLR);
    __bf16*   chwbf = (__bf16*)(ws + O_CHB);
    float*    st    = ws + O_STAT;
    int*      cursor = (int*)(ws + O_CUR);
    int*      bucket = (int*)(ws + O_BUCK);
    float *sum0 = st,       *sq0 = st + 64;
    float *sum1 = st + 128, *sq1 = st + 256;
    float *sum2 = st + 384, *sq2 = st + 512;

    // one memset covers stat block (4KB) + cursor (128KB), contiguous
    hipMemsetAsync(st, 0, (size_t)(1024 + 32768) * 4, stream);

    // prep_w U bn0_sums U bucket_fill
    setup<<<2720, 256, 0, stream>>>(x, cw, wl, wr, chw, ei,
                                    wcbf, wlrbf, chwbf, sum0, sq0, cursor, bucket);
    // bn0-apply -> bf16 (flat + transposed)
    xprep<<<dim3(16, 32), 256, 0, stream>>>(x, sum0, sq0, g0, b0, hbf, xt);
    // conv1d+relu->res U gemm1->xlq/xrq (MFMA, interleaved roles, LDS-staged conv)
    conv_gemm1<<<1024, 256, 0, stream>>>(xt, wcbf, cb, res, hbf, wlrbf, xlq, xrq);
    // fused GATv2 (pipelined)
    gat_agg<<<8192, 256, 0, stream>>>(xlq, xrq, cursor, bucket, att, gout);
    // bn1 + relu + residual -> h2 (bf16)
    bn_stats<<<128, 256, 0, stream>>>(gout, sum1, sq1);
    bn_res_bf<<<4096, 256, 0, stream>>>(gout, res, sum1, sq1, g1, b1, h2bf);
    // cheb linear (MFMA)
    cheb_mfma<<<512, 256, 0, stream>>>((const __bf16*)h2bf, chwbf, z);
    // bn1 again + relu + residual -> out
    bn_stats<<<128, 256, 0, stream>>>(z, sum2, sq2);
    bn_res<<<4096, 256, 0, stream>>>(z, res, sum2, sq2, g1, b1, out);
}

// Round 11
// 236.446 us; speedup vs baseline: 2.9727x; 1.1578x over previous
//
#include <hip/hip_runtime.h>

#define DEVINL __device__ __forceinline__

constexpr int Bc = 32, Cc = 64, Tc = 1024, DIM2c = 128;
constexpr int Nn = Bc * Tc;            // 32768 nodes
constexpr int Ec = 524288;             // edges (self-loops handled in-kernel)

typedef __bf16 bf16x8 __attribute__((ext_vector_type(8)));
typedef __bf16 bf16x4 __attribute__((ext_vector_type(4)));
typedef float  f32x4  __attribute__((ext_vector_type(4)));

// workspace layout (float offsets)
constexpr long O_RES   = 0;            // 4194304 fp32
constexpr long O_GOUT  = 4194304;      // 4194304 fp32
constexpr long O_XT    = 8388608;      // bf16 x 2097152: [b*1024+t][ci]
constexpr long O_HBF   = 9437184;      // bf16 x 2097152: flat bn0(x)
constexpr long O_XLQ   = 10485760;     // 2097152 uint (head-split bf16, u16[n][128])
constexpr long O_XRQ   = 12582912;     // 2097152 uint
constexpr long O_Z     = 16777216;     // 4194304 fp32
constexpr long O_WCBF  = 20971520;     // bf16 x 73728: [kk][co][ci]
constexpr long O_WLR   = 21008384;     // bf16 x 16384: [j 256][c 64]
constexpr long O_CHB   = 21016576;     // bf16 x 16384: [j 128][c 128]
constexpr long O_STAT  = 21024768;     // 1024 (zeroed by memset)
constexpr long O_CUR   = 21025792;     // 32768 ints (zeroed, contiguous w/ STAT)
constexpr long O_BUCK  = 21058560;     // 2097152 ints

DEVINL float unpack_lo(unsigned v) { return __uint_as_float(v << 16); }
DEVINL float unpack_hi(unsigned v) { return __uint_as_float(v & 0xffff0000u); }
DEVINL unsigned bfb(float f) { return (__float_as_uint(f) + 0x8000u) >> 16; }

// ================= setup = prep_w U bn0_sums U bucket_fill =================
__global__ __launch_bounds__(256) void setup(const float* __restrict__ x,
        const float* __restrict__ cw, const float* __restrict__ wl,
        const float* __restrict__ wr, const float* __restrict__ chw,
        const int* __restrict__ ei,
        __bf16* __restrict__ wcbf, __bf16* __restrict__ wlrbf,
        __bf16* __restrict__ chwbf,
        float* __restrict__ sum0, float* __restrict__ sq0,
        int* __restrict__ cursor, int* __restrict__ bucket) {
    int bid = blockIdx.x, tid = threadIdx.x;
    if (bid < 416) {                           // weight prep (106496 items exactly)
        int i = bid * 256 + tid;
        if (i < 73728) {                       // wcbf[kk][co][ci] = cw[co][ci*9+kk]
            int kk = i >> 13, co = (i >> 6) & 127, ci = i & 63;
            wcbf[i] = (__bf16)cw[co * 576 + ci * 9 + kk];
        } else if (i < 73728 + 16384) {        // wlrbf[j][c]
            int j = i - 73728;
            int r = j >> 6, c = j & 63;
            float v = (r < 128) ? wl[r * 64 + c] : wr[(r - 128) * 64 + c];
            wlrbf[j] = (__bf16)v;
        } else {                               // chwbf[j][c]
            int j = i - 73728 - 16384;
            chwbf[j] = (__bf16)chw[j];
        }
    } else if (bid < 672) {                    // bn0 sums (atomics into memset-zeroed stat)
        int pq = bid - 416;
        int c = pq & 63, q = pq >> 6;
        const float4* base = (const float4*)(x + (long)q * 8 * 65536 + (long)c * 1024);
        float s = 0.f, qq = 0.f;
        for (int i = tid; i < 2048; i += 256) {
            int b = i >> 8, t4 = i & 255;
            float4 v = base[b * 16384 + t4];
            s += v.x + v.y + v.z + v.w;
            qq = fmaf(v.x, v.x, qq); qq = fmaf(v.y, v.y, qq);
            qq = fmaf(v.z, v.z, qq); qq = fmaf(v.w, v.w, qq);
        }
        for (int off = 32; off; off >>= 1) { s += __shfl_down(s, off); qq += __shfl_down(qq, off); }
        __shared__ float ls[4], lq[4];
        int w = tid >> 6, lane = tid & 63;
        if (lane == 0) { ls[w] = s; lq[w] = qq; }
        __syncthreads();
        if (tid == 0) {
            unsafeAtomicAdd(sum0 + c, ls[0] + ls[1] + ls[2] + ls[3]);
            unsafeAtomicAdd(sq0 + c, lq[0] + lq[1] + lq[2] + lq[3]);
        }
    } else {                                   // bucket CSR fill (2048 blocks)
        int e = (bid - 672) * 256 + tid;
        int t = ei[Ec + e];
        int slot = atomicAdd(cursor + t, 1);
        bucket[t * 64 + slot] = ei[e];
    }
}

// ================= xprep: bn0-apply -> hbf + xt =================
__global__ __launch_bounds__(256) void xprep(const float* __restrict__ x,
        const float* __restrict__ sum0, const float* __restrict__ sq0,
        const float* __restrict__ g0, const float* __restrict__ b0,
        __bf16* __restrict__ hbf, __bf16* __restrict__ xt) {
    __shared__ float lds[64][65];
    __shared__ float scs[64], shs[64];
    int tid = threadIdx.x;
    if (tid < 64) {
        float mu = sum0[tid] * (1.f / 32768.f);
        float var = sq0[tid] * (1.f / 32768.f) - mu * mu;
        float rs = rsqrtf(var + 1e-5f);
        float sc = rs * g0[tid];
        scs[tid] = sc; shs[tid] = b0[tid] - mu * sc;
    }
    __syncthreads();
    int t0 = blockIdx.x * 64;
    int b  = blockIdx.y;
    const float* xb = x + (long)b * 65536;
    for (int i = tid; i < 4096; i += 256) {
        int ci = i >> 6, tl = i & 63;
        float v = fmaf(xb[ci * 1024 + t0 + tl], scs[ci], shs[ci]);
        hbf[(long)b * 65536 + ci * 1024 + t0 + tl] = (__bf16)v;
        lds[ci][tl] = v;
    }
    __syncthreads();
    for (int i = tid; i < 4096; i += 256) {
        int t = i >> 6, ci = i & 63;
        xt[((long)b * 1024 + t0 + t) * 64 + ci] = (__bf16)lds[ci][t];
    }
}

// ================= conv (LDS-staged) U gemm1 (MFMA), interleaved roles =================
constexpr int XS_STRIDE = 68;          // bf16 units

DEVINL void conv_role(int cid, const __bf16* __restrict__ xt,
        const __bf16* __restrict__ wcbf, const float* __restrict__ cb,
        float* __restrict__ res, __bf16* xs) {
    int tid = threadIdx.x;
    int tbase = (cid & 7) * 128;
    int cohalf = (cid >> 3) & 1;
    int b = cid >> 4;
    const uint2* xg = (const uint2*)(xt + (long)b * 65536);
    for (int i = tid; i < 136 * 16; i += 256) {
        int row = i >> 4, c4 = i & 15;
        int t = tbase + row - 4;
        uint2 v; v.x = 0u; v.y = 0u;
        if ((unsigned)t < 1024u) v = xg[t * 16 + c4];
        *(uint2*)(xs + row * XS_STRIDE + c4 * 4) = v;
    }
    __syncthreads();
    int wv = tid >> 6, lane = tid & 63;
    int col = lane & 15, q = lane >> 4;
    int co0 = cohalf * 64 + wv * 16;
    bf16x8 af[18];
    #pragma unroll
    for (int kk = 0; kk < 9; kk++)
        #pragma unroll
        for (int ks = 0; ks < 2; ks++)
            af[kk * 2 + ks] = *(const bf16x8*)(wcbf +
                ((long)kk * 8192 + (long)(co0 + col) * 64 + ks * 32 + q * 8));
    float bi0 = cb[co0 + q * 4], bi1 = cb[co0 + q * 4 + 1];
    float bi2 = cb[co0 + q * 4 + 2], bi3 = cb[co0 + q * 4 + 3];
    for (int nt = 0; nt < 8; nt++) {
        int t0 = tbase + nt * 16;
        f32x4 acc; acc[0] = bi0; acc[1] = bi1; acc[2] = bi2; acc[3] = bi3;
        #pragma unroll
        for (int kk = 0; kk < 9; kk++) {
            const __bf16* rp = xs + (nt * 16 + col + kk) * XS_STRIDE + q * 8;
            #pragma unroll
            for (int ks = 0; ks < 2; ks++) {
                bf16x4 lo = *(const bf16x4*)(rp + ks * 32);
                bf16x4 hi = *(const bf16x4*)(rp + ks * 32 + 4);
                bf16x8 bfx;
                bfx[0]=lo[0]; bfx[1]=lo[1]; bfx[2]=lo[2]; bfx[3]=lo[3];
                bfx[4]=hi[0]; bfx[5]=hi[1]; bfx[6]=hi[2]; bfx[7]=hi[3];
                acc = __builtin_amdgcn_mfma_f32_16x16x32_bf16(af[kk * 2 + ks], bfx, acc, 0, 0, 0);
            }
        }
        long ob = (long)b * 131072 + (long)(co0 + q * 4) * 1024 + t0 + col;
        res[ob]        = fmaxf(acc[0], 0.f);
        res[ob + 1024] = fmaxf(acc[1], 0.f);
        res[ob + 2048] = fmaxf(acc[2], 0.f);
        res[ob + 3072] = fmaxf(acc[3], 0.f);
    }
}

// u16 slot d (d<64) = head0 dim d; slot 64+d = head1 dim d  (per node row of 128 u16)
DEVINL void gemm1_role(int mb, const __bf16* __restrict__ hbf,
        const __bf16* __restrict__ wlrbf,
        unsigned short* __restrict__ xl16, unsigned short* __restrict__ xr16) {
    int wv = threadIdx.x >> 6, lane = threadIdx.x & 63;
    int col = lane & 15, q = lane >> 4;
    int d0 = wv * 16;
    long mbase = (long)mb * 64;
    bf16x8 bfr[4][2];
    #pragma unroll
    for (int t = 0; t < 4; t++) {
        int j = d0 + t * 64 + col;
        #pragma unroll
        for (int ks = 0; ks < 2; ks++)
            bfr[t][ks] = *(const bf16x8*)(wlrbf + (long)j * 64 + ks * 32 + q * 8);
    }
    int d = d0 + col;
    for (int mt = 0; mt < 4; mt++) {
        long r0 = mbase + mt * 16;
        bf16x8 a0 = *(const bf16x8*)(hbf + (r0 + col) * 64 + q * 8);
        bf16x8 a1 = *(const bf16x8*)(hbf + (r0 + col) * 64 + 32 + q * 8);
        f32x4 acc[4];
        #pragma unroll
        for (int t = 0; t < 4; t++) { acc[t][0] = 0.f; acc[t][1] = 0.f; acc[t][2] = 0.f; acc[t][3] = 0.f; }
        #pragma unroll
        for (int t = 0; t < 4; t++) {
            acc[t] = __builtin_amdgcn_mfma_f32_16x16x32_bf16(a0, bfr[t][0], acc[t], 0, 0, 0);
            acc[t] = __builtin_amdgcn_mfma_f32_16x16x32_bf16(a1, bfr[t][1], acc[t], 0, 0, 0);
        }
        #pragma unroll
        for (int reg = 0; reg < 4; reg++) {
            long rb = (r0 + q * 4 + reg) * 128;
            xl16[rb + d]      = (unsigned short)bfb(acc[0][reg]);
            xl16[rb + 64 + d] = (unsigned short)bfb(acc[1][reg]);
            xr16[rb + d]      = (unsigned short)bfb(acc[2][reg]);
            xr16[rb + 64 + d] = (unsigned short)bfb(acc[3][reg]);
        }
    }
}

__global__ __launch_bounds__(256) void conv_gemm1(const __bf16* __restrict__ xt,
        const __bf16* __restrict__ wcbf, const float* __restrict__ cb,
        float* __restrict__ res, const __bf16* __restrict__ hbf,
        const __bf16* __restrict__ wlrbf,
        unsigned* __restrict__ xlq, unsigned* __restrict__ xrq) {
    __shared__ __bf16 xs[136 * XS_STRIDE];
    int bid = blockIdx.x;
    if (bid & 1) gemm1_role(bid >> 1, hbf, wlrbf, (unsigned short*)xlq, (unsigned short*)xrq);
    else conv_role(bid >> 1, xt, wcbf, cb, res, xs);
}

// ================= fused GATv2: 8 lanes per edge, 8 edges per batch =================
// lane l = g*8+j: group g handles edge it*8+g; lane's 8 uints = u16 slots 16j..16j+15.
// HEADS: j in {0..3} -> head0 (slots 0..63), j in {4..7} -> head1 (slots 64..127).
// Logit reduce uses masks {1,2} ONLY so each head's 4 lanes sum separately (per-head
// softmax, matching the reference). Cross-group reduce (masks 8,16,32) preserves j,
// so den/acc/rn stay per-head. Self-loop = edge index i==cnt.
__global__ __launch_bounds__(256) void gat_agg(const uint4* __restrict__ xlq4,
        const uint4* __restrict__ xrq4,
        const int* __restrict__ cursor, const int* __restrict__ bucket,
        const float* __restrict__ att, float* __restrict__ gout) {
    int wid = (blockIdx.x * 256 + threadIdx.x) >> 6;
    int lane = threadIdx.x & 63;
    int g = lane >> 3, j = lane & 7;
    float av[16];
    #pragma unroll
    for (int k = 0; k < 16; k++) av[k] = att[16 * j + k];
    uint4 r0v = xrq4[(long)wid * 16 + j * 2];
    uint4 r1v = xrq4[(long)wid * 16 + j * 2 + 1];
    float xr[16];
    {
        unsigned ru[8] = {r0v.x, r0v.y, r0v.z, r0v.w, r1v.x, r1v.y, r1v.z, r1v.w};
        #pragma unroll
        for (int k = 0; k < 8; k++) { xr[2*k] = unpack_lo(ru[k]); xr[2*k+1] = unpack_hi(ru[k]); }
    }
    int cnt = cursor[wid];
    int s_all = bucket[wid * 64 + lane];
    float acc[16];
    #pragma unroll
    for (int k = 0; k < 16; k++) acc[k] = 0.f;
    float den = 0.f;
    int nit = (cnt + 8) >> 3;                  // ceil((cnt+1)/8)
    // prime prefetch for it=0
    int sp = __shfl(s_all, g);
    sp = (g < cnt) ? sp : wid;
    uint4 p0 = xlq4[(long)sp * 16 + j * 2];
    uint4 p1 = xlq4[(long)sp * 16 + j * 2 + 1];
    for (int it = 0; it < nit; it++) {
        uint4 c0 = p0, c1 = p1;
        int icur = it * 8 + g;
        int inext = icur + 8;
        if (it + 1 < nit) {
            int sn = __shfl(s_all, inext & 63);
            sn = (inext < cnt) ? sn : wid;
            p0 = xlq4[(long)sn * 16 + j * 2];
            p1 = xlq4[(long)sn * 16 + j * 2 + 1];
        }
        unsigned uu[8] = {c0.x, c0.y, c0.z, c0.w, c1.x, c1.y, c1.z, c1.w};
        float xl[16];
        float w = 0.f;
        #pragma unroll
        for (int k = 0; k < 8; k++) {
            float lo = unpack_lo(uu[k]), hi = unpack_hi(uu[k]);
            xl[2*k] = lo; xl[2*k+1] = hi;
            float s0 = lo + xr[2*k]; s0 = fmaxf(s0, 0.2f * s0);
            float s1 = hi + xr[2*k+1]; s1 = fmaxf(s1, 0.2f * s1);
            w = fmaf(s1, av[2*k+1], fmaf(s0, av[2*k], w));
        }
        // per-head logit: sum only within the 4-lane head subgroup (masks 1,2)
        w += __shfl_xor(w, 1); w += __shfl_xor(w, 2);
        float e2 = (icur <= cnt) ? __expf(w) : 0.f;
        den += e2;
        #pragma unroll
        for (int k = 0; k < 16; k++) acc[k] = fmaf(e2, xl[k], acc[k]);
    }
    // cross-group reduce (masks 8,16,32) — preserves j, hence per-head den/acc
    #pragma unroll
    for (int m = 8; m <= 32; m <<= 1) {
        den += __shfl_xor(den, m);
        #pragma unroll
        for (int k = 0; k < 16; k++) acc[k] += __shfl_xor(acc[k], m);
    }
    float rn = __builtin_amdgcn_rcpf(den);
    if (g == 0) {                              // lanes 0..7 write 64B each
        #pragma unroll
        for (int c = 0; c < 4; c++) {
            float4 o;
            o.x = acc[4*c] * rn;     o.y = acc[4*c+1] * rn;
            o.z = acc[4*c+2] * rn;   o.w = acc[4*c+3] * rn;
            *(float4*)(gout + (long)wid * 128 + 16 * j + 4 * c) = o;
        }
    }
}

// ================= bn over [N,128] (axis 0) =================
__global__ __launch_bounds__(256) void bn_stats(const float* __restrict__ X,
        float* __restrict__ sum, float* __restrict__ sq) {
    int f = threadIdx.x & 127, sub = threadIdx.x >> 7;
    int r0 = blockIdx.x * 256;
    float s = 0.f, q = 0.f;
    for (int r = r0 + sub; r < r0 + 256; r += 2) {
        float v = X[(long)r * 128 + f];
        s += v; q = fmaf(v, v, q);
    }
    __shared__ float ls[256], lq[256];
    ls[threadIdx.x] = s; lq[threadIdx.x] = q;
    __syncthreads();
    if (threadIdx.x < 128) {
        s = ls[threadIdx.x] + ls[threadIdx.x + 128];
        q = lq[threadIdx.x] + lq[threadIdx.x + 128];
        unsafeAtomicAdd(sum + f, s);
        unsafeAtomicAdd(sq + f, q);
    }
}

// ================= cheb_fused: h2 = res+relu(bn1(gout)) in LDS, z = h2 @ chw^T, stats2 =================
__global__ __launch_bounds__(256) void cheb_fused(const float* __restrict__ gout,
        const float* __restrict__ res, const float* __restrict__ sum1,
        const float* __restrict__ sq1, const float* __restrict__ g1,
        const float* __restrict__ b1, const __bf16* __restrict__ chwbf,
        float* __restrict__ z, float* __restrict__ sum2, float* __restrict__ sq2) {
    __shared__ unsigned xs[64 * 68];           // h2 tile, bf16 pairs, stride 68 uints
    __shared__ float scs[128], shs[128], cs[128], cq[128];
    int tid = threadIdx.x;
    if (tid < 128) {
        float mu = sum1[tid] * (1.f / 32768.f);
        float var = sq1[tid] * (1.f / 32768.f) - mu * mu;
        float rs = rsqrtf(var + 1e-5f);
        float sc = rs * g1[tid];
        scs[tid] = sc; shs[tid] = b1[tid] - mu * sc;
        cs[tid] = 0.f;
    } else cq[tid - 128] = 0.f;
    __syncthreads();
    long r0 = (long)blockIdx.x * 64;
    for (int i = tid; i < 2048; i += 256) {    // 64 rows x 32 float4 chunks
        int row = i >> 5, c4 = i & 31;
        long gidx = (r0 + row) * 32 + c4;
        float4 v = ((const float4*)gout)[gidx];
        float4 r = ((const float4*)res)[gidx];
        int f0 = c4 * 4;
        float o0 = r.x + fmaxf(fmaf(v.x, scs[f0],     shs[f0]),     0.f);
        float o1 = r.y + fmaxf(fmaf(v.y, scs[f0 + 1], shs[f0 + 1]), 0.f);
        float o2 = r.z + fmaxf(fmaf(v.z, scs[f0 + 2], shs[f0 + 2]), 0.f);
        float o3 = r.w + fmaxf(fmaf(v.w, scs[f0 + 3], shs[f0 + 3]), 0.f);
        xs[row * 68 + c4 * 2]     = (bfb(o1) << 16) | bfb(o0);
        xs[row * 68 + c4 * 2 + 1] = (bfb(o3) << 16) | bfb(o2);
    }
    __syncthreads();
    int wv = tid >> 6, lane = tid & 63;
    int col = lane & 15, q = lane >> 4;
    bf16x8 bfr[2][4];
    #pragma unroll
    for (int t = 0; t < 2; t++) {
        int jj = wv * 16 + t * 64 + col;
        #pragma unroll
        for (int ks = 0; ks < 4; ks++)
            bfr[t][ks] = *(const bf16x8*)(chwbf + (long)jj * 128 + ks * 32 + q * 8);
    }
    float ls0 = 0.f, ls1 = 0.f, lq0 = 0.f, lq1 = 0.f;
    for (int mt = 0; mt < 4; mt++) {
        const __bf16* ap = (const __bf16*)xs + (mt * 16 + col) * 136;
        bf16x8 a[4];
        #pragma unroll
        for (int ks = 0; ks < 4; ks++)
            a[ks] = *(const bf16x8*)(ap + ks * 32 + q * 8);
        f32x4 acc[2];
        #pragma unroll
        for (int t = 0; t < 2; t++) { acc[t][0] = 0.f; acc[t][1] = 0.f; acc[t][2] = 0.f; acc[t][3] = 0.f; }
        #pragma unroll
        for (int t = 0; t < 2; t++)
            #pragma unroll
            for (int ks = 0; ks < 4; ks++)
                acc[t] = __builtin_amdgcn_mfma_f32_16x16x32_bf16(a[ks], bfr[t][ks], acc[t], 0, 0, 0);
        #pragma unroll
        for (int reg = 0; reg < 4; reg++) {
            float v0 = acc[0][reg], v1 = acc[1][reg];
            long zr = (r0 + mt * 16 + q * 4 + reg) * 128;
            z[zr + wv * 16 + col]      = v0;
            z[zr + wv * 16 + 64 + col] = v1;
            ls0 += v0; lq0 = fmaf(v0, v0, lq0);
            ls1 += v1; lq1 = fmaf(v1, v1, lq1);
        }
    }
    int j0 = wv * 16 + col;
    atomicAdd(&cs[j0], ls0);      atomicAdd(&cs[j0 + 64], ls1);
    atomicAdd(&cq[j0], lq0);      atomicAdd(&cq[j0 + 64], lq1);
    __syncthreads();
    if (tid < 128) unsafeAtomicAdd(sum2 + tid, cs[tid]);
    else unsafeAtomicAdd(sq2 + tid - 128, cq[tid - 128]);
}

// ================= res + relu(bn(z)) -> fp32 out =================
__global__ __launch_bounds__(256) void bn_res(const float* __restrict__ X,
        const float* __restrict__ res, const float* __restrict__ sum,
        const float* __restrict__ sq, const float* __restrict__ g,
        const float* __restrict__ bta, float* __restrict__ out) {
    __shared__ float scs[128], shs[128];
    int tid = threadIdx.x;
    if (tid < 128) {
        float mu = sum[tid] * (1.f / 32768.f);
        float var = sq[tid] * (1.f / 32768.f) - mu * mu;
        float rs = rsqrtf(var + 1e-5f);
        float sc = rs * g[tid];
        scs[tid] = sc; shs[tid] = bta[tid] - mu * sc;
    }
    __syncthreads();
    int idx = blockIdx.x * 256 + tid;
    int f0 = (idx & 31) * 4;
    float4 v = ((const float4*)X)[idx];
    float4 r = ((const float4*)res)[idx];
    float4 o;
    o.x = r.x + fmaxf(fmaf(v.x, scs[f0],     shs[f0]),     0.f);
    o.y = r.y + fmaxf(fmaf(v.y, scs[f0 + 1], shs[f0 + 1]), 0.f);
    o.z = r.z + fmaxf(fmaf(v.z, scs[f0 + 2], shs[f0 + 2]), 0.f);
    o.w = r.w + fmaxf(fmaf(v.w, scs[f0 + 3], shs[f0 + 3]), 0.f);
    ((float4*)out)[idx] = o;
}

extern "C" void kernel_launch(void* const* d_in, const int* in_sizes, int n_in,
                              void* d_out, int out_size, void* d_ws, size_t ws_size,
                              hipStream_t stream) {
    const float* x   = (const float*)d_in[0];
    const int*   ei  = (const int*)d_in[1];
    const float* g0  = (const float*)d_in[2];
    const float* b0  = (const float*)d_in[3];
    const float* cw  = (const float*)d_in[4];
    const float* cb  = (const float*)d_in[5];
    const float* wl  = (const float*)d_in[6];
    const float* wr  = (const float*)d_in[7];
    const float* att = (const float*)d_in[8];
    // d_in[9] = gat_bias: cancels exactly inside the following bn2d -> unused
    const float* g1  = (const float*)d_in[10];
    const float* b1  = (const float*)d_in[11];
    const float* chw = (const float*)d_in[12];
    // d_in[13] = cheb_b: cancels inside the following bn2d -> unused
    float* out = (float*)d_out;

    float* ws = (float*)d_ws;
    float*    res   = ws + O_RES;
    float*    gout  = ws + O_GOUT;
    __bf16*   xt    = (__bf16*)(ws + O_XT);
    __bf16*   hbf   = (__bf16*)(ws + O_HBF);
    unsigned* xlq   = (unsigned*)(ws + O_XLQ);
    unsigned* xrq   = (unsigned*)(ws + O_XRQ);
    float*    z     = ws + O_Z;
    __bf16*   wcbf  = (__bf16*)(ws + O_WCBF);
    __bf16*   wlrbf = (__bf16*)(ws + O_WLR);
    __bf16*   chwbf = (__bf16*)(ws + O_CHB);
    float*    st    = ws + O_STAT;
    int*      cursor = (int*)(ws + O_CUR);
    int*      bucket = (int*)(ws + O_BUCK);
    float *sum0 = st,       *sq0 = st + 64;
    float *sum1 = st + 128, *sq1 = st + 256;
    float *sum2 = st + 384, *sq2 = st + 512;

    // one memset covers stat block (4KB) + cursor (128KB), contiguous
    hipMemsetAsync(st, 0, (size_t)(1024 + 32768) * 4, stream);

    // prep_w U bn0_sums U bucket_fill
    setup<<<2720, 256, 0, stream>>>(x, cw, wl, wr, chw, ei,
                                    wcbf, wlrbf, chwbf, sum0, sq0, cursor, bucket);
    // bn0-apply -> bf16 (flat + transposed)
    xprep<<<dim3(16, 32), 256, 0, stream>>>(x, sum0, sq0, g0, b0, hbf, xt);
    // conv1d+relu->res U gemm1->xlq/xrq (MFMA, interleaved roles, LDS-staged conv)
    conv_gemm1<<<1024, 256, 0, stream>>>(xt, wcbf, cb, res, hbf, wlrbf, xlq, xrq);
    // fused GATv2 (8 lanes/edge, per-head softmax)
    gat_agg<<<8192, 256, 0, stream>>>((const uint4*)xlq, (const uint4*)xrq,
                                      cursor, bucket, att, gout);
    // bn1 stats
    bn_stats<<<128, 256, 0, stream>>>(gout, sum1, sq1);
    // h2 (in LDS) -> cheb GEMM -> z + stats2
    cheb_fused<<<512, 256, 0, stream>>>(gout, res, sum1, sq1, g1, b1, chwbf,
                                        z, sum2, sq2);
    // bn + relu + residual -> out
    bn_res<<<4096, 256, 0, stream>>>(z, res, sum2, sq2, g1, b1, out);
}